// Round 1
// baseline (6483.859 us; speedup 1.0000x reference)
//
#include <hip/hip_runtime.h>
#include <math.h>

#define D_MODEL 1024
#define NHEAD   16
#define HDIM    64
#define HID     2730
#define SEQ     2048
#define BATCH   2
#define NTOK    (BATCH * SEQ)   // 4096

// ---------------------------------------------------------------------------
// LayerNorm: one block (256 threads) per row of 1024
// ---------------------------------------------------------------------------
__global__ void ln_kernel(const float* __restrict__ x,
                          const float* __restrict__ w,
                          const float* __restrict__ b,
                          float* __restrict__ out,
                          float eps)
{
    int row = blockIdx.x;
    int t = threadIdx.x;               // 0..255
    const float4* xr = (const float4*)(x + (size_t)row * D_MODEL);
    float4 v = xr[t];
    float s  = v.x + v.y + v.z + v.w;
    float sq = v.x * v.x + v.y * v.y + v.z * v.z + v.w * v.w;
#pragma unroll
    for (int off = 32; off > 0; off >>= 1) {
        s  += __shfl_xor(s, off);
        sq += __shfl_xor(sq, off);
    }
    __shared__ float ss[4], ssq[4];
    int wave = t >> 6;
    if ((t & 63) == 0) { ss[wave] = s; ssq[wave] = sq; }
    __syncthreads();
    s  = ss[0] + ss[1] + ss[2] + ss[3];
    sq = ssq[0] + ssq[1] + ssq[2] + ssq[3];
    float mu  = s * (1.0f / D_MODEL);
    float var = sq * (1.0f / D_MODEL) - mu * mu;
    float inv = rsqrtf(var + eps);
    float4 wv = ((const float4*)w)[t];
    float4 bv = ((const float4*)b)[t];
    float4 o;
    o.x = (v.x - mu) * inv * wv.x + bv.x;
    o.y = (v.y - mu) * inv * wv.y + bv.y;
    o.z = (v.z - mu) * inv * wv.z + bv.z;
    o.w = (v.w - mu) * inv * wv.w + bv.w;
    ((float4*)(out + (size_t)row * D_MODEL))[t] = o;
}

// ---------------------------------------------------------------------------
// SGEMM: C[M,N] = alpha*(A[M,K] @ B[K,N]) (+bias[N]) (+R[M,N])
// 64x64 block tile, BK=16, 256 threads, 4x4 per thread. Guards on N and K.
// ---------------------------------------------------------------------------
template<bool BIAS, bool RES>
__global__ void sgemm_kernel(const float* __restrict__ A, int lda,
                             const float* __restrict__ B, int ldb,
                             const float* __restrict__ bias,
                             const float* __restrict__ R, int ldr,
                             float* __restrict__ C, int ldc,
                             int M, int N, int K, float alpha)
{
    __shared__ float As[16][68];   // As[k][m]
    __shared__ float Bs[16][68];   // Bs[k][n]
    int bm = blockIdx.y * 64;
    int bn = blockIdx.x * 64;
    int tid = threadIdx.x;
    int tr = (tid >> 4) << 2;      // 0..60
    int tc = (tid & 15) << 2;      // 0..60
    int am = tid >> 2;             // 0..63
    int ak = (tid & 3) << 2;       // 0,4,8,12
    int bk = tid >> 4;             // 0..15
    int bc = (tid & 15) << 2;      // 0..60
    float acc[4][4] = {};
    for (int k0 = 0; k0 < K; k0 += 16) {
        const float* Arow = A + (size_t)(bm + am) * lda + k0 + ak;
#pragma unroll
        for (int i = 0; i < 4; ++i)
            As[ak + i][am] = (k0 + ak + i < K) ? Arow[i] : 0.0f;
        {
            const float* Brow = B + (size_t)(k0 + bk) * ldb + bn + bc;
            bool kok = (k0 + bk) < K;
#pragma unroll
            for (int i = 0; i < 4; ++i)
                Bs[bk][bc + i] = (kok && (bn + bc + i < N)) ? Brow[i] : 0.0f;
        }
        __syncthreads();
#pragma unroll
        for (int kk = 0; kk < 16; ++kk) {
            float a0 = As[kk][tr], a1 = As[kk][tr + 1], a2 = As[kk][tr + 2], a3 = As[kk][tr + 3];
            float b0 = Bs[kk][tc], b1 = Bs[kk][tc + 1], b2 = Bs[kk][tc + 2], b3 = Bs[kk][tc + 3];
            acc[0][0] += a0 * b0; acc[0][1] += a0 * b1; acc[0][2] += a0 * b2; acc[0][3] += a0 * b3;
            acc[1][0] += a1 * b0; acc[1][1] += a1 * b1; acc[1][2] += a1 * b2; acc[1][3] += a1 * b3;
            acc[2][0] += a2 * b0; acc[2][1] += a2 * b1; acc[2][2] += a2 * b2; acc[2][3] += a2 * b3;
            acc[3][0] += a3 * b0; acc[3][1] += a3 * b1; acc[3][2] += a3 * b2; acc[3][3] += a3 * b3;
        }
        __syncthreads();
    }
#pragma unroll
    for (int i = 0; i < 4; ++i) {
        int m = bm + tr + i;
#pragma unroll
        for (int j = 0; j < 4; ++j) {
            int n = bn + tc + j;
            if (n < N) {
                float val = alpha * acc[i][j];
                if (BIAS) val += bias[n];
                if (RES)  val += R[(size_t)m * ldr + n];
                C[(size_t)m * ldc + n] = val;
            }
        }
    }
}

// ---------------------------------------------------------------------------
// Retention: per (b, h, 64-row q tile). out = (QK^T * decay) @ V, then
// per-row groupnorm over the 64 dims (eps 1e-6).
// Layout of q/k/v/ret: (B*S, 1024) row-major, col = h*64 + d.
// ---------------------------------------------------------------------------
__global__ void retention_kernel(const float* __restrict__ q,
                                 const float* __restrict__ k,
                                 const float* __restrict__ v,
                                 float* __restrict__ ret)
{
    int qb = blockIdx.x;   // 0..31
    int h  = blockIdx.y;   // 0..15
    int b  = blockIdx.z;   // 0..1
    __shared__ float ks[64][68];
    __shared__ float vs[64][68];
    __shared__ float sc[64][68];
    int tid  = threadIdx.x;          // 256
    int r    = tid >> 2;             // 0..63 query row within tile
    int quad = tid & 3;
    int srow = qb * 64 + r;
    float log2g = log1pf(-exp2f(-5.0f - (float)h)) * 1.4426950408889634f;
    size_t hbase = (size_t)b * SEQ * D_MODEL + (size_t)h * HDIM;

    // q row into registers (4 threads redundantly load same row; L2-served)
    float qreg[64];
    {
        const float4* qrow = (const float4*)(q + hbase + (size_t)srow * D_MODEL);
#pragma unroll
        for (int d4 = 0; d4 < 16; ++d4) {
            float4 t4 = qrow[d4];
            qreg[4 * d4 + 0] = t4.x; qreg[4 * d4 + 1] = t4.y;
            qreg[4 * d4 + 2] = t4.z; qreg[4 * d4 + 3] = t4.w;
        }
    }
    float acc[16];
#pragma unroll
    for (int i = 0; i < 16; ++i) acc[i] = 0.0f;

    for (int tb = 0; tb <= qb; ++tb) {
        __syncthreads();   // previous iteration's readers done
        // load k, v tiles (64x64 each)
#pragma unroll
        for (int i = 0; i < 4; ++i) {
            int lin = tid + 256 * i;       // 0..1023
            int rr = lin >> 4;
            int c  = (lin & 15) << 2;
            *(float4*)(&ks[rr][c]) = *(const float4*)(k + hbase + (size_t)(tb * 64 + rr) * D_MODEL + c);
            *(float4*)(&vs[rr][c]) = *(const float4*)(v + hbase + (size_t)(tb * 64 + rr) * D_MODEL + c);
        }
        __syncthreads();
        // scores: thread handles j = quad + 4*jj
        int tbase = tb * 64;
#pragma unroll 4
        for (int jj = 0; jj < 16; ++jj) {
            int j = quad + (jj << 2);
            const float4* krow = (const float4*)(&ks[j][0]);
            float dot = 0.0f;
#pragma unroll
            for (int d4 = 0; d4 < 16; ++d4) {
                float4 k4 = krow[d4];
                dot += qreg[4 * d4 + 0] * k4.x + qreg[4 * d4 + 1] * k4.y
                     + qreg[4 * d4 + 2] * k4.z + qreg[4 * d4 + 3] * k4.w;
            }
            int trow = tbase + j;
            float decay = (srow >= trow) ? exp2f((float)(srow - trow) * log2g) : 0.0f;
            sc[r][j] = dot * decay;
        }
        __syncthreads();
        // accumulate out: thread owns (r, d = quad*16 .. +15)
        const int dbase = quad << 4;
#pragma unroll 2
        for (int j = 0; j < 64; ++j) {
            float s = sc[r][j];
            const float4* vrow = (const float4*)(&vs[j][dbase]);
            float4 v0 = vrow[0], v1 = vrow[1], v2 = vrow[2], v3 = vrow[3];
            acc[0]  += s * v0.x; acc[1]  += s * v0.y; acc[2]  += s * v0.z; acc[3]  += s * v0.w;
            acc[4]  += s * v1.x; acc[5]  += s * v1.y; acc[6]  += s * v1.z; acc[7]  += s * v1.w;
            acc[8]  += s * v2.x; acc[9]  += s * v2.y; acc[10] += s * v2.z; acc[11] += s * v2.w;
            acc[12] += s * v3.x; acc[13] += s * v3.y; acc[14] += s * v3.z; acc[15] += s * v3.w;
        }
    }
    // groupnorm over 64 dims (4 lanes x 16 each; lanes 4r..4r+3 in-wave)
    float s1 = 0.0f, s2 = 0.0f;
#pragma unroll
    for (int i = 0; i < 16; ++i) { s1 += acc[i]; s2 += acc[i] * acc[i]; }
    s1 += __shfl_xor(s1, 1); s2 += __shfl_xor(s2, 1);
    s1 += __shfl_xor(s1, 2); s2 += __shfl_xor(s2, 2);
    float mu  = s1 * (1.0f / 64.0f);
    float var = s2 * (1.0f / 64.0f) - mu * mu;
    float inv = rsqrtf(var + 1e-6f);
    float* orow = ret + hbase + (size_t)srow * D_MODEL + (quad << 4);
#pragma unroll
    for (int i = 0; i < 4; ++i) {
        float4 o;
        o.x = (acc[4 * i + 0] - mu) * inv;
        o.y = (acc[4 * i + 1] - mu) * inv;
        o.z = (acc[4 * i + 2] - mu) * inv;
        o.w = (acc[4 * i + 3] - mu) * inv;
        ((float4*)orow)[i] = o;
    }
}

// ---------------------------------------------------------------------------
// gate: ret *= silu(g), elementwise, in-place
// ---------------------------------------------------------------------------
__global__ void gate_kernel(float* __restrict__ ret, const float* __restrict__ g, int n4)
{
    int idx = blockIdx.x * blockDim.x + threadIdx.x;
    if (idx < n4) {
        float4 rv = ((float4*)ret)[idx];
        float4 gv = ((const float4*)g)[idx];
        rv.x *= gv.x / (1.0f + expf(-gv.x));
        rv.y *= gv.y / (1.0f + expf(-gv.y));
        rv.z *= gv.z / (1.0f + expf(-gv.z));
        rv.w *= gv.w / (1.0f + expf(-gv.w));
        ((float4*)ret)[idx] = rv;
    }
}

// ---------------------------------------------------------------------------
// Fused SwiGLU-in GEMM: Hm[M, HID] = (A@W[:, :HID] + b[:HID]) *
//                                    silu(A@W[:, HID:] + b[HID:])
// A is M x 1024 (lda=1024), W is 1024 x 2*HID.
// ---------------------------------------------------------------------------
__global__ void mlp_in_kernel(const float* __restrict__ A,
                              const float* __restrict__ W,
                              const float* __restrict__ bias,
                              float* __restrict__ Hm,
                              int M, int K)
{
    __shared__ float As[16][68];
    __shared__ float Ba[16][68];
    __shared__ float Bb[16][68];
    int bm = blockIdx.y * 64;
    int bn = blockIdx.x * 64;
    int tid = threadIdx.x;
    int tr = (tid >> 4) << 2;
    int tc = (tid & 15) << 2;
    int am = tid >> 2;
    int ak = (tid & 3) << 2;
    int bk = tid >> 4;
    int bc = (tid & 15) << 2;
    float acca[4][4] = {};
    float accb[4][4] = {};
    for (int k0 = 0; k0 < K; k0 += 16) {
        const float* Arow = A + (size_t)(bm + am) * D_MODEL + k0 + ak;
#pragma unroll
        for (int i = 0; i < 4; ++i)
            As[ak + i][am] = Arow[i];          // K=1024, always in-bounds
        {
            const float* Wrow = W + (size_t)(k0 + bk) * (2 * HID) + bn + bc;
#pragma unroll
            for (int i = 0; i < 4; ++i) {
                bool ok = (bn + bc + i) < HID;
                Ba[bk][bc + i] = ok ? Wrow[i] : 0.0f;
                Bb[bk][bc + i] = ok ? Wrow[HID + i] : 0.0f;
            }
        }
        __syncthreads();
#pragma unroll
        for (int kk = 0; kk < 16; ++kk) {
            float a0 = As[kk][tr], a1 = As[kk][tr + 1], a2 = As[kk][tr + 2], a3 = As[kk][tr + 3];
            float p0 = Ba[kk][tc], p1 = Ba[kk][tc + 1], p2 = Ba[kk][tc + 2], p3 = Ba[kk][tc + 3];
            float q0 = Bb[kk][tc], q1 = Bb[kk][tc + 1], q2 = Bb[kk][tc + 2], q3 = Bb[kk][tc + 3];
            acca[0][0] += a0 * p0; acca[0][1] += a0 * p1; acca[0][2] += a0 * p2; acca[0][3] += a0 * p3;
            acca[1][0] += a1 * p0; acca[1][1] += a1 * p1; acca[1][2] += a1 * p2; acca[1][3] += a1 * p3;
            acca[2][0] += a2 * p0; acca[2][1] += a2 * p1; acca[2][2] += a2 * p2; acca[2][3] += a2 * p3;
            acca[3][0] += a3 * p0; acca[3][1] += a3 * p1; acca[3][2] += a3 * p2; acca[3][3] += a3 * p3;
            accb[0][0] += a0 * q0; accb[0][1] += a0 * q1; accb[0][2] += a0 * q2; accb[0][3] += a0 * q3;
            accb[1][0] += a1 * q0; accb[1][1] += a1 * q1; accb[1][2] += a1 * q2; accb[1][3] += a1 * q3;
            accb[2][0] += a2 * q0; accb[2][1] += a2 * q1; accb[2][2] += a2 * q2; accb[2][3] += a2 * q3;
            accb[3][0] += a3 * q0; accb[3][1] += a3 * q1; accb[3][2] += a3 * q2; accb[3][3] += a3 * q3;
        }
        __syncthreads();
    }
#pragma unroll
    for (int i = 0; i < 4; ++i) {
        int m = bm + tr + i;
#pragma unroll
        for (int j = 0; j < 4; ++j) {
            int n = bn + tc + j;
            if (n < HID) {
                float a  = acca[i][j] + bias[n];
                float bb = accb[i][j] + bias[HID + n];
                Hm[(size_t)m * HID + n] = a * (bb / (1.0f + expf(-bb)));
            }
        }
    }
}

// ---------------------------------------------------------------------------
extern "C" void kernel_launch(void* const* d_in, const int* in_sizes, int n_in,
                              void* d_out, int out_size, void* d_ws, size_t ws_size,
                              hipStream_t stream)
{
    const float* x     = (const float*)d_in[0];
    const float* ln1w  = (const float*)d_in[1];
    const float* ln1b  = (const float*)d_in[2];
    const float* wq    = (const float*)d_in[3];
    const float* wk    = (const float*)d_in[4];
    const float* wv    = (const float*)d_in[5];
    const float* wg    = (const float*)d_in[6];
    const float* wo    = (const float*)d_in[7];
    const float* ln2w  = (const float*)d_in[8];
    const float* ln2b  = (const float*)d_in[9];
    const float* w_in  = (const float*)d_in[10];
    const float* b_in  = (const float*)d_in[11];
    const float* w_out = (const float*)d_in[12];
    const float* b_out = (const float*)d_in[13];
    float* out = (float*)d_out;
    float* ws  = (float*)d_ws;

    const size_t T4 = (size_t)NTOK * D_MODEL;   // 4M floats
    float* xn = ws;             // LN1 out; later reused as LN2 out (y)
    float* qb = ws + 1 * T4;
    float* kb = ws + 2 * T4;
    float* vb = ws + 3 * T4;
    float* gb = ws + 4 * T4;
    float* rb = ws + 5 * T4;    // retention out, gated in-place
    float* hm = ws + 1 * T4;    // SwiGLU mid (4096x2730), reuses q/k/v space
    float* y  = ws;             // LN2 out, reuses xn

    dim3 g16(16, 64);           // N=1024 GEMMs

    // LN1
    ln_kernel<<<NTOK, 256, 0, stream>>>(x, ln1w, ln1b, xn, 1e-5f);
    // q,k,v,g projections (q scaled by HEAD_DIM^-0.5 = 0.125)
    sgemm_kernel<false, false><<<g16, 256, 0, stream>>>(xn, D_MODEL, wq, D_MODEL, nullptr, nullptr, 0, qb, D_MODEL, NTOK, D_MODEL, D_MODEL, 0.125f);
    sgemm_kernel<false, false><<<g16, 256, 0, stream>>>(xn, D_MODEL, wk, D_MODEL, nullptr, nullptr, 0, kb, D_MODEL, NTOK, D_MODEL, D_MODEL, 1.0f);
    sgemm_kernel<false, false><<<g16, 256, 0, stream>>>(xn, D_MODEL, wv, D_MODEL, nullptr, nullptr, 0, vb, D_MODEL, NTOK, D_MODEL, D_MODEL, 1.0f);
    sgemm_kernel<false, false><<<g16, 256, 0, stream>>>(xn, D_MODEL, wg, D_MODEL, nullptr, nullptr, 0, gb, D_MODEL, NTOK, D_MODEL, D_MODEL, 1.0f);
    // retention + groupnorm
    retention_kernel<<<dim3(SEQ / 64, NHEAD, BATCH), 256, 0, stream>>>(qb, kb, vb, rb);
    // gate with silu(xn@wg)
    gate_kernel<<<(int)(T4 / 4 / 256), 256, 0, stream>>>(rb, gb, (int)(T4 / 4));
    // project + residual -> out holds x2
    sgemm_kernel<false, true><<<g16, 256, 0, stream>>>(rb, D_MODEL, wo, D_MODEL, nullptr, x, D_MODEL, out, D_MODEL, NTOK, D_MODEL, D_MODEL, 1.0f);
    // LN2
    ln_kernel<<<NTOK, 256, 0, stream>>>(out, ln2w, ln2b, y, 1e-5f);
    // fused w_in GEMM + SwiGLU
    mlp_in_kernel<<<dim3((HID + 63) / 64, NTOK / 64), 256, 0, stream>>>(y, w_in, b_in, hm, NTOK, D_MODEL);
    // w_out GEMM + bias + residual (reads and rewrites out)
    sgemm_kernel<true, true><<<g16, 256, 0, stream>>>(hm, HID, w_out, D_MODEL, b_out, out, D_MODEL, out, D_MODEL, NTOK, D_MODEL, HID, 1.0f);
}

// Round 2
// 2484.166 us; speedup vs baseline: 2.6101x; 2.6101x over previous
//
#include <hip/hip_runtime.h>
#include <math.h>

#define D_MODEL 1024
#define NHEAD   16
#define HDIM    64
#define HID     2730
#define SEQ     2048
#define BATCH   2
#define NTOK    (BATCH * SEQ)   // 4096

typedef __attribute__((ext_vector_type(8))) short bf16x8;
typedef __attribute__((ext_vector_type(4))) float f32x4;

// fp32 -> bf16 round-to-nearest-even
static __device__ inline short f2bf(float f)
{
    union { float f; unsigned int u; } c; c.f = f;
    unsigned int r = c.u + 0x7FFFu + ((c.u >> 16) & 1u);
    return (short)(r >> 16);
}

// ---------------------------------------------------------------------------
// LayerNorm: one block (256 threads) per row of 1024
// ---------------------------------------------------------------------------
__global__ void ln_kernel(const float* __restrict__ x,
                          const float* __restrict__ w,
                          const float* __restrict__ b,
                          float* __restrict__ out,
                          float eps)
{
    int row = blockIdx.x;
    int t = threadIdx.x;               // 0..255
    const float4* xr = (const float4*)(x + (size_t)row * D_MODEL);
    float4 v = xr[t];
    float s  = v.x + v.y + v.z + v.w;
    float sq = v.x * v.x + v.y * v.y + v.z * v.z + v.w * v.w;
#pragma unroll
    for (int off = 32; off > 0; off >>= 1) {
        s  += __shfl_xor(s, off);
        sq += __shfl_xor(sq, off);
    }
    __shared__ float ss[4], ssq[4];
    int wave = t >> 6;
    if ((t & 63) == 0) { ss[wave] = s; ssq[wave] = sq; }
    __syncthreads();
    s  = ss[0] + ss[1] + ss[2] + ss[3];
    sq = ssq[0] + ssq[1] + ssq[2] + ssq[3];
    float mu  = s * (1.0f / D_MODEL);
    float var = sq * (1.0f / D_MODEL) - mu * mu;
    float inv = rsqrtf(var + eps);
    float4 wv = ((const float4*)w)[t];
    float4 bv = ((const float4*)b)[t];
    float4 o;
    o.x = (v.x - mu) * inv * wv.x + bv.x;
    o.y = (v.y - mu) * inv * wv.y + bv.y;
    o.z = (v.z - mu) * inv * wv.z + bv.z;
    o.w = (v.w - mu) * inv * wv.w + bv.w;
    ((float4*)(out + (size_t)row * D_MODEL))[t] = o;
}

// ---------------------------------------------------------------------------
// SGEMM: C[M,N] = alpha*(A[M,K] @ B[K,N]) (+bias[N]) (+R[M,N])
// 64x64 block tile, BK=16, 256 threads, 4x4 per thread.
// BF16OUT: C is stored as bf16 (short*), else fp32 (float*).
// ---------------------------------------------------------------------------
template<bool BIAS, bool RES, bool BF16OUT>
__global__ void sgemm_kernel(const float* __restrict__ A, int lda,
                             const float* __restrict__ B, int ldb,
                             const float* __restrict__ bias,
                             const float* __restrict__ R, int ldr,
                             void* __restrict__ Cv, int ldc,
                             int M, int N, int K, float alpha)
{
    __shared__ float As[16][68];   // As[k][m]
    __shared__ float Bs[16][68];   // Bs[k][n]
    int bm = blockIdx.y * 64;
    int bn = blockIdx.x * 64;
    int tid = threadIdx.x;
    int tr = (tid >> 4) << 2;
    int tc = (tid & 15) << 2;
    int am = tid >> 2;
    int ak = (tid & 3) << 2;
    int bk = tid >> 4;
    int bc = (tid & 15) << 2;
    float acc[4][4] = {};
    for (int k0 = 0; k0 < K; k0 += 16) {
        const float* Arow = A + (size_t)(bm + am) * lda + k0 + ak;
#pragma unroll
        for (int i = 0; i < 4; ++i)
            As[ak + i][am] = (k0 + ak + i < K) ? Arow[i] : 0.0f;
        {
            const float* Brow = B + (size_t)(k0 + bk) * ldb + bn + bc;
            bool kok = (k0 + bk) < K;
#pragma unroll
            for (int i = 0; i < 4; ++i)
                Bs[bk][bc + i] = (kok && (bn + bc + i < N)) ? Brow[i] : 0.0f;
        }
        __syncthreads();
#pragma unroll
        for (int kk = 0; kk < 16; ++kk) {
            float a0 = As[kk][tr], a1 = As[kk][tr + 1], a2 = As[kk][tr + 2], a3 = As[kk][tr + 3];
            float b0 = Bs[kk][tc], b1 = Bs[kk][tc + 1], b2 = Bs[kk][tc + 2], b3 = Bs[kk][tc + 3];
            acc[0][0] += a0 * b0; acc[0][1] += a0 * b1; acc[0][2] += a0 * b2; acc[0][3] += a0 * b3;
            acc[1][0] += a1 * b0; acc[1][1] += a1 * b1; acc[1][2] += a1 * b2; acc[1][3] += a1 * b3;
            acc[2][0] += a2 * b0; acc[2][1] += a2 * b1; acc[2][2] += a2 * b2; acc[2][3] += a2 * b3;
            acc[3][0] += a3 * b0; acc[3][1] += a3 * b1; acc[3][2] += a3 * b2; acc[3][3] += a3 * b3;
        }
        __syncthreads();
    }
#pragma unroll
    for (int i = 0; i < 4; ++i) {
        int m = bm + tr + i;
#pragma unroll
        for (int j = 0; j < 4; ++j) {
            int n = bn + tc + j;
            if (n < N) {
                float val = alpha * acc[i][j];
                if (BIAS) val += bias[n];
                if (RES)  val += R[(size_t)m * ldr + n];
                if (BF16OUT) ((short*)Cv)[(size_t)m * ldc + n] = f2bf(val);
                else         ((float*)Cv)[(size_t)m * ldc + n] = val;
            }
        }
    }
}

// ---------------------------------------------------------------------------
// MFMA retention: block = (64 q-rows, head h, batch b), 4 waves.
// Wave w owns q-rows [16w, 16w+16). Per 64-col k-tile:
//   scores = Q @ K^T (mfma 16x16x32 bf16), decay+mask elementwise,
//   P (bf16) -> wave-private LDS -> A-frags, out += P @ V (mfma).
// Final per-row groupnorm over d=64 (eps 1e-6), fp32 out.
// q/k/v are bf16 [NTOK][1024], col = h*64+d. ret is fp32 same layout.
// ---------------------------------------------------------------------------
#define LSTR 72   // LDS row stride in bf16 elements (144B, 16B-aligned)

__global__ __launch_bounds__(256) void retention_mfma(
        const short* __restrict__ q,
        const short* __restrict__ k,
        const short* __restrict__ v,
        float* __restrict__ ret)
{
    int qb = blockIdx.x;   // 0..31 (q tile)
    int h  = blockIdx.y;   // 0..15
    int b  = blockIdx.z;   // 0..1

    __shared__ short ks[64 * LSTR];       // K tile, [t][d]
    __shared__ short vt[64 * LSTR];       // V tile transposed, [d][t]
    __shared__ short ps[4][16 * LSTR];    // per-wave P tile, [s][t]

    int tid  = threadIdx.x;
    int wave = tid >> 6;
    int lane = tid & 63;
    int quad = lane >> 4;
    int l15  = lane & 15;

    float log2g = log1pf(-exp2f(-5.0f - (float)h)) * 1.4426950408889634f;
    size_t hbase = (size_t)b * SEQ * D_MODEL + (size_t)h * HDIM;
    int s0 = qb * 64;

    // Q A-fragments for the wave's 16 rows (2 k-steps of 32 over d)
    const short* qrow = q + hbase + (size_t)(s0 + wave * 16 + l15) * D_MODEL;
    bf16x8 qa0 = *(const bf16x8*)(qrow + quad * 8);
    bf16x8 qa1 = *(const bf16x8*)(qrow + 32 + quad * 8);

    f32x4 oacc[4];
#pragma unroll
    for (int i = 0; i < 4; ++i) oacc[i] = (f32x4){0.f, 0.f, 0.f, 0.f};

    for (int tb = 0; tb <= qb; ++tb) {
        __syncthreads();    // previous iteration's LDS readers done
        // stage K tile (row-major, coalesced 16B)
#pragma unroll
        for (int i = 0; i < 2; ++i) {
            int slot = tid + 256 * i;         // 0..511
            int row  = slot >> 3;             // 0..63
            int c8   = (slot & 7) * 8;        // 0..56
            *(uint4*)(&ks[row * LSTR + c8]) =
                *(const uint4*)(k + hbase + (size_t)(tb * 64 + row) * D_MODEL + c8);
        }
        // stage V transposed: coalesced 16B load, 8 scalar LDS writes
#pragma unroll
        for (int i = 0; i < 2; ++i) {
            int slot = tid + 256 * i;
            int row  = slot >> 3;
            int c8   = (slot & 7) * 8;
            uint4 raw = *(const uint4*)(v + hbase + (size_t)(tb * 64 + row) * D_MODEL + c8);
            const short* sp = (const short*)&raw;
#pragma unroll
            for (int j = 0; j < 8; ++j)
                vt[(c8 + j) * LSTR + row] = sp[j];
        }
        __syncthreads();

        // scores: 4 t-tiles x 2 k-steps
        f32x4 sacc[4];
#pragma unroll
        for (int i = 0; i < 4; ++i) sacc[i] = (f32x4){0.f, 0.f, 0.f, 0.f};
#pragma unroll
        for (int tile = 0; tile < 4; ++tile) {
            const short* kr = &ks[(tile * 16 + l15) * LSTR + quad * 8];
            bf16x8 kb0 = *(const bf16x8*)(kr);
            bf16x8 kb1 = *(const bf16x8*)(kr + 32);
            sacc[tile] = __builtin_amdgcn_mfma_f32_16x16x32_bf16(qa0, kb0, sacc[tile], 0, 0, 0);
            sacc[tile] = __builtin_amdgcn_mfma_f32_16x16x32_bf16(qa1, kb1, sacc[tile], 0, 0, 0);
        }
        // decay + mask + pack bf16 P into wave-private LDS
        int sbase = s0 + wave * 16 + quad * 4;   // + reg
#pragma unroll
        for (int tile = 0; tile < 4; ++tile) {
            int t = tb * 64 + tile * 16 + l15;
            float fb = (float)(sbase - t);
#pragma unroll
            for (int reg = 0; reg < 4; ++reg) {
                float delta = fb + (float)reg;
                float dec = (delta >= 0.0f) ? exp2f(delta * log2g) : 0.0f;
                ps[wave][(quad * 4 + reg) * LSTR + tile * 16 + l15] = f2bf(sacc[tile][reg] * dec);
            }
        }
        // PV: wave-private P, no barrier needed (in-wave LDS ordering)
#pragma unroll
        for (int ksi = 0; ksi < 2; ++ksi) {
            bf16x8 pa = *(const bf16x8*)(&ps[wave][l15 * LSTR + ksi * 32 + quad * 8]);
#pragma unroll
            for (int dt = 0; dt < 4; ++dt) {
                bf16x8 vb = *(const bf16x8*)(&vt[(dt * 16 + l15) * LSTR + ksi * 32 + quad * 8]);
                oacc[dt] = __builtin_amdgcn_mfma_f32_16x16x32_bf16(pa, vb, oacc[dt], 0, 0, 0);
            }
        }
    }

    // groupnorm over d=64 per s-row; row (quad,reg) spans 16 lanes x 4 dt
    float s1[4], s2[4];
#pragma unroll
    for (int reg = 0; reg < 4; ++reg) {
        float a = oacc[0][reg] + oacc[1][reg] + oacc[2][reg] + oacc[3][reg];
        float sq = oacc[0][reg] * oacc[0][reg] + oacc[1][reg] * oacc[1][reg]
                 + oacc[2][reg] * oacc[2][reg] + oacc[3][reg] * oacc[3][reg];
        s1[reg] = a; s2[reg] = sq;
    }
#pragma unroll
    for (int off = 1; off < 16; off <<= 1) {
#pragma unroll
        for (int reg = 0; reg < 4; ++reg) {
            s1[reg] += __shfl_xor(s1[reg], off);
            s2[reg] += __shfl_xor(s2[reg], off);
        }
    }
    float* obase = ret + ((size_t)b * SEQ + s0 + wave * 16 + quad * 4) * D_MODEL + h * HDIM;
#pragma unroll
    for (int reg = 0; reg < 4; ++reg) {
        float mu  = s1[reg] * (1.0f / 64.0f);
        float var = s2[reg] * (1.0f / 64.0f) - mu * mu;
        float inv = rsqrtf(var + 1e-6f);
        float* orow = obase + (size_t)reg * D_MODEL;
#pragma unroll
        for (int dt = 0; dt < 4; ++dt)
            orow[dt * 16 + l15] = (oacc[dt][reg] - mu) * inv;
    }
}

// ---------------------------------------------------------------------------
// gate: ret *= silu(g), elementwise, in-place
// ---------------------------------------------------------------------------
__global__ void gate_kernel(float* __restrict__ ret, const float* __restrict__ g, int n4)
{
    int idx = blockIdx.x * blockDim.x + threadIdx.x;
    if (idx < n4) {
        float4 rv = ((float4*)ret)[idx];
        float4 gv = ((const float4*)g)[idx];
        rv.x *= gv.x / (1.0f + expf(-gv.x));
        rv.y *= gv.y / (1.0f + expf(-gv.y));
        rv.z *= gv.z / (1.0f + expf(-gv.z));
        rv.w *= gv.w / (1.0f + expf(-gv.w));
        ((float4*)ret)[idx] = rv;
    }
}

// ---------------------------------------------------------------------------
// Fused SwiGLU-in GEMM: Hm[M, HID] = (A@W[:, :HID] + b[:HID]) *
//                                    silu(A@W[:, HID:] + b[HID:])
// ---------------------------------------------------------------------------
__global__ void mlp_in_kernel(const float* __restrict__ A,
                              const float* __restrict__ W,
                              const float* __restrict__ bias,
                              float* __restrict__ Hm,
                              int M, int K)
{
    __shared__ float As[16][68];
    __shared__ float Ba[16][68];
    __shared__ float Bb[16][68];
    int bm = blockIdx.y * 64;
    int bn = blockIdx.x * 64;
    int tid = threadIdx.x;
    int tr = (tid >> 4) << 2;
    int tc = (tid & 15) << 2;
    int am = tid >> 2;
    int ak = (tid & 3) << 2;
    int bk = tid >> 4;
    int bc = (tid & 15) << 2;
    float acca[4][4] = {};
    float accb[4][4] = {};
    for (int k0 = 0; k0 < K; k0 += 16) {
        const float* Arow = A + (size_t)(bm + am) * D_MODEL + k0 + ak;
#pragma unroll
        for (int i = 0; i < 4; ++i)
            As[ak + i][am] = Arow[i];
        {
            const float* Wrow = W + (size_t)(k0 + bk) * (2 * HID) + bn + bc;
#pragma unroll
            for (int i = 0; i < 4; ++i) {
                bool ok = (bn + bc + i) < HID;
                Ba[bk][bc + i] = ok ? Wrow[i] : 0.0f;
                Bb[bk][bc + i] = ok ? Wrow[HID + i] : 0.0f;
            }
        }
        __syncthreads();
#pragma unroll
        for (int kk = 0; kk < 16; ++kk) {
            float a0 = As[kk][tr], a1 = As[kk][tr + 1], a2 = As[kk][tr + 2], a3 = As[kk][tr + 3];
            float p0 = Ba[kk][tc], p1 = Ba[kk][tc + 1], p2 = Ba[kk][tc + 2], p3 = Ba[kk][tc + 3];
            float q0 = Bb[kk][tc], q1 = Bb[kk][tc + 1], q2 = Bb[kk][tc + 2], q3 = Bb[kk][tc + 3];
            acca[0][0] += a0 * p0; acca[0][1] += a0 * p1; acca[0][2] += a0 * p2; acca[0][3] += a0 * p3;
            acca[1][0] += a1 * p0; acca[1][1] += a1 * p1; acca[1][2] += a1 * p2; acca[1][3] += a1 * p3;
            acca[2][0] += a2 * p0; acca[2][1] += a2 * p1; acca[2][2] += a2 * p2; acca[2][3] += a2 * p3;
            acca[3][0] += a3 * p0; acca[3][1] += a3 * p1; acca[3][2] += a3 * p2; acca[3][3] += a3 * p3;
            accb[0][0] += a0 * q0; accb[0][1] += a0 * q1; accb[0][2] += a0 * q2; accb[0][3] += a0 * q3;
            accb[1][0] += a1 * q0; accb[1][1] += a1 * q1; accb[1][2] += a1 * q2; accb[1][3] += a1 * q3;
            accb[2][0] += a2 * q0; accb[2][1] += a2 * q1; accb[2][2] += a2 * q2; accb[2][3] += a2 * q3;
            accb[3][0] += a3 * q0; accb[3][1] += a3 * q1; accb[3][2] += a3 * q2; accb[3][3] += a3 * q3;
        }
        __syncthreads();
    }
#pragma unroll
    for (int i = 0; i < 4; ++i) {
        int m = bm + tr + i;
#pragma unroll
        for (int j = 0; j < 4; ++j) {
            int n = bn + tc + j;
            if (n < HID) {
                float a  = acca[i][j] + bias[n];
                float bb = accb[i][j] + bias[HID + n];
                Hm[(size_t)m * HID + n] = a * (bb / (1.0f + expf(-bb)));
            }
        }
    }
}

// ---------------------------------------------------------------------------
extern "C" void kernel_launch(void* const* d_in, const int* in_sizes, int n_in,
                              void* d_out, int out_size, void* d_ws, size_t ws_size,
                              hipStream_t stream)
{
    const float* x     = (const float*)d_in[0];
    const float* ln1w  = (const float*)d_in[1];
    const float* ln1b  = (const float*)d_in[2];
    const float* wq    = (const float*)d_in[3];
    const float* wk    = (const float*)d_in[4];
    const float* wv    = (const float*)d_in[5];
    const float* wg    = (const float*)d_in[6];
    const float* wo    = (const float*)d_in[7];
    const float* ln2w  = (const float*)d_in[8];
    const float* ln2b  = (const float*)d_in[9];
    const float* w_in  = (const float*)d_in[10];
    const float* b_in  = (const float*)d_in[11];
    const float* w_out = (const float*)d_in[12];
    const float* b_out = (const float*)d_in[13];
    float* out = (float*)d_out;
    char* base = (char*)d_ws;

    const size_t MB = 1u << 20;
    float* xn = (float*)(base);              // [0,16) MiB ; later LN2 out
    short* qb = (short*)(base + 16 * MB);    // [16,24) bf16
    short* kb = (short*)(base + 24 * MB);    // [24,32) bf16
    short* vb = (short*)(base + 32 * MB);    // [32,40) bf16
    float* gb = (float*)(base + 40 * MB);    // [40,56)
    float* rb = (float*)(base + 56 * MB);    // [56,72)
    float* hm = (float*)(base + 16 * MB);    // [16,~58.7) after retention path is dead
    float* y  = xn;

    dim3 g16(16, 64);           // N=1024 GEMMs
    const size_t T4 = (size_t)NTOK * D_MODEL;

    // LN1
    ln_kernel<<<NTOK, 256, 0, stream>>>(x, ln1w, ln1b, xn, 1e-5f);
    // q,k,v (bf16 out; q scaled by 0.125), g (fp32 out)
    sgemm_kernel<false, false, true ><<<g16, 256, 0, stream>>>(xn, D_MODEL, wq, D_MODEL, nullptr, nullptr, 0, qb, D_MODEL, NTOK, D_MODEL, D_MODEL, 0.125f);
    sgemm_kernel<false, false, true ><<<g16, 256, 0, stream>>>(xn, D_MODEL, wk, D_MODEL, nullptr, nullptr, 0, kb, D_MODEL, NTOK, D_MODEL, D_MODEL, 1.0f);
    sgemm_kernel<false, false, true ><<<g16, 256, 0, stream>>>(xn, D_MODEL, wv, D_MODEL, nullptr, nullptr, 0, vb, D_MODEL, NTOK, D_MODEL, D_MODEL, 1.0f);
    sgemm_kernel<false, false, false><<<g16, 256, 0, stream>>>(xn, D_MODEL, wg, D_MODEL, nullptr, nullptr, 0, gb, D_MODEL, NTOK, D_MODEL, D_MODEL, 1.0f);
    // MFMA retention + groupnorm
    retention_mfma<<<dim3(SEQ / 64, NHEAD, BATCH), 256, 0, stream>>>(qb, kb, vb, rb);
    // gate with silu(xn@wg)
    gate_kernel<<<(int)(T4 / 4 / 256), 256, 0, stream>>>(rb, gb, (int)(T4 / 4));
    // project + residual -> out holds x2
    sgemm_kernel<false, true, false><<<g16, 256, 0, stream>>>(rb, D_MODEL, wo, D_MODEL, nullptr, x, D_MODEL, out, D_MODEL, NTOK, D_MODEL, D_MODEL, 1.0f);
    // LN2
    ln_kernel<<<NTOK, 256, 0, stream>>>(out, ln2w, ln2b, y, 1e-5f);
    // fused w_in GEMM + SwiGLU
    mlp_in_kernel<<<dim3((HID + 63) / 64, NTOK / 64), 256, 0, stream>>>(y, w_in, b_in, hm, NTOK, D_MODEL);
    // w_out GEMM + bias + residual
    sgemm_kernel<true, true, false><<<g16, 256, 0, stream>>>(hm, HID, w_out, D_MODEL, b_out, out, D_MODEL, out, D_MODEL, NTOK, D_MODEL, HID, 1.0f);
}

// Round 3
// 577.632 us; speedup vs baseline: 11.2249x; 4.3006x over previous
//
#include <hip/hip_runtime.h>
#include <math.h>

#define D_MODEL 1024
#define NHEAD   16
#define HDIM    64
#define HID     2730
#define HID_PAD 2816          // 22 * 128
#define SEQ     2048
#define BATCH   2
#define NTOK    (BATCH * SEQ)   // 4096
#define QS      4096            // packed qkvg row stride (elements)

typedef __attribute__((ext_vector_type(8))) short bf16x8;
typedef __attribute__((ext_vector_type(4))) float f32x4;
typedef __attribute__((ext_vector_type(4))) short s16x4;

// fp32 -> bf16 round-to-nearest-even
static __device__ inline short f2bf(float f)
{
    union { float f; unsigned int u; } c; c.f = f;
    unsigned int r = c.u + 0x7FFFu + ((c.u >> 16) & 1u);
    return (short)(r >> 16);
}
static __device__ inline float bf2f(short s)
{
    union { unsigned int u; float f; } c;
    c.u = ((unsigned int)(unsigned short)s) << 16;
    return c.f;
}

// async global->LDS, 16B per lane; lds dest = wave-uniform base + lane*16
#define GLD16(gsrc, ldst) \
    __builtin_amdgcn_global_load_lds((const __attribute__((address_space(1))) void*)(gsrc), \
                                     (__attribute__((address_space(3))) void*)(ldst), 16, 0, 0)

// ---------------------------------------------------------------------------
// LayerNorm: one block (256 threads) per row of 1024, fp32 in -> bf16 out
// ---------------------------------------------------------------------------
__global__ void ln_kernel(const float* __restrict__ x,
                          const float* __restrict__ w,
                          const float* __restrict__ b,
                          short* __restrict__ out,
                          float eps)
{
    int row = blockIdx.x;
    int t = threadIdx.x;               // 0..255
    const float4* xr = (const float4*)(x + (size_t)row * D_MODEL);
    float4 v = xr[t];
    float s  = v.x + v.y + v.z + v.w;
    float sq = v.x * v.x + v.y * v.y + v.z * v.z + v.w * v.w;
#pragma unroll
    for (int off = 32; off > 0; off >>= 1) {
        s  += __shfl_xor(s, off);
        sq += __shfl_xor(sq, off);
    }
    __shared__ float ss[4], ssq[4];
    int wave = t >> 6;
    if ((t & 63) == 0) { ss[wave] = s; ssq[wave] = sq; }
    __syncthreads();
    s  = ss[0] + ss[1] + ss[2] + ss[3];
    sq = ssq[0] + ssq[1] + ssq[2] + ssq[3];
    float mu  = s * (1.0f / D_MODEL);
    float var = sq * (1.0f / D_MODEL) - mu * mu;
    float inv = rsqrtf(var + eps);
    float4 wv = ((const float4*)w)[t];
    float4 bv = ((const float4*)b)[t];
    s16x4 o;
    o.x = f2bf((v.x - mu) * inv * wv.x + bv.x);
    o.y = f2bf((v.y - mu) * inv * wv.y + bv.y);
    o.z = f2bf((v.z - mu) * inv * wv.z + bv.z);
    o.w = f2bf((v.w - mu) * inv * wv.w + bv.w);
    *(s16x4*)(out + (size_t)row * D_MODEL + 4 * t) = o;
}

// ---------------------------------------------------------------------------
// Transpose + cast: dst[n][k] (bf16, [NPAD][KPAD]) = src[k][coloff+n] (fp32)
// zero-padded outside (nvalid, kvalid). block (32,8), grid (KPAD/32, NPAD/32)
// ---------------------------------------------------------------------------
__global__ void transpose_f2b(const float* __restrict__ src, int ldsrc, int coloff,
                              int nvalid, int kvalid, int KPAD,
                              short* __restrict__ dst)
{
    __shared__ float tile[32][33];
    int k0 = blockIdx.x * 32, n0 = blockIdx.y * 32;
    int tx = threadIdx.x, ty = threadIdx.y;
#pragma unroll
    for (int i = 0; i < 32; i += 8) {
        int k = k0 + ty + i, n = n0 + tx;
        tile[ty + i][tx] = (k < kvalid && n < nvalid) ? src[(size_t)k * ldsrc + coloff + n] : 0.0f;
    }
    __syncthreads();
#pragma unroll
    for (int i = 0; i < 32; i += 8) {
        int n = n0 + ty + i, k = k0 + tx;
        dst[(size_t)n * KPAD + k] = f2bf(tile[tx][ty + i]);
    }
}

// ---------------------------------------------------------------------------
// bf16 MFMA GEMM (m97 structure): C[M,N] = A[M,K] @ Bt[N,K]^T (+bias)(+R)
// 128x128 tile, BK=32, 256 threads = 4 waves in 2x2, each 64x64 (4x4 MFMA).
// EPI: 0 = bf16 store; 1 = fp32 + R; 2 = fp32 + bias + R
// M,N from grid; K, lda multiples of 32; M,N multiples of 128.
// ---------------------------------------------------------------------------
template<int EPI>
__global__ __launch_bounds__(256) void gemm_bt(
        const short* __restrict__ A, int lda,
        const short* __restrict__ Bt,
        const float* __restrict__ bias,
        const float* __restrict__ R, int ldr,
        void* __restrict__ C, int ldc, int K)
{
    __shared__ short As[128 * 32];
    __shared__ short Bs[128 * 32];
    int bm = blockIdx.y * 128;
    int bn = blockIdx.x * 128;
    int t = threadIdx.x;
    int w = t >> 6;
    int lane = t & 63;
    int quad = lane >> 4;
    int l15  = lane & 15;

    // staging addresses: round r covers rows r*64 + t/4, cols (t&3)*8
    const short* gA0 = A  + (size_t)(bm + (t >> 2)) * lda + ((t & 3) << 3);
    const short* gA1 = gA0 + (size_t)64 * lda;
    const short* gB0 = Bt + (size_t)(bn + (t >> 2)) * K + ((t & 3) << 3);
    const short* gB1 = gB0 + (size_t)64 * K;
    short* lA0 = As + (w << 9);            // wave base, round 0
    short* lA1 = As + 2048 + (w << 9);
    short* lB0 = Bs + (w << 9);
    short* lB1 = Bs + 2048 + (w << 9);

    int wr = (w >> 1) * 64;
    int wc = (w & 1) * 64;

    f32x4 acc[4][4];
#pragma unroll
    for (int i = 0; i < 4; ++i)
#pragma unroll
        for (int j = 0; j < 4; ++j) acc[i][j] = (f32x4){0.f, 0.f, 0.f, 0.f};

    for (int k0 = 0; k0 < K; k0 += 32) {
        GLD16(gA0 + k0, lA0);
        GLD16(gA1 + k0, lA1);
        GLD16(gB0 + k0, lB0);
        GLD16(gB1 + k0, lB1);
        __syncthreads();
        bf16x8 af[4], bfr[4];
#pragma unroll
        for (int i = 0; i < 4; ++i)
            af[i] = *(const bf16x8*)(As + (wr + i * 16 + l15) * 32 + quad * 8);
#pragma unroll
        for (int j = 0; j < 4; ++j)
            bfr[j] = *(const bf16x8*)(Bs + (wc + j * 16 + l15) * 32 + quad * 8);
#pragma unroll
        for (int i = 0; i < 4; ++i)
#pragma unroll
            for (int j = 0; j < 4; ++j)
                acc[i][j] = __builtin_amdgcn_mfma_f32_16x16x32_bf16(af[i], bfr[j], acc[i][j], 0, 0, 0);
        __syncthreads();
    }

#pragma unroll
    for (int i = 0; i < 4; ++i) {
        int gr = bm + wr + i * 16 + quad * 4;
#pragma unroll
        for (int j = 0; j < 4; ++j) {
            int gc = bn + wc + j * 16 + l15;
#pragma unroll
            for (int r = 0; r < 4; ++r) {
                float val = acc[i][j][r];
                size_t idx = (size_t)(gr + r) * ldc + gc;
                if (EPI == 0) {
                    ((short*)C)[idx] = f2bf(val);
                } else if (EPI == 1) {
                    ((float*)C)[idx] = val + R[(size_t)(gr + r) * ldr + gc];
                } else {
                    ((float*)C)[idx] = val + bias[gc] + R[(size_t)(gr + r) * ldr + gc];
                }
            }
        }
    }
}

// ---------------------------------------------------------------------------
// Fused SwiGLU-in GEMM (MFMA): hm[M][HID_PAD] =
//   (A @ Wa^T + ba) * silu(A @ Wb^T + bb),  Wa = w_inT[0..], Wb = w_inT[HID_PAD..]
// ---------------------------------------------------------------------------
__global__ __launch_bounds__(256) void mlp_fused(
        const short* __restrict__ A,       // [NTOK][1024] bf16
        const short* __restrict__ w_inT,   // [2*HID_PAD][1024] bf16
        const float* __restrict__ b_in,    // [2*HID]
        short* __restrict__ hm)            // [NTOK][HID_PAD] bf16
{
    __shared__ short As[128 * 32];
    __shared__ short Ba[128 * 32];
    __shared__ short Bb[128 * 32];
    const int K = D_MODEL;
    int bm = blockIdx.y * 128;
    int bn = blockIdx.x * 128;
    int t = threadIdx.x;
    int w = t >> 6;
    int lane = t & 63;
    int quad = lane >> 4;
    int l15  = lane & 15;

    const short* gA0 = A + (size_t)(bm + (t >> 2)) * K + ((t & 3) << 3);
    const short* gA1 = gA0 + (size_t)64 * K;
    const short* gBa0 = w_inT + (size_t)(bn + (t >> 2)) * K + ((t & 3) << 3);
    const short* gBa1 = gBa0 + (size_t)64 * K;
    const short* gBb0 = gBa0 + (size_t)HID_PAD * K;
    const short* gBb1 = gBa1 + (size_t)HID_PAD * K;
    short* lA0 = As + (w << 9);
    short* lA1 = As + 2048 + (w << 9);
    short* la0 = Ba + (w << 9);
    short* la1 = Ba + 2048 + (w << 9);
    short* lb0 = Bb + (w << 9);
    short* lb1 = Bb + 2048 + (w << 9);

    int wr = (w >> 1) * 64;
    int wc = (w & 1) * 64;

    f32x4 acca[4][4], accb[4][4];
#pragma unroll
    for (int i = 0; i < 4; ++i)
#pragma unroll
        for (int j = 0; j < 4; ++j) {
            acca[i][j] = (f32x4){0.f, 0.f, 0.f, 0.f};
            accb[i][j] = (f32x4){0.f, 0.f, 0.f, 0.f};
        }

    for (int k0 = 0; k0 < K; k0 += 32) {
        GLD16(gA0 + k0, lA0);
        GLD16(gA1 + k0, lA1);
        GLD16(gBa0 + k0, la0);
        GLD16(gBa1 + k0, la1);
        GLD16(gBb0 + k0, lb0);
        GLD16(gBb1 + k0, lb1);
        __syncthreads();
        bf16x8 af[4], baf[4], bbf[4];
#pragma unroll
        for (int i = 0; i < 4; ++i)
            af[i] = *(const bf16x8*)(As + (wr + i * 16 + l15) * 32 + quad * 8);
#pragma unroll
        for (int j = 0; j < 4; ++j) {
            baf[j] = *(const bf16x8*)(Ba + (wc + j * 16 + l15) * 32 + quad * 8);
            bbf[j] = *(const bf16x8*)(Bb + (wc + j * 16 + l15) * 32 + quad * 8);
        }
#pragma unroll
        for (int i = 0; i < 4; ++i)
#pragma unroll
            for (int j = 0; j < 4; ++j) {
                acca[i][j] = __builtin_amdgcn_mfma_f32_16x16x32_bf16(af[i], baf[j], acca[i][j], 0, 0, 0);
                accb[i][j] = __builtin_amdgcn_mfma_f32_16x16x32_bf16(af[i], bbf[j], accb[i][j], 0, 0, 0);
            }
        __syncthreads();
    }

#pragma unroll
    for (int i = 0; i < 4; ++i) {
        int gr = bm + wr + i * 16 + quad * 4;
#pragma unroll
        for (int j = 0; j < 4; ++j) {
            int gc = bn + wc + j * 16 + l15;      // n in [0, HID_PAD)
            bool ok = gc < HID;
            float ba = ok ? b_in[gc] : 0.0f;
            float bb = ok ? b_in[HID + gc] : 0.0f;
#pragma unroll
            for (int r = 0; r < 4; ++r) {
                float a  = acca[i][j][r] + ba;
                float bv = accb[i][j][r] + bb;
                float val = ok ? a * (bv / (1.0f + expf(-bv))) : 0.0f;
                hm[(size_t)(gr + r) * HID_PAD + gc] = f2bf(val);
            }
        }
    }
}

// ---------------------------------------------------------------------------
// MFMA retention + groupnorm + silu gate, packed qkvg input.
// qkvg: [NTOK][4096] bf16, cols [0,1024)=q, [1024,2048)=k, [2048,3072)=v,
// [3072,4096)=g. Output rg: [NTOK][1024] bf16 = groupnorm(out) * silu(g).
// ---------------------------------------------------------------------------
#define LSTR 72   // LDS row stride in bf16 elements

__global__ __launch_bounds__(256) void retention_mfma(
        const short* __restrict__ qkvg,
        short* __restrict__ rg)
{
    int qb = blockIdx.x;   // 0..31 (q tile)
    int h  = blockIdx.y;   // 0..15
    int b  = blockIdx.z;   // 0..1

    __shared__ short ks[64 * LSTR];       // K tile, [t][d]
    __shared__ short vt[64 * LSTR];       // V tile transposed, [d][t]
    __shared__ short ps[4][16 * LSTR];    // per-wave P tile, [s][t]

    int tid  = threadIdx.x;
    int wave = tid >> 6;
    int lane = tid & 63;
    int quad = lane >> 4;
    int l15  = lane & 15;

    float log2g = log1pf(-exp2f(-5.0f - (float)h)) * 1.4426950408889634f;
    int hcol = h * HDIM;
    int s0 = qb * 64;
    size_t tok0 = (size_t)b * SEQ;

    // Q A-fragments for the wave's 16 rows
    const short* qrow = qkvg + (tok0 + s0 + wave * 16 + l15) * QS + hcol;
    bf16x8 qa0 = *(const bf16x8*)(qrow + quad * 8);
    bf16x8 qa1 = *(const bf16x8*)(qrow + 32 + quad * 8);

    f32x4 oacc[4];
#pragma unroll
    for (int i = 0; i < 4; ++i) oacc[i] = (f32x4){0.f, 0.f, 0.f, 0.f};

    for (int tb = 0; tb <= qb; ++tb) {
        __syncthreads();
        // stage K tile (row-major) and V tile (transposed)
#pragma unroll
        for (int i = 0; i < 2; ++i) {
            int slot = tid + 256 * i;
            int row  = slot >> 3;
            int c8   = (slot & 7) * 8;
            size_t gbase = (tok0 + tb * 64 + row) * QS + hcol + c8;
            *(uint4*)(&ks[row * LSTR + c8]) = *(const uint4*)(qkvg + gbase + 1024);
            uint4 raw = *(const uint4*)(qkvg + gbase + 2048);
            const short* sp = (const short*)&raw;
#pragma unroll
            for (int j = 0; j < 8; ++j)
                vt[(c8 + j) * LSTR + row] = sp[j];
        }
        __syncthreads();

        // scores
        f32x4 sacc[4];
#pragma unroll
        for (int i = 0; i < 4; ++i) sacc[i] = (f32x4){0.f, 0.f, 0.f, 0.f};
#pragma unroll
        for (int tile = 0; tile < 4; ++tile) {
            const short* kr = &ks[(tile * 16 + l15) * LSTR + quad * 8];
            bf16x8 kb0 = *(const bf16x8*)(kr);
            bf16x8 kb1 = *(const bf16x8*)(kr + 32);
            sacc[tile] = __builtin_amdgcn_mfma_f32_16x16x32_bf16(qa0, kb0, sacc[tile], 0, 0, 0);
            sacc[tile] = __builtin_amdgcn_mfma_f32_16x16x32_bf16(qa1, kb1, sacc[tile], 0, 0, 0);
        }
        // scale (q * HDIM^-0.5) + decay + mask -> bf16 P
        int sbase = s0 + wave * 16 + quad * 4;
#pragma unroll
        for (int tile = 0; tile < 4; ++tile) {
            int tt = tb * 64 + tile * 16 + l15;
            float fb = (float)(sbase - tt);
#pragma unroll
            for (int reg = 0; reg < 4; ++reg) {
                float delta = fb + (float)reg;
                float dec = (delta >= 0.0f) ? exp2f(delta * log2g) : 0.0f;
                ps[wave][(quad * 4 + reg) * LSTR + tile * 16 + l15] = f2bf(sacc[tile][reg] * 0.125f * dec);
            }
        }
        // PV (wave-private P, no barrier needed)
#pragma unroll
        for (int ksi = 0; ksi < 2; ++ksi) {
            bf16x8 pa = *(const bf16x8*)(&ps[wave][l15 * LSTR + ksi * 32 + quad * 8]);
#pragma unroll
            for (int dt = 0; dt < 4; ++dt) {
                bf16x8 vb = *(const bf16x8*)(&vt[(dt * 16 + l15) * LSTR + ksi * 32 + quad * 8]);
                oacc[dt] = __builtin_amdgcn_mfma_f32_16x16x32_bf16(pa, vb, oacc[dt], 0, 0, 0);
            }
        }
    }

    // groupnorm over d=64 per s-row
    float s1[4], s2[4];
#pragma unroll
    for (int reg = 0; reg < 4; ++reg) {
        s1[reg] = oacc[0][reg] + oacc[1][reg] + oacc[2][reg] + oacc[3][reg];
        s2[reg] = oacc[0][reg] * oacc[0][reg] + oacc[1][reg] * oacc[1][reg]
                + oacc[2][reg] * oacc[2][reg] + oacc[3][reg] * oacc[3][reg];
    }
#pragma unroll
    for (int off = 1; off < 16; off <<= 1) {
#pragma unroll
        for (int reg = 0; reg < 4; ++reg) {
            s1[reg] += __shfl_xor(s1[reg], off);
            s2[reg] += __shfl_xor(s2[reg], off);
        }
    }
    size_t rowtok = tok0 + s0 + wave * 16 + quad * 4;
    short* obase = rg + rowtok * D_MODEL + hcol;
    const short* gbase = qkvg + rowtok * QS + 3072 + hcol;
#pragma unroll
    for (int reg = 0; reg < 4; ++reg) {
        float mu  = s1[reg] * (1.0f / 64.0f);
        float var = s2[reg] * (1.0f / 64.0f) - mu * mu;
        float inv = rsqrtf(var + 1e-6f);
#pragma unroll
        for (int dt = 0; dt < 4; ++dt) {
            float gv = bf2f(gbase[(size_t)reg * QS + dt * 16 + l15]);
            float val = (oacc[dt][reg] - mu) * inv * (gv / (1.0f + expf(-gv)));
            obase[(size_t)reg * D_MODEL + dt * 16 + l15] = f2bf(val);
        }
    }
}

// ---------------------------------------------------------------------------
extern "C" void kernel_launch(void* const* d_in, const int* in_sizes, int n_in,
                              void* d_out, int out_size, void* d_ws, size_t ws_size,
                              hipStream_t stream)
{
    const float* x     = (const float*)d_in[0];
    const float* ln1w  = (const float*)d_in[1];
    const float* ln1b  = (const float*)d_in[2];
    const float* wq    = (const float*)d_in[3];
    const float* wk    = (const float*)d_in[4];
    const float* wv    = (const float*)d_in[5];
    const float* wg    = (const float*)d_in[6];
    const float* wo    = (const float*)d_in[7];
    const float* ln2w  = (const float*)d_in[8];
    const float* ln2b  = (const float*)d_in[9];
    const float* w_in  = (const float*)d_in[10];
    const float* b_in  = (const float*)d_in[11];
    const float* w_out = (const float*)d_in[12];
    const float* b_out = (const float*)d_in[13];
    float* out = (float*)d_out;
    char* base = (char*)d_ws;

    const size_t MB = 1u << 20;
    short* xn     = (short*)(base);            // [0,8)   [4096][1024] bf16 (LN1 out; later LN2 out)
    short* qkvgT  = (short*)(base +  8 * MB);  // [8,16)  [4096][1024] wq/wk/wv/wg transposed, stacked
    short* woT    = (short*)(base + 16 * MB);  // [16,18) [1024][1024]
    short* w_inT  = (short*)(base + 18 * MB);  // [18,29) [5632][1024] (a rows 0..2815, b rows 2816..)
    short* w_outT = (short*)(base + 29 * MB);  // [29,34.5) [1024][2816] (K zero-padded)
    short* qkvg   = (short*)(base + 35 * MB);  // [35,67) [4096][4096] packed q|k|v|g
    short* hm     = (short*)(base + 35 * MB);  // [35,57) [4096][2816] (reuses dead qkvg)
    short* rg     = (short*)(base + 67 * MB);  // [67,75) [4096][1024] gated retention out

    dim3 tb(32, 8);
    // weight transposes (fp32 -> bf16, [N][K], zero-padded)
    transpose_f2b<<<dim3(32, 32), tb, 0, stream>>>(wq, 1024, 0, 1024, 1024, 1024, qkvgT);
    transpose_f2b<<<dim3(32, 32), tb, 0, stream>>>(wk, 1024, 0, 1024, 1024, 1024, qkvgT + 1024 * 1024);
    transpose_f2b<<<dim3(32, 32), tb, 0, stream>>>(wv, 1024, 0, 1024, 1024, 1024, qkvgT + 2 * 1024 * 1024);
    transpose_f2b<<<dim3(32, 32), tb, 0, stream>>>(wg, 1024, 0, 1024, 1024, 1024, qkvgT + 3 * 1024 * 1024);
    transpose_f2b<<<dim3(32, 32), tb, 0, stream>>>(wo, 1024, 0, 1024, 1024, 1024, woT);
    transpose_f2b<<<dim3(32, 88), tb, 0, stream>>>(w_in, 2 * HID, 0,   HID, 1024, 1024, w_inT);
    transpose_f2b<<<dim3(32, 88), tb, 0, stream>>>(w_in, 2 * HID, HID, HID, 1024, 1024, w_inT + (size_t)HID_PAD * 1024);
    transpose_f2b<<<dim3(88, 32), tb, 0, stream>>>(w_out, 1024, 0, 1024, HID, HID_PAD, w_outT);

    // LN1 -> bf16
    ln_kernel<<<NTOK, 256, 0, stream>>>(x, ln1w, ln1b, xn, 1e-5f);
    // fused q|k|v|g projection: [4096,1024] @ [1024,4096] -> [4096][4096] bf16
    gemm_bt<0><<<dim3(32, 32), 256, 0, stream>>>(xn, D_MODEL, qkvgT, nullptr, nullptr, 0, qkvg, QS, D_MODEL);
    // retention + groupnorm + silu gate -> rg bf16
    retention_mfma<<<dim3(SEQ / 64, NHEAD, BATCH), 256, 0, stream>>>(qkvg, rg);
    // wo projection + residual x -> out (fp32)
    gemm_bt<1><<<dim3(8, 32), 256, 0, stream>>>(rg, D_MODEL, woT, nullptr, x, D_MODEL, out, D_MODEL, D_MODEL);
    // LN2 -> bf16 (reuse xn)
    ln_kernel<<<NTOK, 256, 0, stream>>>(out, ln2w, ln2b, xn, 1e-5f);
    // fused SwiGLU-in GEMM -> hm bf16 [4096][2816]
    mlp_fused<<<dim3(HID_PAD / 128, 32), 256, 0, stream>>>(xn, w_inT, b_in, hm);
    // w_out GEMM + bias + residual -> out (fp32, in-place residual)
    gemm_bt<2><<<dim3(8, 32), 256, 0, stream>>>(hm, HID_PAD, w_outT, b_out, out, D_MODEL, out, D_MODEL, HID_PAD);
}

// Round 4
// 541.445 us; speedup vs baseline: 11.9751x; 1.0668x over previous
//
#include <hip/hip_runtime.h>
#include <math.h>

#define D_MODEL 1024
#define NHEAD   16
#define HDIM    64
#define HID     2730
#define HID_PAD 2816          // 22 * 128
#define SEQ     2048
#define BATCH   2
#define NTOK    (BATCH * SEQ)   // 4096
#define QKG     3072            // packed q|k|g row stride (elements)

typedef __attribute__((ext_vector_type(8))) short bf16x8;
typedef __attribute__((ext_vector_type(4))) float f32x4;
typedef __attribute__((ext_vector_type(4))) short s16x4;

// fp32 -> bf16 round-to-nearest-even
static __device__ inline short f2bf(float f)
{
    union { float f; unsigned int u; } c; c.f = f;
    unsigned int r = c.u + 0x7FFFu + ((c.u >> 16) & 1u);
    return (short)(r >> 16);
}
static __device__ inline float bf2f(short s)
{
    union { unsigned int u; float f; } c;
    c.u = ((unsigned int)(unsigned short)s) << 16;
    return c.f;
}

// async global->LDS, 16B per lane; lds dest = wave-uniform base + lane*16
#define GLD16(gsrc, ldst) \
    __builtin_amdgcn_global_load_lds((const __attribute__((address_space(1))) void*)(gsrc), \
                                     (__attribute__((address_space(3))) void*)(ldst), 16, 0, 0)

// ---------------------------------------------------------------------------
// LayerNorm: one block (256 threads) per row of 1024, fp32 in -> bf16 out
// ---------------------------------------------------------------------------
__global__ void ln_kernel(const float* __restrict__ x,
                          const float* __restrict__ w,
                          const float* __restrict__ b,
                          short* __restrict__ out,
                          float eps)
{
    int row = blockIdx.x;
    int t = threadIdx.x;               // 0..255
    const float4* xr = (const float4*)(x + (size_t)row * D_MODEL);
    float4 v = xr[t];
    float s  = v.x + v.y + v.z + v.w;
    float sq = v.x * v.x + v.y * v.y + v.z * v.z + v.w * v.w;
#pragma unroll
    for (int off = 32; off > 0; off >>= 1) {
        s  += __shfl_xor(s, off);
        sq += __shfl_xor(sq, off);
    }
    __shared__ float ss[4], ssq[4];
    int wave = t >> 6;
    if ((t & 63) == 0) { ss[wave] = s; ssq[wave] = sq; }
    __syncthreads();
    s  = ss[0] + ss[1] + ss[2] + ss[3];
    sq = ssq[0] + ssq[1] + ssq[2] + ssq[3];
    float mu  = s * (1.0f / D_MODEL);
    float var = sq * (1.0f / D_MODEL) - mu * mu;
    float inv = rsqrtf(var + eps);
    float4 wv = ((const float4*)w)[t];
    float4 bv = ((const float4*)b)[t];
    s16x4 o;
    o.x = f2bf((v.x - mu) * inv * wv.x + bv.x);
    o.y = f2bf((v.y - mu) * inv * wv.y + bv.y);
    o.z = f2bf((v.z - mu) * inv * wv.z + bv.z);
    o.w = f2bf((v.w - mu) * inv * wv.w + bv.w);
    *(s16x4*)(out + (size_t)row * D_MODEL + 4 * t) = o;
}

// ---------------------------------------------------------------------------
// Transpose + cast: dst[n][k] (bf16, [NPAD][KPAD]) = src[k][coloff+n] (fp32)
// ---------------------------------------------------------------------------
__global__ void transpose_f2b(const float* __restrict__ src, int ldsrc, int coloff,
                              int nvalid, int kvalid, int KPAD,
                              short* __restrict__ dst)
{
    __shared__ float tile[32][33];
    int k0 = blockIdx.x * 32, n0 = blockIdx.y * 32;
    int tx = threadIdx.x, ty = threadIdx.y;
#pragma unroll
    for (int i = 0; i < 32; i += 8) {
        int k = k0 + ty + i, n = n0 + tx;
        tile[ty + i][tx] = (k < kvalid && n < nvalid) ? src[(size_t)k * ldsrc + coloff + n] : 0.0f;
    }
    __syncthreads();
#pragma unroll
    for (int i = 0; i < 32; i += 8) {
        int n = n0 + ty + i, k = k0 + tx;
        dst[(size_t)n * KPAD + k] = f2bf(tile[tx][ty + i]);
    }
}

// ---------------------------------------------------------------------------
// bf16 MFMA GEMM (m97 structure): C[M,N] = A[M,K] @ Bt[N,K]^T (+bias)(+R)
// 128x128 tile, BK=32, 256 threads = 4 waves in 2x2, each 64x64 (4x4 MFMA).
// EPI: 0 = bf16 store; 1 = fp32 + R; 2 = fp32 + bias + R
// ---------------------------------------------------------------------------
template<int EPI>
__global__ __launch_bounds__(256) void gemm_bt(
        const short* __restrict__ A, int lda,
        const short* __restrict__ Bt,
        const float* __restrict__ bias,
        const float* __restrict__ R, int ldr,
        void* __restrict__ C, int ldc, int K)
{
    __shared__ short As[128 * 32];
    __shared__ short Bs[128 * 32];
    int bm = blockIdx.y * 128;
    int bn = blockIdx.x * 128;
    int t = threadIdx.x;
    int w = t >> 6;
    int lane = t & 63;
    int quad = lane >> 4;
    int l15  = lane & 15;

    const short* gA0 = A  + (size_t)(bm + (t >> 2)) * lda + ((t & 3) << 3);
    const short* gA1 = gA0 + (size_t)64 * lda;
    const short* gB0 = Bt + (size_t)(bn + (t >> 2)) * K + ((t & 3) << 3);
    const short* gB1 = gB0 + (size_t)64 * K;
    short* lA0 = As + (w << 9);
    short* lA1 = As + 2048 + (w << 9);
    short* lB0 = Bs + (w << 9);
    short* lB1 = Bs + 2048 + (w << 9);

    int wr = (w >> 1) * 64;
    int wc = (w & 1) * 64;

    f32x4 acc[4][4];
#pragma unroll
    for (int i = 0; i < 4; ++i)
#pragma unroll
        for (int j = 0; j < 4; ++j) acc[i][j] = (f32x4){0.f, 0.f, 0.f, 0.f};

    for (int k0 = 0; k0 < K; k0 += 32) {
        GLD16(gA0 + k0, lA0);
        GLD16(gA1 + k0, lA1);
        GLD16(gB0 + k0, lB0);
        GLD16(gB1 + k0, lB1);
        __syncthreads();
        bf16x8 af[4], bfr[4];
#pragma unroll
        for (int i = 0; i < 4; ++i)
            af[i] = *(const bf16x8*)(As + (wr + i * 16 + l15) * 32 + quad * 8);
#pragma unroll
        for (int j = 0; j < 4; ++j)
            bfr[j] = *(const bf16x8*)(Bs + (wc + j * 16 + l15) * 32 + quad * 8);
#pragma unroll
        for (int i = 0; i < 4; ++i)
#pragma unroll
            for (int j = 0; j < 4; ++j)
                acc[i][j] = __builtin_amdgcn_mfma_f32_16x16x32_bf16(af[i], bfr[j], acc[i][j], 0, 0, 0);
        __syncthreads();
    }

#pragma unroll
    for (int i = 0; i < 4; ++i) {
        int gr = bm + wr + i * 16 + quad * 4;
#pragma unroll
        for (int j = 0; j < 4; ++j) {
            int gc = bn + wc + j * 16 + l15;
#pragma unroll
            for (int r = 0; r < 4; ++r) {
                float val = acc[i][j][r];
                size_t idx = (size_t)(gr + r) * ldc + gc;
                if (EPI == 0) {
                    ((short*)C)[idx] = f2bf(val);
                } else if (EPI == 1) {
                    ((float*)C)[idx] = val + R[(size_t)(gr + r) * ldr + gc];
                } else {
                    ((float*)C)[idx] = val + bias[gc] + R[(size_t)(gr + r) * ldr + gc];
                }
            }
        }
    }
}

// ---------------------------------------------------------------------------
// Fused SwiGLU-in GEMM (MFMA)
// ---------------------------------------------------------------------------
__global__ __launch_bounds__(256) void mlp_fused(
        const short* __restrict__ A,       // [NTOK][1024] bf16
        const short* __restrict__ w_inT,   // [2*HID_PAD][1024] bf16
        const float* __restrict__ b_in,    // [2*HID]
        short* __restrict__ hm)            // [NTOK][HID_PAD] bf16
{
    __shared__ short As[128 * 32];
    __shared__ short Ba[128 * 32];
    __shared__ short Bb[128 * 32];
    const int K = D_MODEL;
    int bm = blockIdx.y * 128;
    int bn = blockIdx.x * 128;
    int t = threadIdx.x;
    int w = t >> 6;
    int lane = t & 63;
    int quad = lane >> 4;
    int l15  = lane & 15;

    const short* gA0 = A + (size_t)(bm + (t >> 2)) * K + ((t & 3) << 3);
    const short* gA1 = gA0 + (size_t)64 * K;
    const short* gBa0 = w_inT + (size_t)(bn + (t >> 2)) * K + ((t & 3) << 3);
    const short* gBa1 = gBa0 + (size_t)64 * K;
    const short* gBb0 = gBa0 + (size_t)HID_PAD * K;
    const short* gBb1 = gBa1 + (size_t)HID_PAD * K;
    short* lA0 = As + (w << 9);
    short* lA1 = As + 2048 + (w << 9);
    short* la0 = Ba + (w << 9);
    short* la1 = Ba + 2048 + (w << 9);
    short* lb0 = Bb + (w << 9);
    short* lb1 = Bb + 2048 + (w << 9);

    int wr = (w >> 1) * 64;
    int wc = (w & 1) * 64;

    f32x4 acca[4][4], accb[4][4];
#pragma unroll
    for (int i = 0; i < 4; ++i)
#pragma unroll
        for (int j = 0; j < 4; ++j) {
            acca[i][j] = (f32x4){0.f, 0.f, 0.f, 0.f};
            accb[i][j] = (f32x4){0.f, 0.f, 0.f, 0.f};
        }

    for (int k0 = 0; k0 < K; k0 += 32) {
        GLD16(gA0 + k0, lA0);
        GLD16(gA1 + k0, lA1);
        GLD16(gBa0 + k0, la0);
        GLD16(gBa1 + k0, la1);
        GLD16(gBb0 + k0, lb0);
        GLD16(gBb1 + k0, lb1);
        __syncthreads();
        bf16x8 af[4], baf[4], bbf[4];
#pragma unroll
        for (int i = 0; i < 4; ++i)
            af[i] = *(const bf16x8*)(As + (wr + i * 16 + l15) * 32 + quad * 8);
#pragma unroll
        for (int j = 0; j < 4; ++j) {
            baf[j] = *(const bf16x8*)(Ba + (wc + j * 16 + l15) * 32 + quad * 8);
            bbf[j] = *(const bf16x8*)(Bb + (wc + j * 16 + l15) * 32 + quad * 8);
        }
#pragma unroll
        for (int i = 0; i < 4; ++i)
#pragma unroll
            for (int j = 0; j < 4; ++j) {
                acca[i][j] = __builtin_amdgcn_mfma_f32_16x16x32_bf16(af[i], baf[j], acca[i][j], 0, 0, 0);
                accb[i][j] = __builtin_amdgcn_mfma_f32_16x16x32_bf16(af[i], bbf[j], accb[i][j], 0, 0, 0);
            }
        __syncthreads();
    }

#pragma unroll
    for (int i = 0; i < 4; ++i) {
        int gr = bm + wr + i * 16 + quad * 4;
#pragma unroll
        for (int j = 0; j < 4; ++j) {
            int gc = bn + wc + j * 16 + l15;
            bool ok = gc < HID;
            float ba = ok ? b_in[gc] : 0.0f;
            float bb = ok ? b_in[HID + gc] : 0.0f;
#pragma unroll
            for (int r = 0; r < 4; ++r) {
                float a  = acca[i][j][r] + ba;
                float bv = accb[i][j][r] + bb;
                float val = ok ? a * (bv / (1.0f + expf(-bv))) : 0.0f;
                hm[(size_t)(gr + r) * HID_PAD + gc] = f2bf(val);
            }
        }
    }
}

// ---------------------------------------------------------------------------
// MFMA retention + groupnorm + silu gate.
// qkg: [NTOK][3072] bf16: cols [0,1024)=q, [1024,2048)=k, [2048,3072)=g.
// vT:  [1024][NTOK]  bf16: row d = h*64+dd, col = token (V transposed).
// Staging via global_load_lds into [64][32]-chunk LDS tiles (m97 layout).
// Output rg: [NTOK][1024] bf16 = groupnorm(out) * silu(g).
// ---------------------------------------------------------------------------
#define PSTR 72   // ps row stride in shorts

__global__ __launch_bounds__(256) void retention_mfma(
        const short* __restrict__ qkg,
        const short* __restrict__ vT,
        short* __restrict__ rg)
{
    int qb = blockIdx.x;   // 0..31 (q tile)
    int h  = blockIdx.y;   // 0..15
    int b  = blockIdx.z;   // 0..1

    __shared__ short ks[2][64 * 32];      // K tile, d-chunk c: [t][d in 32c..]
    __shared__ short vt[2][64 * 32];      // V^T tile, t-chunk c: [d][t in 32c..]
    __shared__ short ps[4][16 * PSTR];    // per-wave P tile, [s][t]

    int tid  = threadIdx.x;
    int wave = tid >> 6;
    int lane = tid & 63;
    int quad = lane >> 4;
    int l15  = lane & 15;

    float log2g = log1pf(-exp2f(-5.0f - (float)h)) * 1.4426950408889634f;
    int hcol = h * HDIM;
    int s0 = qb * 64;
    size_t tok0 = (size_t)b * SEQ;

    // staging address components (thread t loads row t>>2, 8-short piece t&3)
    int srow = tid >> 2;            // 0..63
    int sc8  = (tid & 3) << 3;      // 0,8,16,24
    const short* kbase  = qkg + (tok0 + srow) * QKG + 1024 + hcol + sc8;
    const short* vtbase = vT + (size_t)(hcol + srow) * NTOK + tok0 + sc8;
    short* lks0 = &ks[0][tid << 3]; // = [64][32] layout, thread t at t*8 shorts
    short* lks1 = &ks[1][tid << 3];
    short* lvt0 = &vt[0][tid << 3];
    short* lvt1 = &vt[1][tid << 3];

    // Q A-fragments for the wave's 16 rows
    const short* qrow = qkg + (tok0 + s0 + wave * 16 + l15) * QKG + hcol;
    bf16x8 qa0 = *(const bf16x8*)(qrow + quad * 8);
    bf16x8 qa1 = *(const bf16x8*)(qrow + 32 + quad * 8);

    f32x4 oacc[4];
#pragma unroll
    for (int i = 0; i < 4; ++i) oacc[i] = (f32x4){0.f, 0.f, 0.f, 0.f};

    for (int tb = 0; tb <= qb; ++tb) {
        __syncthreads();
        // stage K tile (2 d-chunks) and V^T tile (2 t-chunks) via async DMA
        {
            size_t koff = (size_t)tb * 64 * QKG;
            GLD16(kbase + koff, lks0);           // d in [0,32)
            GLD16(kbase + koff + 32, lks1);      // d in [32,64)
            int vcol = tb * 64;
            GLD16(vtbase + vcol, lvt0);          // t in [0,32)
            GLD16(vtbase + vcol + 32, lvt1);     // t in [32,64)
        }
        __syncthreads();

        // scores: S[s][t] for 4 t-tiles of 16
        f32x4 sacc[4];
#pragma unroll
        for (int i = 0; i < 4; ++i) sacc[i] = (f32x4){0.f, 0.f, 0.f, 0.f};
#pragma unroll
        for (int tile = 0; tile < 4; ++tile) {
            bf16x8 kb0 = *(const bf16x8*)(&ks[0][(tile * 16 + l15) * 32 + quad * 8]);
            bf16x8 kb1 = *(const bf16x8*)(&ks[1][(tile * 16 + l15) * 32 + quad * 8]);
            sacc[tile] = __builtin_amdgcn_mfma_f32_16x16x32_bf16(qa0, kb0, sacc[tile], 0, 0, 0);
            sacc[tile] = __builtin_amdgcn_mfma_f32_16x16x32_bf16(qa1, kb1, sacc[tile], 0, 0, 0);
        }
        // scale + decay + mask -> bf16 P (wave-private LDS)
        int sbase = s0 + wave * 16 + quad * 4;
#pragma unroll
        for (int tile = 0; tile < 4; ++tile) {
            int tt = tb * 64 + tile * 16 + l15;
            float fb = (float)(sbase - tt);
#pragma unroll
            for (int reg = 0; reg < 4; ++reg) {
                float delta = fb + (float)reg;
                float dec = (delta >= 0.0f) ? exp2f(delta * log2g) : 0.0f;
                ps[wave][(quad * 4 + reg) * PSTR + tile * 16 + l15] = f2bf(sacc[tile][reg] * 0.125f * dec);
            }
        }
        // PV: out[s][d] += P[s][t] * V[t][d]; B-frag from vt chunk ksi
#pragma unroll
        for (int ksi = 0; ksi < 2; ++ksi) {
            bf16x8 pa = *(const bf16x8*)(&ps[wave][l15 * PSTR + ksi * 32 + quad * 8]);
#pragma unroll
            for (int dt = 0; dt < 4; ++dt) {
                bf16x8 vb = *(const bf16x8*)(&vt[ksi][(dt * 16 + l15) * 32 + quad * 8]);
                oacc[dt] = __builtin_amdgcn_mfma_f32_16x16x32_bf16(pa, vb, oacc[dt], 0, 0, 0);
            }
        }
    }

    // groupnorm over d=64 per s-row
    float s1[4], s2[4];
#pragma unroll
    for (int reg = 0; reg < 4; ++reg) {
        s1[reg] = oacc[0][reg] + oacc[1][reg] + oacc[2][reg] + oacc[3][reg];
        s2[reg] = oacc[0][reg] * oacc[0][reg] + oacc[1][reg] * oacc[1][reg]
                + oacc[2][reg] * oacc[2][reg] + oacc[3][reg] * oacc[3][reg];
    }
#pragma unroll
    for (int off = 1; off < 16; off <<= 1) {
#pragma unroll
        for (int reg = 0; reg < 4; ++reg) {
            s1[reg] += __shfl_xor(s1[reg], off);
            s2[reg] += __shfl_xor(s2[reg], off);
        }
    }
    size_t rowtok = tok0 + s0 + wave * 16 + quad * 4;
    short* obase = rg + rowtok * D_MODEL + hcol;
    const short* gbase = qkg + rowtok * QKG + 2048 + hcol;
#pragma unroll
    for (int reg = 0; reg < 4; ++reg) {
        float mu  = s1[reg] * (1.0f / 64.0f);
        float var = s2[reg] * (1.0f / 64.0f) - mu * mu;
        float inv = rsqrtf(var + 1e-6f);
#pragma unroll
        for (int dt = 0; dt < 4; ++dt) {
            float gv = bf2f(gbase[(size_t)reg * QKG + dt * 16 + l15]);
            float val = (oacc[dt][reg] - mu) * inv * (gv / (1.0f + expf(-gv)));
            obase[(size_t)reg * D_MODEL + dt * 16 + l15] = f2bf(val);
        }
    }
}

// ---------------------------------------------------------------------------
extern "C" void kernel_launch(void* const* d_in, const int* in_sizes, int n_in,
                              void* d_out, int out_size, void* d_ws, size_t ws_size,
                              hipStream_t stream)
{
    const float* x     = (const float*)d_in[0];
    const float* ln1w  = (const float*)d_in[1];
    const float* ln1b  = (const float*)d_in[2];
    const float* wq    = (const float*)d_in[3];
    const float* wk    = (const float*)d_in[4];
    const float* wv    = (const float*)d_in[5];
    const float* wg    = (const float*)d_in[6];
    const float* wo    = (const float*)d_in[7];
    const float* ln2w  = (const float*)d_in[8];
    const float* ln2b  = (const float*)d_in[9];
    const float* w_in  = (const float*)d_in[10];
    const float* b_in  = (const float*)d_in[11];
    const float* w_out = (const float*)d_in[12];
    const float* b_out = (const float*)d_in[13];
    float* out = (float*)d_out;
    char* base = (char*)d_ws;

    const size_t MB = 1u << 20;
    short* xn     = (short*)(base);            // [0,8)   [4096][1024] bf16 LN out
    short* qkgT   = (short*)(base +  8 * MB);  // [8,14)  wq|wk|wg transposed [3072][1024]
    short* wvT    = (short*)(base + 14 * MB);  // [14,16) [1024][1024]
    short* woT    = (short*)(base + 16 * MB);  // [16,18) [1024][1024]
    short* w_inT  = (short*)(base + 18 * MB);  // [18,29) [5632][1024]
    short* w_outT = (short*)(base + 29 * MB);  // [29,34.5) [1024][2816]
    short* qkg    = (short*)(base + 35 * MB);  // [35,59) [4096][3072] packed q|k|g
    short* hm     = (short*)(base + 35 * MB);  // [35,57) [4096][2816] reuses dead qkg
    short* vT     = (short*)(base + 59 * MB);  // [59,67) [1024][4096] V transposed
    short* rg     = (short*)(base + 67 * MB);  // [67,75) [4096][1024] gated retention out

    dim3 tb(32, 8);
    // weight transposes (fp32 -> bf16, [N][K])
    transpose_f2b<<<dim3(32, 32), tb, 0, stream>>>(wq, 1024, 0, 1024, 1024, 1024, qkgT);
    transpose_f2b<<<dim3(32, 32), tb, 0, stream>>>(wk, 1024, 0, 1024, 1024, 1024, qkgT + 1024 * 1024);
    transpose_f2b<<<dim3(32, 32), tb, 0, stream>>>(wg, 1024, 0, 1024, 1024, 1024, qkgT + 2 * 1024 * 1024);
    transpose_f2b<<<dim3(32, 32), tb, 0, stream>>>(wv, 1024, 0, 1024, 1024, 1024, wvT);
    transpose_f2b<<<dim3(32, 32), tb, 0, stream>>>(wo, 1024, 0, 1024, 1024, 1024, woT);
    transpose_f2b<<<dim3(32, 88), tb, 0, stream>>>(w_in, 2 * HID, 0,   HID, 1024, 1024, w_inT);
    transpose_f2b<<<dim3(32, 88), tb, 0, stream>>>(w_in, 2 * HID, HID, HID, 1024, 1024, w_inT + (size_t)HID_PAD * 1024);
    transpose_f2b<<<dim3(88, 32), tb, 0, stream>>>(w_out, 1024, 0, 1024, HID, HID_PAD, w_outT);

    // LN1 -> bf16
    ln_kernel<<<NTOK, 256, 0, stream>>>(x, ln1w, ln1b, xn, 1e-5f);
    // packed q|k|g projection: [4096,1024] @ [1024,3072] -> qkg
    gemm_bt<0><<<dim3(QKG / 128, 32), 256, 0, stream>>>(xn, D_MODEL, qkgT, nullptr, nullptr, 0, qkg, QKG, D_MODEL);
    // v^T projection: C[d][tok] = wvT @ xn^T  (A/B swapped => transposed output)
    gemm_bt<0><<<dim3(NTOK / 128, 8), 256, 0, stream>>>(wvT, D_MODEL, xn, nullptr, nullptr, 0, vT, NTOK, D_MODEL);
    // retention + groupnorm + silu gate -> rg bf16
    retention_mfma<<<dim3(SEQ / 64, NHEAD, BATCH), 256, 0, stream>>>(qkg, vT, rg);
    // wo projection + residual x -> out (fp32)
    gemm_bt<1><<<dim3(8, 32), 256, 0, stream>>>(rg, D_MODEL, woT, nullptr, x, D_MODEL, out, D_MODEL, D_MODEL);
    // LN2 -> bf16 (reuse xn)
    ln_kernel<<<NTOK, 256, 0, stream>>>(out, ln2w, ln2b, xn, 1e-5f);
    // fused SwiGLU-in GEMM -> hm bf16 [4096][2816]
    mlp_fused<<<dim3(HID_PAD / 128, 32), 256, 0, stream>>>(xn, w_inT, b_in, hm);
    // w_out GEMM + bias + residual -> out (fp32, in-place residual)
    gemm_bt<2><<<dim3(8, 32), 256, 0, stream>>>(hm, HID_PAD, w_outT, b_out, out, D_MODEL, out, D_MODEL, HID_PAD);
}

// Round 5
// 480.874 us; speedup vs baseline: 13.4835x; 1.1260x over previous
//
#include <hip/hip_runtime.h>
#include <math.h>

#define D_MODEL 1024
#define NHEAD   16
#define HDIM    64
#define HID     2730
#define HID_PAD 2816          // 22 * 128
#define SEQ     2048
#define BATCH   2
#define NTOK    (BATCH * SEQ)   // 4096
#define QKG     3072            // packed q|k|g row stride (elements)

typedef __attribute__((ext_vector_type(8))) short bf16x8;
typedef __attribute__((ext_vector_type(4))) float f32x4;
typedef __attribute__((ext_vector_type(4))) short s16x4;

// fp32 -> bf16 round-to-nearest-even
static __device__ inline short f2bf(float f)
{
    union { float f; unsigned int u; } c; c.f = f;
    unsigned int r = c.u + 0x7FFFu + ((c.u >> 16) & 1u);
    return (short)(r >> 16);
}
static __device__ inline float bf2f(short s)
{
    union { unsigned int u; float f; } c;
    c.u = ((unsigned int)(unsigned short)s) << 16;
    return c.f;
}

// async global->LDS, 16B per lane; lds dest = wave-uniform base + lane*16
#define GLD16(gsrc, ldst) \
    __builtin_amdgcn_global_load_lds((const __attribute__((address_space(1))) void*)(gsrc), \
                                     (__attribute__((address_space(3))) void*)(ldst), 16, 0, 0)

// ---------------------------------------------------------------------------
// LayerNorm: one block (256 threads) per row of 1024, fp32 in -> bf16 out
// ---------------------------------------------------------------------------
__global__ void ln_kernel(const float* __restrict__ x,
                          const float* __restrict__ w,
                          const float* __restrict__ b,
                          short* __restrict__ out,
                          float eps)
{
    int row = blockIdx.x;
    int t = threadIdx.x;               // 0..255
    const float4* xr = (const float4*)(x + (size_t)row * D_MODEL);
    float4 v = xr[t];
    float s  = v.x + v.y + v.z + v.w;
    float sq = v.x * v.x + v.y * v.y + v.z * v.z + v.w * v.w;
#pragma unroll
    for (int off = 32; off > 0; off >>= 1) {
        s  += __shfl_xor(s, off);
        sq += __shfl_xor(sq, off);
    }
    __shared__ float ss[4], ssq[4];
    int wave = t >> 6;
    if ((t & 63) == 0) { ss[wave] = s; ssq[wave] = sq; }
    __syncthreads();
    s  = ss[0] + ss[1] + ss[2] + ss[3];
    sq = ssq[0] + ssq[1] + ssq[2] + ssq[3];
    float mu  = s * (1.0f / D_MODEL);
    float var = sq * (1.0f / D_MODEL) - mu * mu;
    float inv = rsqrtf(var + eps);
    float4 wv = ((const float4*)w)[t];
    float4 bv = ((const float4*)b)[t];
    s16x4 o;
    o.x = f2bf((v.x - mu) * inv * wv.x + bv.x);
    o.y = f2bf((v.y - mu) * inv * wv.y + bv.y);
    o.z = f2bf((v.z - mu) * inv * wv.z + bv.z);
    o.w = f2bf((v.w - mu) * inv * wv.w + bv.w);
    *(s16x4*)(out + (size_t)row * D_MODEL + 4 * t) = o;
}

// ---------------------------------------------------------------------------
// Transpose + cast: dst[n][k] (bf16, [NPAD][KPAD]) = src[k][coloff+n] (fp32)
// ---------------------------------------------------------------------------
__global__ void transpose_f2b(const float* __restrict__ src, int ldsrc, int coloff,
                              int nvalid, int kvalid, int KPAD,
                              short* __restrict__ dst)
{
    __shared__ float tile[32][33];
    int k0 = blockIdx.x * 32, n0 = blockIdx.y * 32;
    int tx = threadIdx.x, ty = threadIdx.y;
#pragma unroll
    for (int i = 0; i < 32; i += 8) {
        int k = k0 + ty + i, n = n0 + tx;
        tile[ty + i][tx] = (k < kvalid && n < nvalid) ? src[(size_t)k * ldsrc + coloff + n] : 0.0f;
    }
    __syncthreads();
#pragma unroll
    for (int i = 0; i < 32; i += 8) {
        int n = n0 + ty + i, k = k0 + tx;
        dst[(size_t)n * KPAD + k] = f2bf(tile[tx][ty + i]);
    }
}

// ---------------------------------------------------------------------------
// bf16 MFMA GEMM (m97 structure): C[M,N] = A[M,K] @ Bt[N,K]^T (+bias)(+R)
// 128x128 tile, BK=32, 256 threads = 4 waves in 2x2, each 64x64 (4x4 MFMA).
// EPI: 0 = bf16 store; 1 = fp32 + R; 2 = fp32 + bias + R
// ---------------------------------------------------------------------------
template<int EPI>
__global__ __launch_bounds__(256) void gemm_bt(
        const short* __restrict__ A, int lda,
        const short* __restrict__ Bt,
        const float* __restrict__ bias,
        const float* __restrict__ R, int ldr,
        void* __restrict__ C, int ldc, int K)
{
    __shared__ short As[128 * 32];
    __shared__ short Bs[128 * 32];
    int bm = blockIdx.y * 128;
    int bn = blockIdx.x * 128;
    int t = threadIdx.x;
    int w = t >> 6;
    int lane = t & 63;
    int quad = lane >> 4;
    int l15  = lane & 15;

    const short* gA0 = A  + (size_t)(bm + (t >> 2)) * lda + ((t & 3) << 3);
    const short* gA1 = gA0 + (size_t)64 * lda;
    const short* gB0 = Bt + (size_t)(bn + (t >> 2)) * K + ((t & 3) << 3);
    const short* gB1 = gB0 + (size_t)64 * K;
    short* lA0 = As + (w << 9);
    short* lA1 = As + 2048 + (w << 9);
    short* lB0 = Bs + (w << 9);
    short* lB1 = Bs + 2048 + (w << 9);

    int wr = (w >> 1) * 64;
    int wc = (w & 1) * 64;

    f32x4 acc[4][4];
#pragma unroll
    for (int i = 0; i < 4; ++i)
#pragma unroll
        for (int j = 0; j < 4; ++j) acc[i][j] = (f32x4){0.f, 0.f, 0.f, 0.f};

    for (int k0 = 0; k0 < K; k0 += 32) {
        GLD16(gA0 + k0, lA0);
        GLD16(gA1 + k0, lA1);
        GLD16(gB0 + k0, lB0);
        GLD16(gB1 + k0, lB1);
        __syncthreads();
        bf16x8 af[4], bfr[4];
#pragma unroll
        for (int i = 0; i < 4; ++i)
            af[i] = *(const bf16x8*)(As + (wr + i * 16 + l15) * 32 + quad * 8);
#pragma unroll
        for (int j = 0; j < 4; ++j)
            bfr[j] = *(const bf16x8*)(Bs + (wc + j * 16 + l15) * 32 + quad * 8);
#pragma unroll
        for (int i = 0; i < 4; ++i)
#pragma unroll
            for (int j = 0; j < 4; ++j)
                acc[i][j] = __builtin_amdgcn_mfma_f32_16x16x32_bf16(af[i], bfr[j], acc[i][j], 0, 0, 0);
        __syncthreads();
    }

#pragma unroll
    for (int i = 0; i < 4; ++i) {
        int gr = bm + wr + i * 16 + quad * 4;
#pragma unroll
        for (int j = 0; j < 4; ++j) {
            int gc = bn + wc + j * 16 + l15;
#pragma unroll
            for (int r = 0; r < 4; ++r) {
                float val = acc[i][j][r];
                size_t idx = (size_t)(gr + r) * ldc + gc;
                if (EPI == 0) {
                    ((short*)C)[idx] = f2bf(val);
                } else if (EPI == 1) {
                    ((float*)C)[idx] = val + R[(size_t)(gr + r) * ldr + gc];
                } else {
                    ((float*)C)[idx] = val + bias[gc] + R[(size_t)(gr + r) * ldr + gc];
                }
            }
        }
    }
}

// ---------------------------------------------------------------------------
// Fused SwiGLU-in GEMM (MFMA), occupancy-tuned:
// block tile 128 rows x 64 cols of BOTH halves; waves 2x2, each 64x32 of a+b.
// acc = 16 f32x4 = 64 AGPR (vs 128 before) -> ~3 waves/SIMD.
// ---------------------------------------------------------------------------
__global__ __launch_bounds__(256) void mlp_fused(
        const short* __restrict__ A,       // [NTOK][1024] bf16
        const short* __restrict__ w_inT,   // [2*HID_PAD][1024] bf16
        const float* __restrict__ b_in,    // [2*HID]
        short* __restrict__ hm)            // [NTOK][HID_PAD] bf16
{
    __shared__ short As[128 * 32];   // 8 KB
    __shared__ short Ba[64 * 32];    // 4 KB
    __shared__ short Bb[64 * 32];    // 4 KB
    const int K = D_MODEL;
    int bm = blockIdx.y * 128;
    int bn = blockIdx.x * 64;
    int t = threadIdx.x;
    int w = t >> 6;
    int lane = t & 63;
    int quad = lane >> 4;
    int l15  = lane & 15;

    const short* gA0 = A + (size_t)(bm + (t >> 2)) * K + ((t & 3) << 3);
    const short* gA1 = gA0 + (size_t)64 * K;
    const short* gBa = w_inT + (size_t)(bn + (t >> 2)) * K + ((t & 3) << 3);
    const short* gBb = gBa + (size_t)HID_PAD * K;
    short* lA0 = As + (w << 9);
    short* lA1 = As + 2048 + (w << 9);
    short* lBa = Ba + (w << 9);
    short* lBb = Bb + (w << 9);

    int wr = (w >> 1) * 64;
    int wc = (w & 1) * 32;

    f32x4 acca[4][2], accb[4][2];
#pragma unroll
    for (int i = 0; i < 4; ++i)
#pragma unroll
        for (int j = 0; j < 2; ++j) {
            acca[i][j] = (f32x4){0.f, 0.f, 0.f, 0.f};
            accb[i][j] = (f32x4){0.f, 0.f, 0.f, 0.f};
        }

    for (int k0 = 0; k0 < K; k0 += 32) {
        GLD16(gA0 + k0, lA0);
        GLD16(gA1 + k0, lA1);
        GLD16(gBa + k0, lBa);
        GLD16(gBb + k0, lBb);
        __syncthreads();
        bf16x8 af[4], baf[2], bbf[2];
#pragma unroll
        for (int i = 0; i < 4; ++i)
            af[i] = *(const bf16x8*)(As + (wr + i * 16 + l15) * 32 + quad * 8);
#pragma unroll
        for (int j = 0; j < 2; ++j) {
            baf[j] = *(const bf16x8*)(Ba + (wc + j * 16 + l15) * 32 + quad * 8);
            bbf[j] = *(const bf16x8*)(Bb + (wc + j * 16 + l15) * 32 + quad * 8);
        }
#pragma unroll
        for (int i = 0; i < 4; ++i)
#pragma unroll
            for (int j = 0; j < 2; ++j) {
                acca[i][j] = __builtin_amdgcn_mfma_f32_16x16x32_bf16(af[i], baf[j], acca[i][j], 0, 0, 0);
                accb[i][j] = __builtin_amdgcn_mfma_f32_16x16x32_bf16(af[i], bbf[j], accb[i][j], 0, 0, 0);
            }
        __syncthreads();
    }

#pragma unroll
    for (int i = 0; i < 4; ++i) {
        int gr = bm + wr + i * 16 + quad * 4;
#pragma unroll
        for (int j = 0; j < 2; ++j) {
            int gc = bn + wc + j * 16 + l15;
            bool ok = gc < HID;
            float ba = ok ? b_in[gc] : 0.0f;
            float bb = ok ? b_in[HID + gc] : 0.0f;
#pragma unroll
            for (int r = 0; r < 4; ++r) {
                float a  = acca[i][j][r] + ba;
                float bv = accb[i][j][r] + bb;
                float val = ok ? a * (bv / (1.0f + expf(-bv))) : 0.0f;
                hm[(size_t)(gr + r) * HID_PAD + gc] = f2bf(val);
            }
        }
    }
}

// ---------------------------------------------------------------------------
// MFMA retention + groupnorm + silu gate.
// qkg: [NTOK][3072] bf16: cols [0,1024)=q, [1024,2048)=k, [2048,3072)=g.
// vT:  [1024][NTOK]  bf16: row d = h*64+dd, col = token (V transposed).
// ---------------------------------------------------------------------------
#define PSTR 72   // ps row stride in shorts

__global__ __launch_bounds__(256) void retention_mfma(
        const short* __restrict__ qkg,
        const short* __restrict__ vT,
        short* __restrict__ rg)
{
    int qb = blockIdx.x;   // 0..31 (q tile)
    int h  = blockIdx.y;   // 0..15
    int b  = blockIdx.z;   // 0..1

    __shared__ short ks[2][64 * 32];      // K tile, d-chunk c: [t][d in 32c..]
    __shared__ short vt[2][64 * 32];      // V^T tile, t-chunk c: [d][t in 32c..]
    __shared__ short ps[4][16 * PSTR];    // per-wave P tile, [s][t]

    int tid  = threadIdx.x;
    int wave = tid >> 6;
    int lane = tid & 63;
    int quad = lane >> 4;
    int l15  = lane & 15;

    float log2g = log1pf(-exp2f(-5.0f - (float)h)) * 1.4426950408889634f;
    int hcol = h * HDIM;
    int s0 = qb * 64;
    size_t tok0 = (size_t)b * SEQ;

    int srow = tid >> 2;            // 0..63
    int sc8  = (tid & 3) << 3;      // 0,8,16,24
    const short* kbase  = qkg + (tok0 + srow) * QKG + 1024 + hcol + sc8;
    const short* vtbase = vT + (size_t)(hcol + srow) * NTOK + tok0 + sc8;
    short* lks0 = &ks[0][tid << 3];
    short* lks1 = &ks[1][tid << 3];
    short* lvt0 = &vt[0][tid << 3];
    short* lvt1 = &vt[1][tid << 3];

    const short* qrow = qkg + (tok0 + s0 + wave * 16 + l15) * QKG + hcol;
    bf16x8 qa0 = *(const bf16x8*)(qrow + quad * 8);
    bf16x8 qa1 = *(const bf16x8*)(qrow + 32 + quad * 8);

    f32x4 oacc[4];
#pragma unroll
    for (int i = 0; i < 4; ++i) oacc[i] = (f32x4){0.f, 0.f, 0.f, 0.f};

    for (int tb = 0; tb <= qb; ++tb) {
        __syncthreads();
        {
            size_t koff = (size_t)tb * 64 * QKG;
            GLD16(kbase + koff, lks0);
            GLD16(kbase + koff + 32, lks1);
            int vcol = tb * 64;
            GLD16(vtbase + vcol, lvt0);
            GLD16(vtbase + vcol + 32, lvt1);
        }
        __syncthreads();

        f32x4 sacc[4];
#pragma unroll
        for (int i = 0; i < 4; ++i) sacc[i] = (f32x4){0.f, 0.f, 0.f, 0.f};
#pragma unroll
        for (int tile = 0; tile < 4; ++tile) {
            bf16x8 kb0 = *(const bf16x8*)(&ks[0][(tile * 16 + l15) * 32 + quad * 8]);
            bf16x8 kb1 = *(const bf16x8*)(&ks[1][(tile * 16 + l15) * 32 + quad * 8]);
            sacc[tile] = __builtin_amdgcn_mfma_f32_16x16x32_bf16(qa0, kb0, sacc[tile], 0, 0, 0);
            sacc[tile] = __builtin_amdgcn_mfma_f32_16x16x32_bf16(qa1, kb1, sacc[tile], 0, 0, 0);
        }
        int sbase = s0 + wave * 16 + quad * 4;
#pragma unroll
        for (int tile = 0; tile < 4; ++tile) {
            int tt = tb * 64 + tile * 16 + l15;
            float fb = (float)(sbase - tt);
#pragma unroll
            for (int reg = 0; reg < 4; ++reg) {
                float delta = fb + (float)reg;
                float dec = (delta >= 0.0f) ? exp2f(delta * log2g) : 0.0f;
                ps[wave][(quad * 4 + reg) * PSTR + tile * 16 + l15] = f2bf(sacc[tile][reg] * 0.125f * dec);
            }
        }
#pragma unroll
        for (int ksi = 0; ksi < 2; ++ksi) {
            bf16x8 pa = *(const bf16x8*)(&ps[wave][l15 * PSTR + ksi * 32 + quad * 8]);
#pragma unroll
            for (int dt = 0; dt < 4; ++dt) {
                bf16x8 vb = *(const bf16x8*)(&vt[ksi][(dt * 16 + l15) * 32 + quad * 8]);
                oacc[dt] = __builtin_amdgcn_mfma_f32_16x16x32_bf16(pa, vb, oacc[dt], 0, 0, 0);
            }
        }
    }

    float s1[4], s2[4];
#pragma unroll
    for (int reg = 0; reg < 4; ++reg) {
        s1[reg] = oacc[0][reg] + oacc[1][reg] + oacc[2][reg] + oacc[3][reg];
        s2[reg] = oacc[0][reg] * oacc[0][reg] + oacc[1][reg] * oacc[1][reg]
                + oacc[2][reg] * oacc[2][reg] + oacc[3][reg] * oacc[3][reg];
    }
#pragma unroll
    for (int off = 1; off < 16; off <<= 1) {
#pragma unroll
        for (int reg = 0; reg < 4; ++reg) {
            s1[reg] += __shfl_xor(s1[reg], off);
            s2[reg] += __shfl_xor(s2[reg], off);
        }
    }
    size_t rowtok = tok0 + s0 + wave * 16 + quad * 4;
    short* obase = rg + rowtok * D_MODEL + hcol;
    const short* gbase = qkg + rowtok * QKG + 2048 + hcol;
#pragma unroll
    for (int reg = 0; reg < 4; ++reg) {
        float mu  = s1[reg] * (1.0f / 64.0f);
        float var = s2[reg] * (1.0f / 64.0f) - mu * mu;
        float inv = rsqrtf(var + 1e-6f);
#pragma unroll
        for (int dt = 0; dt < 4; ++dt) {
            float gv = bf2f(gbase[(size_t)reg * QKG + dt * 16 + l15]);
            float val = (oacc[dt][reg] - mu) * inv * (gv / (1.0f + expf(-gv)));
            obase[(size_t)reg * D_MODEL + dt * 16 + l15] = f2bf(val);
        }
    }
}

// ---------------------------------------------------------------------------
extern "C" void kernel_launch(void* const* d_in, const int* in_sizes, int n_in,
                              void* d_out, int out_size, void* d_ws, size_t ws_size,
                              hipStream_t stream)
{
    const float* x     = (const float*)d_in[0];
    const float* ln1w  = (const float*)d_in[1];
    const float* ln1b  = (const float*)d_in[2];
    const float* wq    = (const float*)d_in[3];
    const float* wk    = (const float*)d_in[4];
    const float* wv    = (const float*)d_in[5];
    const float* wg    = (const float*)d_in[6];
    const float* wo    = (const float*)d_in[7];
    const float* ln2w  = (const float*)d_in[8];
    const float* ln2b  = (const float*)d_in[9];
    const float* w_in  = (const float*)d_in[10];
    const float* b_in  = (const float*)d_in[11];
    const float* w_out = (const float*)d_in[12];
    const float* b_out = (const float*)d_in[13];
    float* out = (float*)d_out;
    char* base = (char*)d_ws;

    const size_t MB = 1u << 20;
    short* xn     = (short*)(base);            // [0,8)   [4096][1024] bf16 LN out
    short* qkgT   = (short*)(base +  8 * MB);  // [8,14)  wq|wk|wg transposed [3072][1024]
    short* wvT    = (short*)(base + 14 * MB);  // [14,16) [1024][1024]
    short* woT    = (short*)(base + 16 * MB);  // [16,18) [1024][1024]
    short* w_inT  = (short*)(base + 18 * MB);  // [18,29) [5632][1024]
    short* w_outT = (short*)(base + 29 * MB);  // [29,34.5) [1024][2816]
    short* qkg    = (short*)(base + 35 * MB);  // [35,59) [4096][3072] packed q|k|g
    short* hm     = (short*)(base + 35 * MB);  // [35,57) [4096][2816] reuses dead qkg
    short* vT     = (short*)(base + 59 * MB);  // [59,67) [1024][4096] V transposed
    short* rg     = (short*)(base + 67 * MB);  // [67,75) [4096][1024] gated retention out

    dim3 tb(32, 8);
    transpose_f2b<<<dim3(32, 32), tb, 0, stream>>>(wq, 1024, 0, 1024, 1024, 1024, qkgT);
    transpose_f2b<<<dim3(32, 32), tb, 0, stream>>>(wk, 1024, 0, 1024, 1024, 1024, qkgT + 1024 * 1024);
    transpose_f2b<<<dim3(32, 32), tb, 0, stream>>>(wg, 1024, 0, 1024, 1024, 1024, qkgT + 2 * 1024 * 1024);
    transpose_f2b<<<dim3(32, 32), tb, 0, stream>>>(wv, 1024, 0, 1024, 1024, 1024, wvT);
    transpose_f2b<<<dim3(32, 32), tb, 0, stream>>>(wo, 1024, 0, 1024, 1024, 1024, woT);
    transpose_f2b<<<dim3(32, 88), tb, 0, stream>>>(w_in, 2 * HID, 0,   HID, 1024, 1024, w_inT);
    transpose_f2b<<<dim3(32, 88), tb, 0, stream>>>(w_in, 2 * HID, HID, HID, 1024, 1024, w_inT + (size_t)HID_PAD * 1024);
    transpose_f2b<<<dim3(88, 32), tb, 0, stream>>>(w_out, 1024, 0, 1024, HID, HID_PAD, w_outT);

    // LN1 -> bf16
    ln_kernel<<<NTOK, 256, 0, stream>>>(x, ln1w, ln1b, xn, 1e-5f);
    // packed q|k|g projection
    gemm_bt<0><<<dim3(QKG / 128, 32), 256, 0, stream>>>(xn, D_MODEL, qkgT, nullptr, nullptr, 0, qkg, QKG, D_MODEL);
    // v^T projection (A/B swapped => transposed output)
    gemm_bt<0><<<dim3(NTOK / 128, 8), 256, 0, stream>>>(wvT, D_MODEL, xn, nullptr, nullptr, 0, vT, NTOK, D_MODEL);
    // retention + groupnorm + silu gate
    retention_mfma<<<dim3(SEQ / 64, NHEAD, BATCH), 256, 0, stream>>>(qkg, vT, rg);
    // wo projection + residual x -> out (fp32)
    gemm_bt<1><<<dim3(8, 32), 256, 0, stream>>>(rg, D_MODEL, woT, nullptr, x, D_MODEL, out, D_MODEL, D_MODEL);
    // LN2 -> bf16
    ln_kernel<<<NTOK, 256, 0, stream>>>(out, ln2w, ln2b, xn, 1e-5f);
    // fused SwiGLU-in GEMM -> hm bf16, 128x64 tiles
    mlp_fused<<<dim3(HID_PAD / 64, NTOK / 128), 256, 0, stream>>>(xn, w_inT, b_in, hm);
    // w_out GEMM + bias + residual
    gemm_bt<2><<<dim3(8, 32), 256, 0, stream>>>(hm, HID_PAD, w_outT, b_out, out, D_MODEL, out, D_MODEL, HID_PAD);
}

// Round 6
// 464.480 us; speedup vs baseline: 13.9594x; 1.0353x over previous
//
#include <hip/hip_runtime.h>
#include <math.h>

#define D_MODEL 1024
#define NHEAD   16
#define HDIM    64
#define HID     2730
#define HID_PAD 2816          // 22 * 128
#define SEQ     2048
#define BATCH   2
#define NTOK    (BATCH * SEQ)   // 4096
#define QKG     3072            // packed q|k|g row stride (elements)

typedef __attribute__((ext_vector_type(8))) short bf16x8;
typedef __attribute__((ext_vector_type(4))) float f32x4;
typedef __attribute__((ext_vector_type(4))) short s16x4;

// fp32 -> bf16 round-to-nearest-even
static __device__ inline short f2bf(float f)
{
    union { float f; unsigned int u; } c; c.f = f;
    unsigned int r = c.u + 0x7FFFu + ((c.u >> 16) & 1u);
    return (short)(r >> 16);
}
static __device__ inline float bf2f(short s)
{
    union { unsigned int u; float f; } c;
    c.u = ((unsigned int)(unsigned short)s) << 16;
    return c.f;
}

// async global->LDS, 16B per lane; lds dest = wave-uniform base + lane*16
#define GLD16(gsrc, ldst) \
    __builtin_amdgcn_global_load_lds((const __attribute__((address_space(1))) void*)(gsrc), \
                                     (__attribute__((address_space(3))) void*)(ldst), 16, 0, 0)

// ---------------------------------------------------------------------------
// LayerNorm: one block (256 threads) per row of 1024, fp32 in -> bf16 out
// ---------------------------------------------------------------------------
__global__ void ln_kernel(const float* __restrict__ x,
                          const float* __restrict__ w,
                          const float* __restrict__ b,
                          short* __restrict__ out,
                          float eps)
{
    int row = blockIdx.x;
    int t = threadIdx.x;               // 0..255
    const float4* xr = (const float4*)(x + (size_t)row * D_MODEL);
    float4 v = xr[t];
    float s  = v.x + v.y + v.z + v.w;
    float sq = v.x * v.x + v.y * v.y + v.z * v.z + v.w * v.w;
#pragma unroll
    for (int off = 32; off > 0; off >>= 1) {
        s  += __shfl_xor(s, off);
        sq += __shfl_xor(sq, off);
    }
    __shared__ float ss[4], ssq[4];
    int wave = t >> 6;
    if ((t & 63) == 0) { ss[wave] = s; ssq[wave] = sq; }
    __syncthreads();
    s  = ss[0] + ss[1] + ss[2] + ss[3];
    sq = ssq[0] + ssq[1] + ssq[2] + ssq[3];
    float mu  = s * (1.0f / D_MODEL);
    float var = sq * (1.0f / D_MODEL) - mu * mu;
    float inv = rsqrtf(var + eps);
    float4 wv = ((const float4*)w)[t];
    float4 bv = ((const float4*)b)[t];
    s16x4 o;
    o.x = f2bf((v.x - mu) * inv * wv.x + bv.x);
    o.y = f2bf((v.y - mu) * inv * wv.y + bv.y);
    o.z = f2bf((v.z - mu) * inv * wv.z + bv.z);
    o.w = f2bf((v.w - mu) * inv * wv.w + bv.w);
    *(s16x4*)(out + (size_t)row * D_MODEL + 4 * t) = o;
}

// ---------------------------------------------------------------------------
// Transpose + cast: dst[n][k] (bf16, [NPAD][KPAD]) = src[k][coloff+n] (fp32)
// ---------------------------------------------------------------------------
__global__ void transpose_f2b(const float* __restrict__ src, int ldsrc, int coloff,
                              int nvalid, int kvalid, int KPAD,
                              short* __restrict__ dst)
{
    __shared__ float tile[32][33];
    int k0 = blockIdx.x * 32, n0 = blockIdx.y * 32;
    int tx = threadIdx.x, ty = threadIdx.y;
#pragma unroll
    for (int i = 0; i < 32; i += 8) {
        int k = k0 + ty + i, n = n0 + tx;
        tile[ty + i][tx] = (k < kvalid && n < nvalid) ? src[(size_t)k * ldsrc + coloff + n] : 0.0f;
    }
    __syncthreads();
#pragma unroll
    for (int i = 0; i < 32; i += 8) {
        int n = n0 + ty + i, k = k0 + tx;
        dst[(size_t)n * KPAD + k] = f2bf(tile[tx][ty + i]);
    }
}

// ---------------------------------------------------------------------------
// bf16 MFMA GEMM, double-buffered prefetch (1 barrier / k-iter):
// C[M,N] = A[M,K] @ Bt[N,K]^T (+bias)(+R). 128x128 tile, BK=32, 4 waves 2x2.
// EPI: 0 = bf16 store; 1 = fp32 + R; 2 = fp32 + bias + R
// ---------------------------------------------------------------------------
template<int EPI>
__global__ __launch_bounds__(256) void gemm_bt(
        const short* __restrict__ A, int lda,
        const short* __restrict__ Bt,
        const float* __restrict__ bias,
        const float* __restrict__ R, int ldr,
        void* __restrict__ C, int ldc, int K)
{
    __shared__ short As[2][4096];
    __shared__ short Bs[2][4096];
    int bm = blockIdx.y * 128;
    int bn = blockIdx.x * 128;
    int t = threadIdx.x;
    int w = t >> 6;
    int lane = t & 63;
    int quad = lane >> 4;
    int l15  = lane & 15;

    const short* gA0 = A  + (size_t)(bm + (t >> 2)) * lda + ((t & 3) << 3);
    const short* gA1 = gA0 + (size_t)64 * lda;
    const short* gB0 = Bt + (size_t)(bn + (t >> 2)) * K + ((t & 3) << 3);
    const short* gB1 = gB0 + (size_t)64 * K;
    int wb = w << 9;   // wave staging base (shorts)

    int wr = (w >> 1) * 64;
    int wc = (w & 1) * 64;

    f32x4 acc[4][4];
#pragma unroll
    for (int i = 0; i < 4; ++i)
#pragma unroll
        for (int j = 0; j < 4; ++j) acc[i][j] = (f32x4){0.f, 0.f, 0.f, 0.f};

    // prologue: stage k0=0 into buf 0
    GLD16(gA0, &As[0][wb]);
    GLD16(gA1, &As[0][2048 + wb]);
    GLD16(gB0, &Bs[0][wb]);
    GLD16(gB1, &Bs[0][2048 + wb]);

    for (int k0 = 0; k0 < K; k0 += 32) {
        int cur = (k0 >> 5) & 1;
        __syncthreads();                 // drains GLD for buf[cur]; protects buf[cur^1]
        int k1 = k0 + 32;
        if (k1 < K) {                    // prefetch next chunk, overlaps compute below
            GLD16(gA0 + k1, &As[cur ^ 1][wb]);
            GLD16(gA1 + k1, &As[cur ^ 1][2048 + wb]);
            GLD16(gB0 + k1, &Bs[cur ^ 1][wb]);
            GLD16(gB1 + k1, &Bs[cur ^ 1][2048 + wb]);
        }
        bf16x8 af[4], bfr[4];
#pragma unroll
        for (int i = 0; i < 4; ++i)
            af[i] = *(const bf16x8*)(&As[cur][(wr + i * 16 + l15) * 32 + quad * 8]);
#pragma unroll
        for (int j = 0; j < 4; ++j)
            bfr[j] = *(const bf16x8*)(&Bs[cur][(wc + j * 16 + l15) * 32 + quad * 8]);
#pragma unroll
        for (int i = 0; i < 4; ++i)
#pragma unroll
            for (int j = 0; j < 4; ++j)
                acc[i][j] = __builtin_amdgcn_mfma_f32_16x16x32_bf16(af[i], bfr[j], acc[i][j], 0, 0, 0);
    }

#pragma unroll
    for (int i = 0; i < 4; ++i) {
        int gr = bm + wr + i * 16 + quad * 4;
#pragma unroll
        for (int j = 0; j < 4; ++j) {
            int gc = bn + wc + j * 16 + l15;
#pragma unroll
            for (int r = 0; r < 4; ++r) {
                float val = acc[i][j][r];
                size_t idx = (size_t)(gr + r) * ldc + gc;
                if (EPI == 0) {
                    ((short*)C)[idx] = f2bf(val);
                } else if (EPI == 1) {
                    ((float*)C)[idx] = val + R[(size_t)(gr + r) * ldr + gc];
                } else {
                    ((float*)C)[idx] = val + bias[gc] + R[(size_t)(gr + r) * ldr + gc];
                }
            }
        }
    }
}

// ---------------------------------------------------------------------------
// Fused SwiGLU-in GEMM (MFMA), 128x64 tile, double-buffered prefetch.
// ---------------------------------------------------------------------------
__global__ __launch_bounds__(256) void mlp_fused(
        const short* __restrict__ A,       // [NTOK][1024] bf16
        const short* __restrict__ w_inT,   // [2*HID_PAD][1024] bf16
        const float* __restrict__ b_in,    // [2*HID]
        short* __restrict__ hm)            // [NTOK][HID_PAD] bf16
{
    __shared__ short As[2][4096];
    __shared__ short Ba[2][2048];
    __shared__ short Bb[2][2048];
    const int K = D_MODEL;
    int bm = blockIdx.y * 128;
    int bn = blockIdx.x * 64;
    int t = threadIdx.x;
    int w = t >> 6;
    int lane = t & 63;
    int quad = lane >> 4;
    int l15  = lane & 15;

    const short* gA0 = A + (size_t)(bm + (t >> 2)) * K + ((t & 3) << 3);
    const short* gA1 = gA0 + (size_t)64 * K;
    const short* gBa = w_inT + (size_t)(bn + (t >> 2)) * K + ((t & 3) << 3);
    const short* gBb = gBa + (size_t)HID_PAD * K;
    int wb = w << 9;

    int wr = (w >> 1) * 64;
    int wc = (w & 1) * 32;

    f32x4 acca[4][2], accb[4][2];
#pragma unroll
    for (int i = 0; i < 4; ++i)
#pragma unroll
        for (int j = 0; j < 2; ++j) {
            acca[i][j] = (f32x4){0.f, 0.f, 0.f, 0.f};
            accb[i][j] = (f32x4){0.f, 0.f, 0.f, 0.f};
        }

    GLD16(gA0, &As[0][wb]);
    GLD16(gA1, &As[0][2048 + wb]);
    GLD16(gBa, &Ba[0][wb]);
    GLD16(gBb, &Bb[0][wb]);

    for (int k0 = 0; k0 < K; k0 += 32) {
        int cur = (k0 >> 5) & 1;
        __syncthreads();
        int k1 = k0 + 32;
        if (k1 < K) {
            GLD16(gA0 + k1, &As[cur ^ 1][wb]);
            GLD16(gA1 + k1, &As[cur ^ 1][2048 + wb]);
            GLD16(gBa + k1, &Ba[cur ^ 1][wb]);
            GLD16(gBb + k1, &Bb[cur ^ 1][wb]);
        }
        bf16x8 af[4], baf[2], bbf[2];
#pragma unroll
        for (int i = 0; i < 4; ++i)
            af[i] = *(const bf16x8*)(&As[cur][(wr + i * 16 + l15) * 32 + quad * 8]);
#pragma unroll
        for (int j = 0; j < 2; ++j) {
            baf[j] = *(const bf16x8*)(&Ba[cur][(wc + j * 16 + l15) * 32 + quad * 8]);
            bbf[j] = *(const bf16x8*)(&Bb[cur][(wc + j * 16 + l15) * 32 + quad * 8]);
        }
#pragma unroll
        for (int i = 0; i < 4; ++i)
#pragma unroll
            for (int j = 0; j < 2; ++j) {
                acca[i][j] = __builtin_amdgcn_mfma_f32_16x16x32_bf16(af[i], baf[j], acca[i][j], 0, 0, 0);
                accb[i][j] = __builtin_amdgcn_mfma_f32_16x16x32_bf16(af[i], bbf[j], accb[i][j], 0, 0, 0);
            }
    }

#pragma unroll
    for (int i = 0; i < 4; ++i) {
        int gr = bm + wr + i * 16 + quad * 4;
#pragma unroll
        for (int j = 0; j < 2; ++j) {
            int gc = bn + wc + j * 16 + l15;
            bool ok = gc < HID;
            float ba = ok ? b_in[gc] : 0.0f;
            float bb = ok ? b_in[HID + gc] : 0.0f;
#pragma unroll
            for (int r = 0; r < 4; ++r) {
                float a  = acca[i][j][r] + ba;
                float bv = accb[i][j][r] + bb;
                float val = ok ? a * (bv / (1.0f + expf(-bv))) : 0.0f;
                hm[(size_t)(gr + r) * HID_PAD + gc] = f2bf(val);
            }
        }
    }
}

// ---------------------------------------------------------------------------
// MFMA retention + groupnorm + silu gate. Double-buffered K/V staging,
// factorized decay (4 exp2f/tile), heavy-first block order.
// qkg: [NTOK][3072] bf16: cols [0,1024)=q, [1024,2048)=k, [2048,3072)=g.
// vT:  [1024][NTOK]  bf16: row d = h*64+dd, col = token (V transposed).
// ---------------------------------------------------------------------------
#define PSTR 72   // ps row stride in shorts

__global__ __launch_bounds__(256) void retention_mfma(
        const short* __restrict__ qkg,
        const short* __restrict__ vT,
        short* __restrict__ rg)
{
    int qb = (int)gridDim.x - 1 - (int)blockIdx.x;   // heavy blocks first
    int h  = blockIdx.y;   // 0..15
    int b  = blockIdx.z;   // 0..1

    __shared__ short ks[2][2][2048];      // [buf][d-chunk][64 t x 32 d]
    __shared__ short vt[2][2][2048];      // [buf][t-chunk][64 d x 32 t]
    __shared__ short ps[4][16 * PSTR];    // per-wave P tile, [s][t]

    int tid  = threadIdx.x;
    int wave = tid >> 6;
    int lane = tid & 63;
    int quad = lane >> 4;
    int l15  = lane & 15;

    float log2g = log1pf(-exp2f(-5.0f - (float)h)) * 1.4426950408889634f;
    int hcol = h * HDIM;
    int s0 = qb * 64;
    size_t tok0 = (size_t)b * SEQ;

    int srow = tid >> 2;            // 0..63
    int sc8  = (tid & 3) << 3;      // 0,8,16,24
    const short* kbase  = qkg + (tok0 + srow) * QKG + 1024 + hcol + sc8;
    const short* vtbase = vT + (size_t)(hcol + srow) * NTOK + tok0 + sc8;
    int lb = tid << 3;              // lds staging offset (shorts)

    // Q A-fragments for the wave's 16 rows
    const short* qrow = qkg + (tok0 + s0 + wave * 16 + l15) * QKG + hcol;
    bf16x8 qa0 = *(const bf16x8*)(qrow + quad * 8);
    bf16x8 qa1 = *(const bf16x8*)(qrow + 32 + quad * 8);

    // decay column factors: gamma^-(tile*16 + l15)
    float colfac[4];
#pragma unroll
    for (int tile = 0; tile < 4; ++tile)
        colfac[tile] = exp2f(-(float)(tile * 16 + l15) * log2g);

    f32x4 oacc[4];
#pragma unroll
    for (int i = 0; i < 4; ++i) oacc[i] = (f32x4){0.f, 0.f, 0.f, 0.f};

    int sbase = s0 + wave * 16 + quad * 4;   // s of reg 0

    // prologue: stage tile 0 into buf 0
    GLD16(kbase, &ks[0][0][lb]);
    GLD16(kbase + 32, &ks[0][1][lb]);
    GLD16(vtbase, &vt[0][0][lb]);
    GLD16(vtbase + 32, &vt[0][1][lb]);

    for (int tb = 0; tb <= qb; ++tb) {
        int cur = tb & 1;
        __syncthreads();                 // buf[cur] staged; buf[cur^1] readers done
        if (tb < qb) {                   // prefetch next tile
            size_t koff = (size_t)(tb + 1) * 64 * QKG;
            int vcol = (tb + 1) * 64;
            GLD16(kbase + koff, &ks[cur ^ 1][0][lb]);
            GLD16(kbase + koff + 32, &ks[cur ^ 1][1][lb]);
            GLD16(vtbase + vcol, &vt[cur ^ 1][0][lb]);
            GLD16(vtbase + vcol + 32, &vt[cur ^ 1][1][lb]);
        }

        // scores: S[s][t] for 4 t-tiles of 16
        f32x4 sacc[4];
#pragma unroll
        for (int i = 0; i < 4; ++i) sacc[i] = (f32x4){0.f, 0.f, 0.f, 0.f};
#pragma unroll
        for (int tile = 0; tile < 4; ++tile) {
            bf16x8 kb0 = *(const bf16x8*)(&ks[cur][0][(tile * 16 + l15) * 32 + quad * 8]);
            bf16x8 kb1 = *(const bf16x8*)(&ks[cur][1][(tile * 16 + l15) * 32 + quad * 8]);
            sacc[tile] = __builtin_amdgcn_mfma_f32_16x16x32_bf16(qa0, kb0, sacc[tile], 0, 0, 0);
            sacc[tile] = __builtin_amdgcn_mfma_f32_16x16x32_bf16(qa1, kb1, sacc[tile], 0, 0, 0);
        }

        // decay: gamma^(s-t) = rowfac(s - 64 tb) * colfac(t - 64 tb); 0.125 q-scale folded in
        int fbi = sbase - tb * 64;
        float rf[4];
#pragma unroll
        for (int reg = 0; reg < 4; ++reg)
            rf[reg] = exp2f((float)(fbi + reg) * log2g) * 0.125f;

        if (tb == qb) {        // diagonal tile: apply causal mask
#pragma unroll
            for (int tile = 0; tile < 4; ++tile) {
                int tt = tile * 16 + l15;
#pragma unroll
                for (int reg = 0; reg < 4; ++reg) {
                    float p = (fbi + reg >= tt) ? sacc[tile][reg] * rf[reg] * colfac[tile] : 0.0f;
                    ps[wave][(quad * 4 + reg) * PSTR + tile * 16 + l15] = f2bf(p);
                }
            }
        } else {
#pragma unroll
            for (int tile = 0; tile < 4; ++tile)
#pragma unroll
                for (int reg = 0; reg < 4; ++reg)
                    ps[wave][(quad * 4 + reg) * PSTR + tile * 16 + l15] =
                        f2bf(sacc[tile][reg] * (rf[reg] * colfac[tile]));
        }

        // PV: out[s][d] += P[s][t] * V[t][d]  (wave-private P, no barrier)
#pragma unroll
        for (int ksi = 0; ksi < 2; ++ksi) {
            bf16x8 pa = *(const bf16x8*)(&ps[wave][l15 * PSTR + ksi * 32 + quad * 8]);
#pragma unroll
            for (int dt = 0; dt < 4; ++dt) {
                bf16x8 vb = *(const bf16x8*)(&vt[cur][ksi][(dt * 16 + l15) * 32 + quad * 8]);
                oacc[dt] = __builtin_amdgcn_mfma_f32_16x16x32_bf16(pa, vb, oacc[dt], 0, 0, 0);
            }
        }
    }

    // groupnorm over d=64 per s-row
    float s1[4], s2[4];
#pragma unroll
    for (int reg = 0; reg < 4; ++reg) {
        s1[reg] = oacc[0][reg] + oacc[1][reg] + oacc[2][reg] + oacc[3][reg];
        s2[reg] = oacc[0][reg] * oacc[0][reg] + oacc[1][reg] * oacc[1][reg]
                + oacc[2][reg] * oacc[2][reg] + oacc[3][reg] * oacc[3][reg];
    }
#pragma unroll
    for (int off = 1; off < 16; off <<= 1) {
#pragma unroll
        for (int reg = 0; reg < 4; ++reg) {
            s1[reg] += __shfl_xor(s1[reg], off);
            s2[reg] += __shfl_xor(s2[reg], off);
        }
    }
    size_t rowtok = tok0 + s0 + wave * 16 + quad * 4;
    short* obase = rg + rowtok * D_MODEL + hcol;
    const short* gbase = qkg + rowtok * QKG + 2048 + hcol;
#pragma unroll
    for (int reg = 0; reg < 4; ++reg) {
        float mu  = s1[reg] * (1.0f / 64.0f);
        float var = s2[reg] * (1.0f / 64.0f) - mu * mu;
        float inv = rsqrtf(var + 1e-6f);
#pragma unroll
        for (int dt = 0; dt < 4; ++dt) {
            float gv = bf2f(gbase[(size_t)reg * QKG + dt * 16 + l15]);
            float val = (oacc[dt][reg] - mu) * inv * (gv / (1.0f + expf(-gv)));
            obase[(size_t)reg * D_MODEL + dt * 16 + l15] = f2bf(val);
        }
    }
}

// ---------------------------------------------------------------------------
extern "C" void kernel_launch(void* const* d_in, const int* in_sizes, int n_in,
                              void* d_out, int out_size, void* d_ws, size_t ws_size,
                              hipStream_t stream)
{
    const float* x     = (const float*)d_in[0];
    const float* ln1w  = (const float*)d_in[1];
    const float* ln1b  = (const float*)d_in[2];
    const float* wq    = (const float*)d_in[3];
    const float* wk    = (const float*)d_in[4];
    const float* wv    = (const float*)d_in[5];
    const float* wg    = (const float*)d_in[6];
    const float* wo    = (const float*)d_in[7];
    const float* ln2w  = (const float*)d_in[8];
    const float* ln2b  = (const float*)d_in[9];
    const float* w_in  = (const float*)d_in[10];
    const float* b_in  = (const float*)d_in[11];
    const float* w_out = (const float*)d_in[12];
    const float* b_out = (const float*)d_in[13];
    float* out = (float*)d_out;
    char* base = (char*)d_ws;

    const size_t MB = 1u << 20;
    short* xn     = (short*)(base);            // [0,8)   [4096][1024] bf16 LN out
    short* qkgT   = (short*)(base +  8 * MB);  // [8,14)  wq|wk|wg transposed [3072][1024]
    short* wvT    = (short*)(base + 14 * MB);  // [14,16) [1024][1024]
    short* woT    = (short*)(base + 16 * MB);  // [16,18) [1024][1024]
    short* w_inT  = (short*)(base + 18 * MB);  // [18,29) [5632][1024]
    short* w_outT = (short*)(base + 29 * MB);  // [29,34.5) [1024][2816]
    short* qkg    = (short*)(base + 35 * MB);  // [35,59) [4096][3072] packed q|k|g
    short* hm     = (short*)(base + 35 * MB);  // [35,57) [4096][2816] reuses dead qkg
    short* vT     = (short*)(base + 59 * MB);  // [59,67) [1024][4096] V transposed
    short* rg     = (short*)(base + 67 * MB);  // [67,75) [4096][1024] gated retention out

    dim3 tb(32, 8);
    transpose_f2b<<<dim3(32, 32), tb, 0, stream>>>(wq, 1024, 0, 1024, 1024, 1024, qkgT);
    transpose_f2b<<<dim3(32, 32), tb, 0, stream>>>(wk, 1024, 0, 1024, 1024, 1024, qkgT + 1024 * 1024);
    transpose_f2b<<<dim3(32, 32), tb, 0, stream>>>(wg, 1024, 0, 1024, 1024, 1024, qkgT + 2 * 1024 * 1024);
    transpose_f2b<<<dim3(32, 32), tb, 0, stream>>>(wv, 1024, 0, 1024, 1024, 1024, wvT);
    transpose_f2b<<<dim3(32, 32), tb, 0, stream>>>(wo, 1024, 0, 1024, 1024, 1024, woT);
    transpose_f2b<<<dim3(32, 88), tb, 0, stream>>>(w_in, 2 * HID, 0,   HID, 1024, 1024, w_inT);
    transpose_f2b<<<dim3(32, 88), tb, 0, stream>>>(w_in, 2 * HID, HID, HID, 1024, 1024, w_inT + (size_t)HID_PAD * 1024);
    transpose_f2b<<<dim3(88, 32), tb, 0, stream>>>(w_out, 1024, 0, 1024, HID, HID_PAD, w_outT);

    // LN1 -> bf16
    ln_kernel<<<NTOK, 256, 0, stream>>>(x, ln1w, ln1b, xn, 1e-5f);
    // packed q|k|g projection
    gemm_bt<0><<<dim3(QKG / 128, 32), 256, 0, stream>>>(xn, D_MODEL, qkgT, nullptr, nullptr, 0, qkg, QKG, D_MODEL);
    // v^T projection (A/B swapped => transposed output)
    gemm_bt<0><<<dim3(NTOK / 128, 8), 256, 0, stream>>>(wvT, D_MODEL, xn, nullptr, nullptr, 0, vT, NTOK, D_MODEL);
    // retention + groupnorm + silu gate
    retention_mfma<<<dim3(SEQ / 64, NHEAD, BATCH), 256, 0, stream>>>(qkg, vT, rg);
    // wo projection + residual x -> out (fp32)
    gemm_bt<1><<<dim3(8, 32), 256, 0, stream>>>(rg, D_MODEL, woT, nullptr, x, D_MODEL, out, D_MODEL, D_MODEL);
    // LN2 -> bf16
    ln_kernel<<<NTOK, 256, 0, stream>>>(out, ln2w, ln2b, xn, 1e-5f);
    // fused SwiGLU-in GEMM -> hm bf16, 128x64 tiles
    mlp_fused<<<dim3(HID_PAD / 64, NTOK / 128), 256, 0, stream>>>(xn, w_inT, b_in, hm);
    // w_out GEMM + bias + residual
    gemm_bt<2><<<dim3(8, 32), 256, 0, stream>>>(hm, HID_PAD, w_outT, b_out, out, D_MODEL, out, D_MODEL, HID_PAD);
}

// Round 7
// 442.851 us; speedup vs baseline: 14.6412x; 1.0488x over previous
//
#include <hip/hip_runtime.h>
#include <math.h>

#define D_MODEL 1024
#define NHEAD   16
#define HDIM    64
#define HID     2730
#define HID_PAD 2816          // 22 * 128
#define SEQ     2048
#define BATCH   2
#define NTOK    (BATCH * SEQ)   // 4096
#define QKG     3072            // packed q|k|g row stride (elements)

typedef __attribute__((ext_vector_type(8))) short bf16x8;
typedef __attribute__((ext_vector_type(4))) float f32x4;
typedef __attribute__((ext_vector_type(4))) short s16x4;

// fp32 -> bf16 round-to-nearest-even
static __device__ inline short f2bf(float f)
{
    union { float f; unsigned int u; } c; c.f = f;
    unsigned int r = c.u + 0x7FFFu + ((c.u >> 16) & 1u);
    return (short)(r >> 16);
}
static __device__ inline float bf2f(short s)
{
    union { unsigned int u; float f; } c;
    c.u = ((unsigned int)(unsigned short)s) << 16;
    return c.f;
}

// async global->LDS, 16B per lane; lds dest = wave-uniform base + lane*16
#define GLD16(gsrc, ldst) \
    __builtin_amdgcn_global_load_lds((const __attribute__((address_space(1))) void*)(gsrc), \
                                     (__attribute__((address_space(3))) void*)(ldst), 16, 0, 0)

// ---------------------------------------------------------------------------
// LayerNorm: one block (256 threads) per row of 1024, fp32 in -> bf16 out
// ---------------------------------------------------------------------------
__global__ void ln_kernel(const float* __restrict__ x,
                          const float* __restrict__ w,
                          const float* __restrict__ b,
                          short* __restrict__ out,
                          float eps)
{
    int row = blockIdx.x;
    int t = threadIdx.x;               // 0..255
    const float4* xr = (const float4*)(x + (size_t)row * D_MODEL);
    float4 v = xr[t];
    float s  = v.x + v.y + v.z + v.w;
    float sq = v.x * v.x + v.y * v.y + v.z * v.z + v.w * v.w;
#pragma unroll
    for (int off = 32; off > 0; off >>= 1) {
        s  += __shfl_xor(s, off);
        sq += __shfl_xor(sq, off);
    }
    __shared__ float ss[4], ssq[4];
    int wave = t >> 6;
    if ((t & 63) == 0) { ss[wave] = s; ssq[wave] = sq; }
    __syncthreads();
    s  = ss[0] + ss[1] + ss[2] + ss[3];
    sq = ssq[0] + ssq[1] + ssq[2] + ssq[3];
    float mu  = s * (1.0f / D_MODEL);
    float var = sq * (1.0f / D_MODEL) - mu * mu;
    float inv = rsqrtf(var + eps);
    float4 wv = ((const float4*)w)[t];
    float4 bv = ((const float4*)b)[t];
    s16x4 o;
    o.x = f2bf((v.x - mu) * inv * wv.x + bv.x);
    o.y = f2bf((v.y - mu) * inv * wv.y + bv.y);
    o.z = f2bf((v.z - mu) * inv * wv.z + bv.z);
    o.w = f2bf((v.w - mu) * inv * wv.w + bv.w);
    *(s16x4*)(out + (size_t)row * D_MODEL + 4 * t) = o;
}

// ---------------------------------------------------------------------------
// Transpose + cast: dst[n][k] (bf16, [NPAD][KPAD]) = src[k][coloff+n] (fp32)
// ---------------------------------------------------------------------------
__global__ void transpose_f2b(const float* __restrict__ src, int ldsrc, int coloff,
                              int nvalid, int kvalid, int KPAD,
                              short* __restrict__ dst)
{
    __shared__ float tile[32][33];
    int k0 = blockIdx.x * 32, n0 = blockIdx.y * 32;
    int tx = threadIdx.x, ty = threadIdx.y;
#pragma unroll
    for (int i = 0; i < 32; i += 8) {
        int k = k0 + ty + i, n = n0 + tx;
        tile[ty + i][tx] = (k < kvalid && n < nvalid) ? src[(size_t)k * ldsrc + coloff + n] : 0.0f;
    }
    __syncthreads();
#pragma unroll
    for (int i = 0; i < 32; i += 8) {
        int n = n0 + ty + i, k = k0 + tx;
        dst[(size_t)n * KPAD + k] = f2bf(tile[tx][ty + i]);
    }
}

// ---------------------------------------------------------------------------
// bf16 MFMA GEMM, double-buffered prefetch (1 barrier / k-iter):
// C[M,N] = A[M,K] @ Bt[N,K]^T (+bias)(+R). 128x128 tile, BK=32, 4 waves 2x2.
// EPI: 0 = bf16 store; 1 = fp32 + R; 2 = fp32 + bias + R
// ---------------------------------------------------------------------------
template<int EPI>
__global__ __launch_bounds__(256) void gemm_bt(
        const short* __restrict__ A, int lda,
        const short* __restrict__ Bt,
        const float* __restrict__ bias,
        const float* __restrict__ R, int ldr,
        void* __restrict__ C, int ldc, int K)
{
    __shared__ short As[2][4096];
    __shared__ short Bs[2][4096];
    int bm = blockIdx.y * 128;
    int bn = blockIdx.x * 128;
    int t = threadIdx.x;
    int w = t >> 6;
    int lane = t & 63;
    int quad = lane >> 4;
    int l15  = lane & 15;

    const short* gA0 = A  + (size_t)(bm + (t >> 2)) * lda + ((t & 3) << 3);
    const short* gA1 = gA0 + (size_t)64 * lda;
    const short* gB0 = Bt + (size_t)(bn + (t >> 2)) * K + ((t & 3) << 3);
    const short* gB1 = gB0 + (size_t)64 * K;
    int wb = w << 9;   // wave staging base (shorts)

    int wr = (w >> 1) * 64;
    int wc = (w & 1) * 64;

    f32x4 acc[4][4];
#pragma unroll
    for (int i = 0; i < 4; ++i)
#pragma unroll
        for (int j = 0; j < 4; ++j) acc[i][j] = (f32x4){0.f, 0.f, 0.f, 0.f};

    // prologue: stage k0=0 into buf 0
    GLD16(gA0, &As[0][wb]);
    GLD16(gA1, &As[0][2048 + wb]);
    GLD16(gB0, &Bs[0][wb]);
    GLD16(gB1, &Bs[0][2048 + wb]);

    for (int k0 = 0; k0 < K; k0 += 32) {
        int cur = (k0 >> 5) & 1;
        __syncthreads();                 // drains GLD for buf[cur]; protects buf[cur^1]
        int k1 = k0 + 32;
        if (k1 < K) {                    // prefetch next chunk, overlaps compute below
            GLD16(gA0 + k1, &As[cur ^ 1][wb]);
            GLD16(gA1 + k1, &As[cur ^ 1][2048 + wb]);
            GLD16(gB0 + k1, &Bs[cur ^ 1][wb]);
            GLD16(gB1 + k1, &Bs[cur ^ 1][2048 + wb]);
        }
        bf16x8 af[4], bfr[4];
#pragma unroll
        for (int i = 0; i < 4; ++i)
            af[i] = *(const bf16x8*)(&As[cur][(wr + i * 16 + l15) * 32 + quad * 8]);
#pragma unroll
        for (int j = 0; j < 4; ++j)
            bfr[j] = *(const bf16x8*)(&Bs[cur][(wc + j * 16 + l15) * 32 + quad * 8]);
#pragma unroll
        for (int i = 0; i < 4; ++i)
#pragma unroll
            for (int j = 0; j < 4; ++j)
                acc[i][j] = __builtin_amdgcn_mfma_f32_16x16x32_bf16(af[i], bfr[j], acc[i][j], 0, 0, 0);
    }

#pragma unroll
    for (int i = 0; i < 4; ++i) {
        int gr = bm + wr + i * 16 + quad * 4;
#pragma unroll
        for (int j = 0; j < 4; ++j) {
            int gc = bn + wc + j * 16 + l15;
#pragma unroll
            for (int r = 0; r < 4; ++r) {
                float val = acc[i][j][r];
                size_t idx = (size_t)(gr + r) * ldc + gc;
                if (EPI == 0) {
                    ((short*)C)[idx] = f2bf(val);
                } else if (EPI == 1) {
                    ((float*)C)[idx] = val + R[(size_t)(gr + r) * ldr + gc];
                } else {
                    ((float*)C)[idx] = val + bias[gc] + R[(size_t)(gr + r) * ldr + gc];
                }
            }
        }
    }
}

// ---------------------------------------------------------------------------
// Fused SwiGLU-in GEMM (MFMA), 128x64 tile, double-buffered prefetch.
// ---------------------------------------------------------------------------
__global__ __launch_bounds__(256) void mlp_fused(
        const short* __restrict__ A,       // [NTOK][1024] bf16
        const short* __restrict__ w_inT,   // [2*HID_PAD][1024] bf16
        const float* __restrict__ b_in,    // [2*HID]
        short* __restrict__ hm)            // [NTOK][HID_PAD] bf16
{
    __shared__ short As[2][4096];
    __shared__ short Ba[2][2048];
    __shared__ short Bb[2][2048];
    const int K = D_MODEL;
    int bm = blockIdx.y * 128;
    int bn = blockIdx.x * 64;
    int t = threadIdx.x;
    int w = t >> 6;
    int lane = t & 63;
    int quad = lane >> 4;
    int l15  = lane & 15;

    const short* gA0 = A + (size_t)(bm + (t >> 2)) * K + ((t & 3) << 3);
    const short* gA1 = gA0 + (size_t)64 * K;
    const short* gBa = w_inT + (size_t)(bn + (t >> 2)) * K + ((t & 3) << 3);
    const short* gBb = gBa + (size_t)HID_PAD * K;
    int wb = w << 9;

    int wr = (w >> 1) * 64;
    int wc = (w & 1) * 32;

    f32x4 acca[4][2], accb[4][2];
#pragma unroll
    for (int i = 0; i < 4; ++i)
#pragma unroll
        for (int j = 0; j < 2; ++j) {
            acca[i][j] = (f32x4){0.f, 0.f, 0.f, 0.f};
            accb[i][j] = (f32x4){0.f, 0.f, 0.f, 0.f};
        }

    GLD16(gA0, &As[0][wb]);
    GLD16(gA1, &As[0][2048 + wb]);
    GLD16(gBa, &Ba[0][wb]);
    GLD16(gBb, &Bb[0][wb]);

    for (int k0 = 0; k0 < K; k0 += 32) {
        int cur = (k0 >> 5) & 1;
        __syncthreads();
        int k1 = k0 + 32;
        if (k1 < K) {
            GLD16(gA0 + k1, &As[cur ^ 1][wb]);
            GLD16(gA1 + k1, &As[cur ^ 1][2048 + wb]);
            GLD16(gBa + k1, &Ba[cur ^ 1][wb]);
            GLD16(gBb + k1, &Bb[cur ^ 1][wb]);
        }
        bf16x8 af[4], baf[2], bbf[2];
#pragma unroll
        for (int i = 0; i < 4; ++i)
            af[i] = *(const bf16x8*)(&As[cur][(wr + i * 16 + l15) * 32 + quad * 8]);
#pragma unroll
        for (int j = 0; j < 2; ++j) {
            baf[j] = *(const bf16x8*)(&Ba[cur][(wc + j * 16 + l15) * 32 + quad * 8]);
            bbf[j] = *(const bf16x8*)(&Bb[cur][(wc + j * 16 + l15) * 32 + quad * 8]);
        }
#pragma unroll
        for (int i = 0; i < 4; ++i)
#pragma unroll
            for (int j = 0; j < 2; ++j) {
                acca[i][j] = __builtin_amdgcn_mfma_f32_16x16x32_bf16(af[i], baf[j], acca[i][j], 0, 0, 0);
                accb[i][j] = __builtin_amdgcn_mfma_f32_16x16x32_bf16(af[i], bbf[j], accb[i][j], 0, 0, 0);
            }
    }

#pragma unroll
    for (int i = 0; i < 4; ++i) {
        int gr = bm + wr + i * 16 + quad * 4;
#pragma unroll
        for (int j = 0; j < 2; ++j) {
            int gc = bn + wc + j * 16 + l15;
            bool ok = gc < HID;
            float ba = ok ? b_in[gc] : 0.0f;
            float bb = ok ? b_in[HID + gc] : 0.0f;
#pragma unroll
            for (int r = 0; r < 4; ++r) {
                float a  = acca[i][j][r] + ba;
                float bv = accb[i][j][r] + bb;
                float val = ok ? a * (bv / (1.0f + expf(-bv))) : 0.0f;
                hm[(size_t)(gr + r) * HID_PAD + gc] = f2bf(val);
            }
        }
    }
}

// ---------------------------------------------------------------------------
// MFMA retention + groupnorm + silu gate. 512 threads (8 waves), 128 q-rows
// per block: 8 waves share each staged K/V tile (2x the reuse of r6's 4),
// staging is one GLD16 per matrix per tile, barrier count halved.
// qkg: [NTOK][3072] bf16: cols [0,1024)=q, [1024,2048)=k, [2048,3072)=g.
// vT:  [1024][NTOK]  bf16: row d = h*64+dd, col = token (V transposed).
// ---------------------------------------------------------------------------
#define PSTR 72   // ps row stride in shorts

__global__ __launch_bounds__(512) void retention_mfma(
        const short* __restrict__ qkg,
        const short* __restrict__ vT,
        short* __restrict__ rg)
{
    int qb = (int)gridDim.x - 1 - (int)blockIdx.x;   // heavy blocks first
    int h  = blockIdx.y;   // 0..15
    int b  = blockIdx.z;   // 0..1

    __shared__ short ks[2][4096];         // [buf][d-chunk(2)][64 t][32 d]
    __shared__ short vt[2][4096];         // [buf][t-chunk(2)][64 d][32 t]
    __shared__ short ps[8][16 * PSTR];    // per-wave P tile, [s(16)][t(64)+pad]

    int tid  = threadIdx.x;               // 0..511 (8 waves, wave w owns rows w*16..+16)
    int w    = tid >> 6;
    int lane = tid & 63;
    int quad = lane >> 4;
    int l15  = lane & 15;

    float log2g = log1pf(-exp2f(-5.0f - (float)h)) * 1.4426950408889634f;
    int hcol = h * HDIM;
    int s0 = qb * 128;
    size_t tok0 = (size_t)b * SEQ;

    // staging: thread t -> chunk c = t>>8, row = (t>>2)&63, piece p = t&3
    int sch  = tid >> 8;                 // 0..1
    int srow = (tid >> 2) & 63;          // 0..63
    int sp8  = (tid & 3) << 3;           // 0,8,16,24
    const short* kbase  = qkg + (tok0 + srow) * QKG + 1024 + hcol + sch * 32 + sp8;
    const short* vtbase = vT + (size_t)(hcol + srow) * NTOK + tok0 + sch * 32 + sp8;
    int lb = tid << 3;                   // LDS staging offset (shorts): [c][64][32] layout

    // Q A-fragments for this wave's 16 rows
    const short* qrow = qkg + (tok0 + s0 + w * 16 + l15) * QKG + hcol;
    bf16x8 qa0 = *(const bf16x8*)(qrow + quad * 8);
    bf16x8 qa1 = *(const bf16x8*)(qrow + 32 + quad * 8);

    // decay column factors (0.125 q-scale folded in)
    float colfac[4];
#pragma unroll
    for (int tile = 0; tile < 4; ++tile)
        colfac[tile] = exp2f(-(float)(tile * 16 + l15) * log2g) * 0.125f;

    f32x4 oacc[4];
#pragma unroll
    for (int i = 0; i < 4; ++i) oacc[i] = (f32x4){0.f, 0.f, 0.f, 0.f};

    int sbase = s0 + w * 16 + quad * 4;   // s of reg 0
    int tmax = 2 * qb + 1;                // t-tiles 0..tmax (64 wide)

    // prologue: stage tile 0 into buf 0 (one GLD16 per matrix covers 64x64)
    GLD16(kbase, &ks[0][lb]);
    GLD16(vtbase, &vt[0][lb]);

    for (int tb = 0; tb <= tmax; ++tb) {
        int cur = tb & 1;
        __syncthreads();                 // buf[cur] staged; buf[cur^1] readers done
        if (tb < tmax) {                 // prefetch next tile
            GLD16(kbase + (size_t)(tb + 1) * 64 * QKG, &ks[cur ^ 1][lb]);
            GLD16(vtbase + (tb + 1) * 64, &vt[cur ^ 1][lb]);
        }

        // scores: S[s][t] for 4 t-tiles of 16
        f32x4 sacc[4];
#pragma unroll
        for (int i = 0; i < 4; ++i) sacc[i] = (f32x4){0.f, 0.f, 0.f, 0.f};
#pragma unroll
        for (int tile = 0; tile < 4; ++tile) {
            bf16x8 kb0 = *(const bf16x8*)(&ks[cur][(tile * 16 + l15) * 32 + quad * 8]);
            bf16x8 kb1 = *(const bf16x8*)(&ks[cur][2048 + (tile * 16 + l15) * 32 + quad * 8]);
            sacc[tile] = __builtin_amdgcn_mfma_f32_16x16x32_bf16(qa0, kb0, sacc[tile], 0, 0, 0);
            sacc[tile] = __builtin_amdgcn_mfma_f32_16x16x32_bf16(qa1, kb1, sacc[tile], 0, 0, 0);
        }

        // decay: gamma^(s-t) = rowfac(s-64tb) * colfac(t-64tb)
        int fbi = sbase - tb * 64;
        float rf[4];
#pragma unroll
        for (int reg = 0; reg < 4; ++reg)
            rf[reg] = exp2f((float)(fbi + reg) * log2g);

        if (tb * 64 + 63 > s0 + w * 16) {   // tile can reach above diagonal: mask
#pragma unroll
            for (int tile = 0; tile < 4; ++tile) {
                int tt = tile * 16 + l15;
#pragma unroll
                for (int reg = 0; reg < 4; ++reg) {
                    float p = (fbi + reg >= tt) ? sacc[tile][reg] * rf[reg] * colfac[tile] : 0.0f;
                    ps[w][(quad * 4 + reg) * PSTR + tile * 16 + l15] = f2bf(p);
                }
            }
        } else {
#pragma unroll
            for (int tile = 0; tile < 4; ++tile)
#pragma unroll
                for (int reg = 0; reg < 4; ++reg)
                    ps[w][(quad * 4 + reg) * PSTR + tile * 16 + l15] =
                        f2bf(sacc[tile][reg] * (rf[reg] * colfac[tile]));
        }

        // PV: out[s][d] += P[s][t] * V[t][d]  (wave-private P, no barrier)
#pragma unroll
        for (int ksi = 0; ksi < 2; ++ksi) {
            bf16x8 pa = *(const bf16x8*)(&ps[w][l15 * PSTR + ksi * 32 + quad * 8]);
#pragma unroll
            for (int dt = 0; dt < 4; ++dt) {
                bf16x8 vb = *(const bf16x8*)(&vt[cur][ksi * 2048 + (dt * 16 + l15) * 32 + quad * 8]);
                oacc[dt] = __builtin_amdgcn_mfma_f32_16x16x32_bf16(pa, vb, oacc[dt], 0, 0, 0);
            }
        }
    }

    // groupnorm over d=64 per s-row
    float s1[4], s2[4];
#pragma unroll
    for (int reg = 0; reg < 4; ++reg) {
        s1[reg] = oacc[0][reg] + oacc[1][reg] + oacc[2][reg] + oacc[3][reg];
        s2[reg] = oacc[0][reg] * oacc[0][reg] + oacc[1][reg] * oacc[1][reg]
                + oacc[2][reg] * oacc[2][reg] + oacc[3][reg] * oacc[3][reg];
    }
#pragma unroll
    for (int off = 1; off < 16; off <<= 1) {
#pragma unroll
        for (int reg = 0; reg < 4; ++reg) {
            s1[reg] += __shfl_xor(s1[reg], off);
            s2[reg] += __shfl_xor(s2[reg], off);
        }
    }
    size_t rowtok = tok0 + s0 + w * 16 + quad * 4;
    short* obase = rg + rowtok * D_MODEL + hcol;
    const short* gbase = qkg + rowtok * QKG + 2048 + hcol;
#pragma unroll
    for (int reg = 0; reg < 4; ++reg) {
        float mu  = s1[reg] * (1.0f / 64.0f);
        float var = s2[reg] * (1.0f / 64.0f) - mu * mu;
        float inv = rsqrtf(var + 1e-6f);
#pragma unroll
        for (int dt = 0; dt < 4; ++dt) {
            float gv = bf2f(gbase[(size_t)reg * QKG + dt * 16 + l15]);
            float val = (oacc[dt][reg] - mu) * inv * (gv / (1.0f + expf(-gv)));
            obase[(size_t)reg * D_MODEL + dt * 16 + l15] = f2bf(val);
        }
    }
}

// ---------------------------------------------------------------------------
extern "C" void kernel_launch(void* const* d_in, const int* in_sizes, int n_in,
                              void* d_out, int out_size, void* d_ws, size_t ws_size,
                              hipStream_t stream)
{
    const float* x     = (const float*)d_in[0];
    const float* ln1w  = (const float*)d_in[1];
    const float* ln1b  = (const float*)d_in[2];
    const float* wq    = (const float*)d_in[3];
    const float* wk    = (const float*)d_in[4];
    const float* wv    = (const float*)d_in[5];
    const float* wg    = (const float*)d_in[6];
    const float* wo    = (const float*)d_in[7];
    const float* ln2w  = (const float*)d_in[8];
    const float* ln2b  = (const float*)d_in[9];
    const float* w_in  = (const float*)d_in[10];
    const float* b_in  = (const float*)d_in[11];
    const float* w_out = (const float*)d_in[12];
    const float* b_out = (const float*)d_in[13];
    float* out = (float*)d_out;
    char* base = (char*)d_ws;

    const size_t MB = 1u << 20;
    short* xn     = (short*)(base);            // [0,8)   [4096][1024] bf16 LN out
    short* qkgT   = (short*)(base +  8 * MB);  // [8,14)  wq|wk|wg transposed [3072][1024]
    short* wvT    = (short*)(base + 14 * MB);  // [14,16) [1024][1024]
    short* woT    = (short*)(base + 16 * MB);  // [16,18) [1024][1024]
    short* w_inT  = (short*)(base + 18 * MB);  // [18,29) [5632][1024]
    short* w_outT = (short*)(base + 29 * MB);  // [29,34.5) [1024][2816]
    short* qkg    = (short*)(base + 35 * MB);  // [35,59) [4096][3072] packed q|k|g
    short* hm     = (short*)(base + 35 * MB);  // [35,57) [4096][2816] reuses dead qkg
    short* vT     = (short*)(base + 59 * MB);  // [59,67) [1024][4096] V transposed
    short* rg     = (short*)(base + 67 * MB);  // [67,75) [4096][1024] gated retention out

    dim3 tb(32, 8);
    transpose_f2b<<<dim3(32, 32), tb, 0, stream>>>(wq, 1024, 0, 1024, 1024, 1024, qkgT);
    transpose_f2b<<<dim3(32, 32), tb, 0, stream>>>(wk, 1024, 0, 1024, 1024, 1024, qkgT + 1024 * 1024);
    transpose_f2b<<<dim3(32, 32), tb, 0, stream>>>(wg, 1024, 0, 1024, 1024, 1024, qkgT + 2 * 1024 * 1024);
    transpose_f2b<<<dim3(32, 32), tb, 0, stream>>>(wv, 1024, 0, 1024, 1024, 1024, wvT);
    transpose_f2b<<<dim3(32, 32), tb, 0, stream>>>(wo, 1024, 0, 1024, 1024, 1024, woT);
    transpose_f2b<<<dim3(32, 88), tb, 0, stream>>>(w_in, 2 * HID, 0,   HID, 1024, 1024, w_inT);
    transpose_f2b<<<dim3(32, 88), tb, 0, stream>>>(w_in, 2 * HID, HID, HID, 1024, 1024, w_inT + (size_t)HID_PAD * 1024);
    transpose_f2b<<<dim3(88, 32), tb, 0, stream>>>(w_out, 1024, 0, 1024, HID, HID_PAD, w_outT);

    // LN1 -> bf16
    ln_kernel<<<NTOK, 256, 0, stream>>>(x, ln1w, ln1b, xn, 1e-5f);
    // packed q|k|g projection
    gemm_bt<0><<<dim3(QKG / 128, 32), 256, 0, stream>>>(xn, D_MODEL, qkgT, nullptr, nullptr, 0, qkg, QKG, D_MODEL);
    // v^T projection (A/B swapped => transposed output)
    gemm_bt<0><<<dim3(NTOK / 128, 8), 256, 0, stream>>>(wvT, D_MODEL, xn, nullptr, nullptr, 0, vT, NTOK, D_MODEL);
    // retention + groupnorm + silu gate: 512 thr, 128 q-rows/block
    retention_mfma<<<dim3(SEQ / 128, NHEAD, BATCH), 512, 0, stream>>>(qkg, vT, rg);
    // wo projection + residual x -> out (fp32)
    gemm_bt<1><<<dim3(8, 32), 256, 0, stream>>>(rg, D_MODEL, woT, nullptr, x, D_MODEL, out, D_MODEL, D_MODEL);
    // LN2 -> bf16
    ln_kernel<<<NTOK, 256, 0, stream>>>(out, ln2w, ln2b, xn, 1e-5f);
    // fused SwiGLU-in GEMM -> hm bf16, 128x64 tiles
    mlp_fused<<<dim3(HID_PAD / 64, NTOK / 128), 256, 0, stream>>>(xn, w_inT, b_in, hm);
    // w_out GEMM + bias + residual
    gemm_bt<2><<<dim3(8, 32), 256, 0, stream>>>(hm, HID_PAD, w_outT, b_out, out, D_MODEL, out, D_MODEL, HID_PAD);
}

// Round 8
// 433.495 us; speedup vs baseline: 14.9572x; 1.0216x over previous
//
#include <hip/hip_runtime.h>
#include <math.h>

#define D_MODEL 1024
#define NHEAD   16
#define HDIM    64
#define HID     2730
#define HID_PAD 2816          // 22 * 128
#define SEQ     2048
#define BATCH   2
#define NTOK    (BATCH * SEQ)   // 4096
#define QKG     3072            // packed q|k|g row stride (elements)

typedef __attribute__((ext_vector_type(8))) short bf16x8;
typedef __attribute__((ext_vector_type(4))) float f32x4;
typedef __attribute__((ext_vector_type(4))) short s16x4;

// fp32 -> bf16 round-to-nearest-even
static __device__ inline short f2bf(float f)
{
    union { float f; unsigned int u; } c; c.f = f;
    unsigned int r = c.u + 0x7FFFu + ((c.u >> 16) & 1u);
    return (short)(r >> 16);
}
static __device__ inline float bf2f(short s)
{
    union { unsigned int u; float f; } c;
    c.u = ((unsigned int)(unsigned short)s) << 16;
    return c.f;
}

// async global->LDS, 16B per lane; lds dest = wave-uniform base + lane*16
#define GLD16(gsrc, ldst) \
    __builtin_amdgcn_global_load_lds((const __attribute__((address_space(1))) void*)(gsrc), \
                                     (__attribute__((address_space(3))) void*)(ldst), 16, 0, 0)

// ---------------------------------------------------------------------------
// LayerNorm: one block (256 threads) per row of 1024, fp32 in -> bf16 out
// ---------------------------------------------------------------------------
__global__ void ln_kernel(const float* __restrict__ x,
                          const float* __restrict__ w,
                          const float* __restrict__ b,
                          short* __restrict__ out,
                          float eps)
{
    int row = blockIdx.x;
    int t = threadIdx.x;               // 0..255
    const float4* xr = (const float4*)(x + (size_t)row * D_MODEL);
    float4 v = xr[t];
    float s  = v.x + v.y + v.z + v.w;
    float sq = v.x * v.x + v.y * v.y + v.z * v.z + v.w * v.w;
#pragma unroll
    for (int off = 32; off > 0; off >>= 1) {
        s  += __shfl_xor(s, off);
        sq += __shfl_xor(sq, off);
    }
    __shared__ float ss[4], ssq[4];
    int wave = t >> 6;
    if ((t & 63) == 0) { ss[wave] = s; ssq[wave] = sq; }
    __syncthreads();
    s  = ss[0] + ss[1] + ss[2] + ss[3];
    sq = ssq[0] + ssq[1] + ssq[2] + ssq[3];
    float mu  = s * (1.0f / D_MODEL);
    float var = sq * (1.0f / D_MODEL) - mu * mu;
    float inv = rsqrtf(var + eps);
    float4 wv = ((const float4*)w)[t];
    float4 bv = ((const float4*)b)[t];
    s16x4 o;
    o.x = f2bf((v.x - mu) * inv * wv.x + bv.x);
    o.y = f2bf((v.y - mu) * inv * wv.y + bv.y);
    o.z = f2bf((v.z - mu) * inv * wv.z + bv.z);
    o.w = f2bf((v.w - mu) * inv * wv.w + bv.w);
    *(s16x4*)(out + (size_t)row * D_MODEL + 4 * t) = o;
}

// ---------------------------------------------------------------------------
// Merged transpose+cast: all 8 weight jobs in ONE launch.
// dst[n][k] (bf16, [NPAD][KPAD]) = src[k][coloff+n] (fp32), zero-padded.
// grid (44,44,8); 64x64 tile per block; idle tiles exit.
// ---------------------------------------------------------------------------
struct TJob {
    const float* src;
    short* dst;
    int ldsrc, coloff, nvalid, kvalid, KPAD, NPAD;
};
struct TJobs { TJob j[8]; };

__global__ __launch_bounds__(256) void transpose_all(TJobs jobs)
{
    TJob jb = jobs.j[blockIdx.z];
    int k0 = blockIdx.x * 64, n0 = blockIdx.y * 64;
    if (k0 >= jb.KPAD || n0 >= jb.NPAD) return;
    __shared__ float tile[64][65];
    int t = threadIdx.x;
    // load: thread t -> src row k0+(t>>2), 16 cols at n0+(t&3)*16
    {
        int kk = t >> 2, np = (t & 3) << 4;
        int k = k0 + kk;
        bool kok = k < jb.kvalid;
        const float* srow = jb.src + (size_t)k * jb.ldsrc + jb.coloff + n0 + np;
#pragma unroll
        for (int i = 0; i < 16; ++i) {
            int n = n0 + np + i;
            tile[kk][np + i] = (kok && n < jb.nvalid) ? srow[i] : 0.0f;
        }
    }
    __syncthreads();
    // write: thread t -> dst row n0+(t>>2), 16 k at k0+(t&3)*16
    {
        int nn = t >> 2, kp = (t & 3) << 4;
        short* drow = jb.dst + (size_t)(n0 + nn) * jb.KPAD + k0 + kp;
#pragma unroll
        for (int v4 = 0; v4 < 4; ++v4) {
            s16x4 o;
            o.x = f2bf(tile[kp + v4 * 4 + 0][nn]);
            o.y = f2bf(tile[kp + v4 * 4 + 1][nn]);
            o.z = f2bf(tile[kp + v4 * 4 + 2][nn]);
            o.w = f2bf(tile[kp + v4 * 4 + 3][nn]);
            *(s16x4*)(drow + v4 * 4) = o;
        }
    }
}

// ---------------------------------------------------------------------------
// bf16 MFMA GEMM core (m97 structure + dbuf prefetch), 128x128, BK=32.
// EPI: 0 = bf16 store; 1 = fp32 + R; 2 = fp32 + bias + R
// ---------------------------------------------------------------------------
template<int EPI>
static __device__ __forceinline__ void gemm_core(
        const short* __restrict__ A, int lda,
        const short* __restrict__ Bt,
        const float* __restrict__ bias,
        const float* __restrict__ R, int ldr,
        void* __restrict__ C, int ldc, int K, int bm, int bn,
        short (*As)[4096], short (*Bs)[4096])
{
    int t = threadIdx.x;
    int w = t >> 6;
    int lane = t & 63;
    int quad = lane >> 4;
    int l15  = lane & 15;

    const short* gA0 = A  + (size_t)(bm + (t >> 2)) * lda + ((t & 3) << 3);
    const short* gA1 = gA0 + (size_t)64 * lda;
    const short* gB0 = Bt + (size_t)(bn + (t >> 2)) * K + ((t & 3) << 3);
    const short* gB1 = gB0 + (size_t)64 * K;
    int wb = w << 9;   // wave staging base (shorts)

    int wr = (w >> 1) * 64;
    int wc = (w & 1) * 64;

    f32x4 acc[4][4];
#pragma unroll
    for (int i = 0; i < 4; ++i)
#pragma unroll
        for (int j = 0; j < 4; ++j) acc[i][j] = (f32x4){0.f, 0.f, 0.f, 0.f};

    GLD16(gA0, &As[0][wb]);
    GLD16(gA1, &As[0][2048 + wb]);
    GLD16(gB0, &Bs[0][wb]);
    GLD16(gB1, &Bs[0][2048 + wb]);

    for (int k0 = 0; k0 < K; k0 += 32) {
        int cur = (k0 >> 5) & 1;
        __syncthreads();
        int k1 = k0 + 32;
        if (k1 < K) {
            GLD16(gA0 + k1, &As[cur ^ 1][wb]);
            GLD16(gA1 + k1, &As[cur ^ 1][2048 + wb]);
            GLD16(gB0 + k1, &Bs[cur ^ 1][wb]);
            GLD16(gB1 + k1, &Bs[cur ^ 1][2048 + wb]);
        }
        bf16x8 af[4], bfr[4];
#pragma unroll
        for (int i = 0; i < 4; ++i)
            af[i] = *(const bf16x8*)(&As[cur][(wr + i * 16 + l15) * 32 + quad * 8]);
#pragma unroll
        for (int j = 0; j < 4; ++j)
            bfr[j] = *(const bf16x8*)(&Bs[cur][(wc + j * 16 + l15) * 32 + quad * 8]);
#pragma unroll
        for (int i = 0; i < 4; ++i)
#pragma unroll
            for (int j = 0; j < 4; ++j)
                acc[i][j] = __builtin_amdgcn_mfma_f32_16x16x32_bf16(af[i], bfr[j], acc[i][j], 0, 0, 0);
    }

#pragma unroll
    for (int i = 0; i < 4; ++i) {
        int gr = bm + wr + i * 16 + quad * 4;
#pragma unroll
        for (int j = 0; j < 4; ++j) {
            int gc = bn + wc + j * 16 + l15;
#pragma unroll
            for (int r = 0; r < 4; ++r) {
                float val = acc[i][j][r];
                size_t idx = (size_t)(gr + r) * ldc + gc;
                if (EPI == 0) {
                    ((short*)C)[idx] = f2bf(val);
                } else if (EPI == 1) {
                    ((float*)C)[idx] = val + R[(size_t)(gr + r) * ldr + gc];
                } else {
                    ((float*)C)[idx] = val + bias[gc] + R[(size_t)(gr + r) * ldr + gc];
                }
            }
        }
    }
}

// swizzled-grid GEMM: x = row-tile (fastest) so consecutive blocks share Bt strip
template<int EPI>
__global__ __launch_bounds__(256) void gemm_swz(
        const short* __restrict__ A, int lda,
        const short* __restrict__ Bt,
        const float* __restrict__ bias,
        const float* __restrict__ R, int ldr,
        void* __restrict__ C, int ldc, int K)
{
    __shared__ short As[2][4096];
    __shared__ short Bs[2][4096];
    gemm_core<EPI>(A, lda, Bt, bias, R, ldr, C, ldc, K,
                   blockIdx.x * 128, blockIdx.y * 128, As, Bs);
}

// merged q|k|g + v^T projection: 1024 blocks in one launch
__global__ __launch_bounds__(256) void proj_kernel(
        const short* __restrict__ xn,
        const short* __restrict__ qkgT,
        short* __restrict__ qkg,
        const short* __restrict__ wvT,
        short* __restrict__ vT)
{
    __shared__ short As[2][4096];
    __shared__ short Bs[2][4096];
    int id = blockIdx.x;
    if (id < 768) {
        // qkg: M=4096, N=3072; consecutive ids share bn (weight strip)
        int bm = (id & 31) * 128, bn = (id >> 5) * 128;
        gemm_core<0>(xn, D_MODEL, qkgT, nullptr, nullptr, 0, qkg, QKG, D_MODEL, bm, bn, As, Bs);
    } else {
        // vT: M=1024 (wvT rows), N=4096 (tokens); consecutive share bm (wvT strip)
        int i2 = id - 768;
        int bn = (i2 & 31) * 128, bm = (i2 >> 5) * 128;
        gemm_core<0>(wvT, D_MODEL, xn, nullptr, nullptr, 0, vT, NTOK, D_MODEL, bm, bn, As, Bs);
    }
}

// ---------------------------------------------------------------------------
// Fused SwiGLU-in GEMM (MFMA), 128x64 tile, dbuf prefetch, swizzled grid
// (x = row-tile fastest -> consecutive blocks share the w_inT strip).
// ---------------------------------------------------------------------------
__global__ __launch_bounds__(256) void mlp_fused(
        const short* __restrict__ A,       // [NTOK][1024] bf16
        const short* __restrict__ w_inT,   // [2*HID_PAD][1024] bf16
        const float* __restrict__ b_in,    // [2*HID]
        short* __restrict__ hm)            // [NTOK][HID_PAD] bf16
{
    __shared__ short As[2][4096];
    __shared__ short Ba[2][2048];
    __shared__ short Bb[2][2048];
    const int K = D_MODEL;
    int bm = blockIdx.x * 128;            // row tile fastest
    int bn = blockIdx.y * 64;
    int t = threadIdx.x;
    int w = t >> 6;
    int lane = t & 63;
    int quad = lane >> 4;
    int l15  = lane & 15;

    const short* gA0 = A + (size_t)(bm + (t >> 2)) * K + ((t & 3) << 3);
    const short* gA1 = gA0 + (size_t)64 * K;
    const short* gBa = w_inT + (size_t)(bn + (t >> 2)) * K + ((t & 3) << 3);
    const short* gBb = gBa + (size_t)HID_PAD * K;
    int wb = w << 9;

    int wr = (w >> 1) * 64;
    int wc = (w & 1) * 32;

    f32x4 acca[4][2], accb[4][2];
#pragma unroll
    for (int i = 0; i < 4; ++i)
#pragma unroll
        for (int j = 0; j < 2; ++j) {
            acca[i][j] = (f32x4){0.f, 0.f, 0.f, 0.f};
            accb[i][j] = (f32x4){0.f, 0.f, 0.f, 0.f};
        }

    GLD16(gA0, &As[0][wb]);
    GLD16(gA1, &As[0][2048 + wb]);
    GLD16(gBa, &Ba[0][wb]);
    GLD16(gBb, &Bb[0][wb]);

    for (int k0 = 0; k0 < K; k0 += 32) {
        int cur = (k0 >> 5) & 1;
        __syncthreads();
        int k1 = k0 + 32;
        if (k1 < K) {
            GLD16(gA0 + k1, &As[cur ^ 1][wb]);
            GLD16(gA1 + k1, &As[cur ^ 1][2048 + wb]);
            GLD16(gBa + k1, &Ba[cur ^ 1][wb]);
            GLD16(gBb + k1, &Bb[cur ^ 1][wb]);
        }
        bf16x8 af[4], baf[2], bbf[2];
#pragma unroll
        for (int i = 0; i < 4; ++i)
            af[i] = *(const bf16x8*)(&As[cur][(wr + i * 16 + l15) * 32 + quad * 8]);
#pragma unroll
        for (int j = 0; j < 2; ++j) {
            baf[j] = *(const bf16x8*)(&Ba[cur][(wc + j * 16 + l15) * 32 + quad * 8]);
            bbf[j] = *(const bf16x8*)(&Bb[cur][(wc + j * 16 + l15) * 32 + quad * 8]);
        }
#pragma unroll
        for (int i = 0; i < 4; ++i)
#pragma unroll
            for (int j = 0; j < 2; ++j) {
                acca[i][j] = __builtin_amdgcn_mfma_f32_16x16x32_bf16(af[i], baf[j], acca[i][j], 0, 0, 0);
                accb[i][j] = __builtin_amdgcn_mfma_f32_16x16x32_bf16(af[i], bbf[j], accb[i][j], 0, 0, 0);
            }
    }

#pragma unroll
    for (int i = 0; i < 4; ++i) {
        int gr = bm + wr + i * 16 + quad * 4;
#pragma unroll
        for (int j = 0; j < 2; ++j) {
            int gc = bn + wc + j * 16 + l15;
            bool ok = gc < HID;
            float ba = ok ? b_in[gc] : 0.0f;
            float bb = ok ? b_in[HID + gc] : 0.0f;
#pragma unroll
            for (int r = 0; r < 4; ++r) {
                float a  = acca[i][j][r] + ba;
                float bv = accb[i][j][r] + bb;
                float val = ok ? a * (bv / (1.0f + expf(-bv))) : 0.0f;
                hm[(size_t)(gr + r) * HID_PAD + gc] = f2bf(val);
            }
        }
    }
}

// ---------------------------------------------------------------------------
// MFMA retention + groupnorm + silu gate. 512 threads (8 waves), 128 q-rows.
// qkg: [NTOK][3072] bf16: cols [0,1024)=q, [1024,2048)=k, [2048,3072)=g.
// vT:  [1024][NTOK]  bf16: row d = h*64+dd, col = token (V transposed).
// ---------------------------------------------------------------------------
#define PSTR 72   // ps row stride in shorts

__global__ __launch_bounds__(512) void retention_mfma(
        const short* __restrict__ qkg,
        const short* __restrict__ vT,
        short* __restrict__ rg)
{
    int qb = (int)gridDim.x - 1 - (int)blockIdx.x;   // heavy blocks first
    int h  = blockIdx.y;
    int b  = blockIdx.z;

    __shared__ short ks[2][4096];         // [buf][d-chunk(2)][64 t][32 d]
    __shared__ short vt[2][4096];         // [buf][t-chunk(2)][64 d][32 t]
    __shared__ short ps[8][16 * PSTR];    // per-wave P tile

    int tid  = threadIdx.x;
    int w    = tid >> 6;
    int lane = tid & 63;
    int quad = lane >> 4;
    int l15  = lane & 15;

    float log2g = log1pf(-exp2f(-5.0f - (float)h)) * 1.4426950408889634f;
    int hcol = h * HDIM;
    int s0 = qb * 128;
    size_t tok0 = (size_t)b * SEQ;

    int sch  = tid >> 8;
    int srow = (tid >> 2) & 63;
    int sp8  = (tid & 3) << 3;
    const short* kbase  = qkg + (tok0 + srow) * QKG + 1024 + hcol + sch * 32 + sp8;
    const short* vtbase = vT + (size_t)(hcol + srow) * NTOK + tok0 + sch * 32 + sp8;
    int lb = tid << 3;

    const short* qrow = qkg + (tok0 + s0 + w * 16 + l15) * QKG + hcol;
    bf16x8 qa0 = *(const bf16x8*)(qrow + quad * 8);
    bf16x8 qa1 = *(const bf16x8*)(qrow + 32 + quad * 8);

    float colfac[4];
#pragma unroll
    for (int tile = 0; tile < 4; ++tile)
        colfac[tile] = exp2f(-(float)(tile * 16 + l15) * log2g) * 0.125f;

    f32x4 oacc[4];
#pragma unroll
    for (int i = 0; i < 4; ++i) oacc[i] = (f32x4){0.f, 0.f, 0.f, 0.f};

    int sbase = s0 + w * 16 + quad * 4;
    int tmax = 2 * qb + 1;

    GLD16(kbase, &ks[0][lb]);
    GLD16(vtbase, &vt[0][lb]);

    for (int tb = 0; tb <= tmax; ++tb) {
        int cur = tb & 1;
        __syncthreads();
        if (tb < tmax) {
            GLD16(kbase + (size_t)(tb + 1) * 64 * QKG, &ks[cur ^ 1][lb]);
            GLD16(vtbase + (tb + 1) * 64, &vt[cur ^ 1][lb]);
        }

        f32x4 sacc[4];
#pragma unroll
        for (int i = 0; i < 4; ++i) sacc[i] = (f32x4){0.f, 0.f, 0.f, 0.f};
#pragma unroll
        for (int tile = 0; tile < 4; ++tile) {
            bf16x8 kb0 = *(const bf16x8*)(&ks[cur][(tile * 16 + l15) * 32 + quad * 8]);
            bf16x8 kb1 = *(const bf16x8*)(&ks[cur][2048 + (tile * 16 + l15) * 32 + quad * 8]);
            sacc[tile] = __builtin_amdgcn_mfma_f32_16x16x32_bf16(qa0, kb0, sacc[tile], 0, 0, 0);
            sacc[tile] = __builtin_amdgcn_mfma_f32_16x16x32_bf16(qa1, kb1, sacc[tile], 0, 0, 0);
        }

        int fbi = sbase - tb * 64;
        float rf[4];
#pragma unroll
        for (int reg = 0; reg < 4; ++reg)
            rf[reg] = exp2f((float)(fbi + reg) * log2g);

        if (tb * 64 + 63 > s0 + w * 16) {
#pragma unroll
            for (int tile = 0; tile < 4; ++tile) {
                int tt = tile * 16 + l15;
#pragma unroll
                for (int reg = 0; reg < 4; ++reg) {
                    float p = (fbi + reg >= tt) ? sacc[tile][reg] * rf[reg] * colfac[tile] : 0.0f;
                    ps[w][(quad * 4 + reg) * PSTR + tile * 16 + l15] = f2bf(p);
                }
            }
        } else {
#pragma unroll
            for (int tile = 0; tile < 4; ++tile)
#pragma unroll
                for (int reg = 0; reg < 4; ++reg)
                    ps[w][(quad * 4 + reg) * PSTR + tile * 16 + l15] =
                        f2bf(sacc[tile][reg] * (rf[reg] * colfac[tile]));
        }

#pragma unroll
        for (int ksi = 0; ksi < 2; ++ksi) {
            bf16x8 pa = *(const bf16x8*)(&ps[w][l15 * PSTR + ksi * 32 + quad * 8]);
#pragma unroll
            for (int dt = 0; dt < 4; ++dt) {
                bf16x8 vb = *(const bf16x8*)(&vt[cur][ksi * 2048 + (dt * 16 + l15) * 32 + quad * 8]);
                oacc[dt] = __builtin_amdgcn_mfma_f32_16x16x32_bf16(pa, vb, oacc[dt], 0, 0, 0);
            }
        }
    }

    float s1[4], s2[4];
#pragma unroll
    for (int reg = 0; reg < 4; ++reg) {
        s1[reg] = oacc[0][reg] + oacc[1][reg] + oacc[2][reg] + oacc[3][reg];
        s2[reg] = oacc[0][reg] * oacc[0][reg] + oacc[1][reg] * oacc[1][reg]
                + oacc[2][reg] * oacc[2][reg] + oacc[3][reg] * oacc[3][reg];
    }
#pragma unroll
    for (int off = 1; off < 16; off <<= 1) {
#pragma unroll
        for (int reg = 0; reg < 4; ++reg) {
            s1[reg] += __shfl_xor(s1[reg], off);
            s2[reg] += __shfl_xor(s2[reg], off);
        }
    }
    size_t rowtok = tok0 + s0 + w * 16 + quad * 4;
    short* obase = rg + rowtok * D_MODEL + hcol;
    const short* gbase = qkg + rowtok * QKG + 2048 + hcol;
#pragma unroll
    for (int reg = 0; reg < 4; ++reg) {
        float mu  = s1[reg] * (1.0f / 64.0f);
        float var = s2[reg] * (1.0f / 64.0f) - mu * mu;
        float inv = rsqrtf(var + 1e-6f);
#pragma unroll
        for (int dt = 0; dt < 4; ++dt) {
            float gv = bf2f(gbase[(size_t)reg * QKG + dt * 16 + l15]);
            float val = (oacc[dt][reg] - mu) * inv * (gv / (1.0f + expf(-gv)));
            obase[(size_t)reg * D_MODEL + dt * 16 + l15] = f2bf(val);
        }
    }
}

// ---------------------------------------------------------------------------
extern "C" void kernel_launch(void* const* d_in, const int* in_sizes, int n_in,
                              void* d_out, int out_size, void* d_ws, size_t ws_size,
                              hipStream_t stream)
{
    const float* x     = (const float*)d_in[0];
    const float* ln1w  = (const float*)d_in[1];
    const float* ln1b  = (const float*)d_in[2];
    const float* wq    = (const float*)d_in[3];
    const float* wk    = (const float*)d_in[4];
    const float* wv    = (const float*)d_in[5];
    const float* wg    = (const float*)d_in[6];
    const float* wo    = (const float*)d_in[7];
    const float* ln2w  = (const float*)d_in[8];
    const float* ln2b  = (const float*)d_in[9];
    const float* w_in  = (const float*)d_in[10];
    const float* b_in  = (const float*)d_in[11];
    const float* w_out = (const float*)d_in[12];
    const float* b_out = (const float*)d_in[13];
    float* out = (float*)d_out;
    char* base = (char*)d_ws;

    const size_t MB = 1u << 20;
    short* xn     = (short*)(base);            // [0,8)   [4096][1024] bf16 LN out
    short* qkgT   = (short*)(base +  8 * MB);  // [8,14)  wq|wk|wg transposed [3072][1024]
    short* wvT    = (short*)(base + 14 * MB);  // [14,16) [1024][1024]
    short* woT    = (short*)(base + 16 * MB);  // [16,18) [1024][1024]
    short* w_inT  = (short*)(base + 18 * MB);  // [18,29) [5632][1024]
    short* w_outT = (short*)(base + 29 * MB);  // [29,34.5) [1024][2816]
    short* qkg    = (short*)(base + 35 * MB);  // [35,59) [4096][3072] packed q|k|g
    short* hm     = (short*)(base + 35 * MB);  // [35,57) [4096][2816] reuses dead qkg
    short* vT     = (short*)(base + 59 * MB);  // [59,67) [1024][4096] V transposed
    short* rg     = (short*)(base + 67 * MB);  // [67,75) [4096][1024] gated retention out

    // all 8 weight transposes in one launch
    TJobs jobs;
    jobs.j[0] = { wq,    qkgT,                          1024,    0, 1024, 1024, 1024, 1024 };
    jobs.j[1] = { wk,    qkgT + 1024 * 1024,            1024,    0, 1024, 1024, 1024, 1024 };
    jobs.j[2] = { wg,    qkgT + 2 * 1024 * 1024,        1024,    0, 1024, 1024, 1024, 1024 };
    jobs.j[3] = { wv,    wvT,                           1024,    0, 1024, 1024, 1024, 1024 };
    jobs.j[4] = { wo,    woT,                           1024,    0, 1024, 1024, 1024, 1024 };
    jobs.j[5] = { w_in,  w_inT,                         2 * HID, 0,   HID, 1024, 1024, HID_PAD };
    jobs.j[6] = { w_in,  w_inT + (size_t)HID_PAD * 1024, 2 * HID, HID, HID, 1024, 1024, HID_PAD };
    jobs.j[7] = { w_out, w_outT,                        1024,    0, 1024, HID, HID_PAD, 1024 };
    transpose_all<<<dim3(44, 44, 8), 256, 0, stream>>>(jobs);

    // LN1 -> bf16
    ln_kernel<<<NTOK, 256, 0, stream>>>(x, ln1w, ln1b, xn, 1e-5f);
    // merged q|k|g + v^T projections (1024 blocks, one launch)
    proj_kernel<<<1024, 256, 0, stream>>>(xn, qkgT, qkg, wvT, vT);
    // retention + groupnorm + silu gate
    retention_mfma<<<dim3(SEQ / 128, NHEAD, BATCH), 512, 0, stream>>>(qkg, vT, rg);
    // wo projection + residual x -> out (fp32); x = row tile (share woT strip)
    gemm_swz<1><<<dim3(32, 8), 256, 0, stream>>>(rg, D_MODEL, woT, nullptr, x, D_MODEL, out, D_MODEL, D_MODEL);
    // LN2 -> bf16
    ln_kernel<<<NTOK, 256, 0, stream>>>(out, ln2w, ln2b, xn, 1e-5f);
    // fused SwiGLU-in GEMM (x = row tile fastest -> share w_inT strip)
    mlp_fused<<<dim3(NTOK / 128, HID_PAD / 64), 256, 0, stream>>>(xn, w_inT, b_in, hm);
    // w_out GEMM + bias + residual
    gemm_swz<2><<<dim3(32, 8), 256, 0, stream>>>(hm, HID_PAD, w_outT, b_out, out, D_MODEL, out, D_MODEL, HID_PAD);
}

// Round 9
// 413.356 us; speedup vs baseline: 15.6859x; 1.0487x over previous
//
#include <hip/hip_runtime.h>
#include <math.h>

#define D_MODEL 1024
#define NHEAD   16
#define HDIM    64
#define HID     2730
#define HID_PAD 2816          // 22 * 128
#define SEQ     2048
#define BATCH   2
#define NTOK    (BATCH * SEQ)   // 4096
#define QKG     3072            // packed q|k|g row stride (elements)

typedef __attribute__((ext_vector_type(8))) short bf16x8;
typedef __attribute__((ext_vector_type(4))) float f32x4;
typedef __attribute__((ext_vector_type(4))) short s16x4;

// fp32 -> bf16 round-to-nearest-even
static __device__ inline short f2bf(float f)
{
    union { float f; unsigned int u; } c; c.f = f;
    unsigned int r = c.u + 0x7FFFu + ((c.u >> 16) & 1u);
    return (short)(r >> 16);
}
static __device__ inline float bf2f(short s)
{
    union { unsigned int u; float f; } c;
    c.u = ((unsigned int)(unsigned short)s) << 16;
    return c.f;
}

// async global->LDS, 16B per lane; lds dest = wave-uniform base + lane*16
#define GLD16(gsrc, ldst) \
    __builtin_amdgcn_global_load_lds((const __attribute__((address_space(1))) void*)(gsrc), \
                                     (__attribute__((address_space(3))) void*)(ldst), 16, 0, 0)

// ---------------------------------------------------------------------------
// LayerNorm: one block (256 threads) per row of 1024, fp32 in -> bf16 out
// ---------------------------------------------------------------------------
__global__ void ln_kernel(const float* __restrict__ x,
                          const float* __restrict__ w,
                          const float* __restrict__ b,
                          short* __restrict__ out,
                          float eps)
{
    int row = blockIdx.x;
    int t = threadIdx.x;               // 0..255
    const float4* xr = (const float4*)(x + (size_t)row * D_MODEL);
    float4 v = xr[t];
    float s  = v.x + v.y + v.z + v.w;
    float sq = v.x * v.x + v.y * v.y + v.z * v.z + v.w * v.w;
#pragma unroll
    for (int off = 32; off > 0; off >>= 1) {
        s  += __shfl_xor(s, off);
        sq += __shfl_xor(sq, off);
    }
    __shared__ float ss[4], ssq[4];
    int wave = t >> 6;
    if ((t & 63) == 0) { ss[wave] = s; ssq[wave] = sq; }
    __syncthreads();
    s  = ss[0] + ss[1] + ss[2] + ss[3];
    sq = ssq[0] + ssq[1] + ssq[2] + ssq[3];
    float mu  = s * (1.0f / D_MODEL);
    float var = sq * (1.0f / D_MODEL) - mu * mu;
    float inv = rsqrtf(var + eps);
    float4 wv = ((const float4*)w)[t];
    float4 bv = ((const float4*)b)[t];
    s16x4 o;
    o.x = f2bf((v.x - mu) * inv * wv.x + bv.x);
    o.y = f2bf((v.y - mu) * inv * wv.y + bv.y);
    o.z = f2bf((v.z - mu) * inv * wv.z + bv.z);
    o.w = f2bf((v.w - mu) * inv * wv.w + bv.w);
    *(s16x4*)(out + (size_t)row * D_MODEL + 4 * t) = o;
}

// ---------------------------------------------------------------------------
// Merged transpose+cast: all 8 weight jobs in ONE launch.
// ---------------------------------------------------------------------------
struct TJob {
    const float* src;
    short* dst;
    int ldsrc, coloff, nvalid, kvalid, KPAD, NPAD;
};
struct TJobs { TJob j[8]; };

__global__ __launch_bounds__(256) void transpose_all(TJobs jobs)
{
    TJob jb = jobs.j[blockIdx.z];
    int k0 = blockIdx.x * 64, n0 = blockIdx.y * 64;
    if (k0 >= jb.KPAD || n0 >= jb.NPAD) return;
    __shared__ float tile[64][65];
    int t = threadIdx.x;
    {
        int kk = t >> 2, np = (t & 3) << 4;
        int k = k0 + kk;
        bool kok = k < jb.kvalid;
        const float* srow = jb.src + (size_t)k * jb.ldsrc + jb.coloff + n0 + np;
#pragma unroll
        for (int i = 0; i < 16; ++i) {
            int n = n0 + np + i;
            tile[kk][np + i] = (kok && n < jb.nvalid) ? srow[i] : 0.0f;
        }
    }
    __syncthreads();
    {
        int nn = t >> 2, kp = (t & 3) << 4;
        short* drow = jb.dst + (size_t)(n0 + nn) * jb.KPAD + k0 + kp;
#pragma unroll
        for (int v4 = 0; v4 < 4; ++v4) {
            s16x4 o;
            o.x = f2bf(tile[kp + v4 * 4 + 0][nn]);
            o.y = f2bf(tile[kp + v4 * 4 + 1][nn]);
            o.z = f2bf(tile[kp + v4 * 4 + 2][nn]);
            o.w = f2bf(tile[kp + v4 * 4 + 3][nn]);
            *(s16x4*)(drow + v4 * 4) = o;
        }
    }
}

// ---------------------------------------------------------------------------
// bf16 MFMA GEMM core (m97 structure + dbuf prefetch), 128x128, BK=32.
// EPI: 0 = bf16 store; 1 = fp32 + R; 2 = fp32 + bias + R
// ---------------------------------------------------------------------------
template<int EPI>
static __device__ __forceinline__ void gemm_core(
        const short* __restrict__ A, int lda,
        const short* __restrict__ Bt,
        const float* __restrict__ bias,
        const float* __restrict__ R, int ldr,
        void* __restrict__ C, int ldc, int K, int bm, int bn,
        short (*As)[4096], short (*Bs)[4096])
{
    int t = threadIdx.x;
    int w = t >> 6;
    int lane = t & 63;
    int quad = lane >> 4;
    int l15  = lane & 15;

    const short* gA0 = A  + (size_t)(bm + (t >> 2)) * lda + ((t & 3) << 3);
    const short* gA1 = gA0 + (size_t)64 * lda;
    const short* gB0 = Bt + (size_t)(bn + (t >> 2)) * K + ((t & 3) << 3);
    const short* gB1 = gB0 + (size_t)64 * K;
    int wb = w << 9;   // wave staging base (shorts)

    int wr = (w >> 1) * 64;
    int wc = (w & 1) * 64;

    f32x4 acc[4][4];
#pragma unroll
    for (int i = 0; i < 4; ++i)
#pragma unroll
        for (int j = 0; j < 4; ++j) acc[i][j] = (f32x4){0.f, 0.f, 0.f, 0.f};

    GLD16(gA0, &As[0][wb]);
    GLD16(gA1, &As[0][2048 + wb]);
    GLD16(gB0, &Bs[0][wb]);
    GLD16(gB1, &Bs[0][2048 + wb]);

    for (int k0 = 0; k0 < K; k0 += 32) {
        int cur = (k0 >> 5) & 1;
        __syncthreads();
        int k1 = k0 + 32;
        if (k1 < K) {
            GLD16(gA0 + k1, &As[cur ^ 1][wb]);
            GLD16(gA1 + k1, &As[cur ^ 1][2048 + wb]);
            GLD16(gB0 + k1, &Bs[cur ^ 1][wb]);
            GLD16(gB1 + k1, &Bs[cur ^ 1][2048 + wb]);
        }
        bf16x8 af[4], bfr[4];
#pragma unroll
        for (int i = 0; i < 4; ++i)
            af[i] = *(const bf16x8*)(&As[cur][(wr + i * 16 + l15) * 32 + quad * 8]);
#pragma unroll
        for (int j = 0; j < 4; ++j)
            bfr[j] = *(const bf16x8*)(&Bs[cur][(wc + j * 16 + l15) * 32 + quad * 8]);
#pragma unroll
        for (int i = 0; i < 4; ++i)
#pragma unroll
            for (int j = 0; j < 4; ++j)
                acc[i][j] = __builtin_amdgcn_mfma_f32_16x16x32_bf16(af[i], bfr[j], acc[i][j], 0, 0, 0);
    }

#pragma unroll
    for (int i = 0; i < 4; ++i) {
        int gr = bm + wr + i * 16 + quad * 4;
#pragma unroll
        for (int j = 0; j < 4; ++j) {
            int gc = bn + wc + j * 16 + l15;
#pragma unroll
            for (int r = 0; r < 4; ++r) {
                float val = acc[i][j][r];
                size_t idx = (size_t)(gr + r) * ldc + gc;
                if (EPI == 0) {
                    ((short*)C)[idx] = f2bf(val);
                } else if (EPI == 1) {
                    ((float*)C)[idx] = val + R[(size_t)(gr + r) * ldr + gc];
                } else {
                    ((float*)C)[idx] = val + bias[gc] + R[(size_t)(gr + r) * ldr + gc];
                }
            }
        }
    }
}

// merged q|k|g + v^T projection: 1024 blocks in one launch
__global__ __launch_bounds__(256, 4) void proj_kernel(
        const short* __restrict__ xn,
        const short* __restrict__ qkgT,
        short* __restrict__ qkg,
        const short* __restrict__ wvT,
        short* __restrict__ vT)
{
    __shared__ short As[2][4096];
    __shared__ short Bs[2][4096];
    int id = blockIdx.x;
    if (id < 768) {
        int bm = (id & 31) * 128, bn = (id >> 5) * 128;
        gemm_core<0>(xn, D_MODEL, qkgT, nullptr, nullptr, 0, qkg, QKG, D_MODEL, bm, bn, As, Bs);
    } else {
        int i2 = id - 768;
        int bn = (i2 & 31) * 128, bm = (i2 >> 5) * 128;
        gemm_core<0>(wvT, D_MODEL, xn, nullptr, nullptr, 0, vT, NTOK, D_MODEL, bm, bn, As, Bs);
    }
}

// ---------------------------------------------------------------------------
// 128x64-tile GEMM for the N=1024 projections (wo, w_out): 512 blocks so the
// whole grid is co-resident (2+ blocks/CU); acc = 32 AGPR.
// x = row tile fastest -> consecutive blocks share the weight strip.
// ---------------------------------------------------------------------------
template<int EPI>
__global__ __launch_bounds__(256, 4) void gemm_n64(
        const short* __restrict__ A, int lda,
        const short* __restrict__ Bt,
        const float* __restrict__ bias,
        const float* __restrict__ R, int ldr,
        void* __restrict__ C, int ldc, int K)
{
    __shared__ short As[2][4096];
    __shared__ short Bs[2][2048];
    int bm = blockIdx.x * 128;          // row tile fastest
    int bn = blockIdx.y * 64;
    int t = threadIdx.x;
    int w = t >> 6;
    int lane = t & 63;
    int quad = lane >> 4;
    int l15  = lane & 15;

    const short* gA0 = A  + (size_t)(bm + (t >> 2)) * lda + ((t & 3) << 3);
    const short* gA1 = gA0 + (size_t)64 * lda;
    const short* gB0 = Bt + (size_t)(bn + (t >> 2)) * K + ((t & 3) << 3);
    int wb = w << 9;

    int wr = (w >> 1) * 64;
    int wc = (w & 1) * 32;

    f32x4 acc[4][2];
#pragma unroll
    for (int i = 0; i < 4; ++i)
#pragma unroll
        for (int j = 0; j < 2; ++j) acc[i][j] = (f32x4){0.f, 0.f, 0.f, 0.f};

    GLD16(gA0, &As[0][wb]);
    GLD16(gA1, &As[0][2048 + wb]);
    GLD16(gB0, &Bs[0][wb]);

    for (int k0 = 0; k0 < K; k0 += 32) {
        int cur = (k0 >> 5) & 1;
        __syncthreads();
        int k1 = k0 + 32;
        if (k1 < K) {
            GLD16(gA0 + k1, &As[cur ^ 1][wb]);
            GLD16(gA1 + k1, &As[cur ^ 1][2048 + wb]);
            GLD16(gB0 + k1, &Bs[cur ^ 1][wb]);
        }
        bf16x8 af[4], bfr[2];
#pragma unroll
        for (int i = 0; i < 4; ++i)
            af[i] = *(const bf16x8*)(&As[cur][(wr + i * 16 + l15) * 32 + quad * 8]);
#pragma unroll
        for (int j = 0; j < 2; ++j)
            bfr[j] = *(const bf16x8*)(&Bs[cur][(wc + j * 16 + l15) * 32 + quad * 8]);
#pragma unroll
        for (int i = 0; i < 4; ++i)
#pragma unroll
            for (int j = 0; j < 2; ++j)
                acc[i][j] = __builtin_amdgcn_mfma_f32_16x16x32_bf16(af[i], bfr[j], acc[i][j], 0, 0, 0);
    }

#pragma unroll
    for (int i = 0; i < 4; ++i) {
        int gr = bm + wr + i * 16 + quad * 4;
#pragma unroll
        for (int j = 0; j < 2; ++j) {
            int gc = bn + wc + j * 16 + l15;
#pragma unroll
            for (int r = 0; r < 4; ++r) {
                float val = acc[i][j][r];
                size_t idx = (size_t)(gr + r) * ldc + gc;
                if (EPI == 0) {
                    ((short*)C)[idx] = f2bf(val);
                } else if (EPI == 1) {
                    ((float*)C)[idx] = val + R[(size_t)(gr + r) * ldr + gc];
                } else {
                    ((float*)C)[idx] = val + bias[gc] + R[(size_t)(gr + r) * ldr + gc];
                }
            }
        }
    }
}

// ---------------------------------------------------------------------------
// Fused SwiGLU-in GEMM (MFMA), 128x64 tile, dbuf prefetch, row-tile-fastest.
// ---------------------------------------------------------------------------
__global__ __launch_bounds__(256, 4) void mlp_fused(
        const short* __restrict__ A,       // [NTOK][1024] bf16
        const short* __restrict__ w_inT,   // [2*HID_PAD][1024] bf16
        const float* __restrict__ b_in,    // [2*HID]
        short* __restrict__ hm)            // [NTOK][HID_PAD] bf16
{
    __shared__ short As[2][4096];
    __shared__ short Ba[2][2048];
    __shared__ short Bb[2][2048];
    const int K = D_MODEL;
    int bm = blockIdx.x * 128;            // row tile fastest
    int bn = blockIdx.y * 64;
    int t = threadIdx.x;
    int w = t >> 6;
    int lane = t & 63;
    int quad = lane >> 4;
    int l15  = lane & 15;

    const short* gA0 = A + (size_t)(bm + (t >> 2)) * K + ((t & 3) << 3);
    const short* gA1 = gA0 + (size_t)64 * K;
    const short* gBa = w_inT + (size_t)(bn + (t >> 2)) * K + ((t & 3) << 3);
    const short* gBb = gBa + (size_t)HID_PAD * K;
    int wb = w << 9;

    int wr = (w >> 1) * 64;
    int wc = (w & 1) * 32;

    f32x4 acca[4][2], accb[4][2];
#pragma unroll
    for (int i = 0; i < 4; ++i)
#pragma unroll
        for (int j = 0; j < 2; ++j) {
            acca[i][j] = (f32x4){0.f, 0.f, 0.f, 0.f};
            accb[i][j] = (f32x4){0.f, 0.f, 0.f, 0.f};
        }

    GLD16(gA0, &As[0][wb]);
    GLD16(gA1, &As[0][2048 + wb]);
    GLD16(gBa, &Ba[0][wb]);
    GLD16(gBb, &Bb[0][wb]);

    for (int k0 = 0; k0 < K; k0 += 32) {
        int cur = (k0 >> 5) & 1;
        __syncthreads();
        int k1 = k0 + 32;
        if (k1 < K) {
            GLD16(gA0 + k1, &As[cur ^ 1][wb]);
            GLD16(gA1 + k1, &As[cur ^ 1][2048 + wb]);
            GLD16(gBa + k1, &Ba[cur ^ 1][wb]);
            GLD16(gBb + k1, &Bb[cur ^ 1][wb]);
        }
        bf16x8 af[4], baf[2], bbf[2];
#pragma unroll
        for (int i = 0; i < 4; ++i)
            af[i] = *(const bf16x8*)(&As[cur][(wr + i * 16 + l15) * 32 + quad * 8]);
#pragma unroll
        for (int j = 0; j < 2; ++j) {
            baf[j] = *(const bf16x8*)(&Ba[cur][(wc + j * 16 + l15) * 32 + quad * 8]);
            bbf[j] = *(const bf16x8*)(&Bb[cur][(wc + j * 16 + l15) * 32 + quad * 8]);
        }
#pragma unroll
        for (int i = 0; i < 4; ++i)
#pragma unroll
            for (int j = 0; j < 2; ++j) {
                acca[i][j] = __builtin_amdgcn_mfma_f32_16x16x32_bf16(af[i], baf[j], acca[i][j], 0, 0, 0);
                accb[i][j] = __builtin_amdgcn_mfma_f32_16x16x32_bf16(af[i], bbf[j], accb[i][j], 0, 0, 0);
            }
    }

#pragma unroll
    for (int i = 0; i < 4; ++i) {
        int gr = bm + wr + i * 16 + quad * 4;
#pragma unroll
        for (int j = 0; j < 2; ++j) {
            int gc = bn + wc + j * 16 + l15;
            bool ok = gc < HID;
            float ba = ok ? b_in[gc] : 0.0f;
            float bb = ok ? b_in[HID + gc] : 0.0f;
#pragma unroll
            for (int r = 0; r < 4; ++r) {
                float a  = acca[i][j][r] + ba;
                float bv = accb[i][j][r] + bb;
                float val = ok ? a * (bv / (1.0f + expf(-bv))) : 0.0f;
                hm[(size_t)(gr + r) * HID_PAD + gc] = f2bf(val);
            }
        }
    }
}

// ---------------------------------------------------------------------------
// MFMA retention + groupnorm + silu gate. 512 threads (8 waves), 128 q-rows.
// ---------------------------------------------------------------------------
#define PSTR 72   // ps row stride in shorts

__global__ __launch_bounds__(512) void retention_mfma(
        const short* __restrict__ qkg,
        const short* __restrict__ vT,
        short* __restrict__ rg)
{
    int qb = (int)gridDim.x - 1 - (int)blockIdx.x;   // heavy blocks first
    int h  = blockIdx.y;
    int b  = blockIdx.z;

    __shared__ short ks[2][4096];         // [buf][d-chunk(2)][64 t][32 d]
    __shared__ short vt[2][4096];         // [buf][t-chunk(2)][64 d][32 t]
    __shared__ short ps[8][16 * PSTR];    // per-wave P tile

    int tid  = threadIdx.x;
    int w    = tid >> 6;
    int lane = tid & 63;
    int quad = lane >> 4;
    int l15  = lane & 15;

    float log2g = log1pf(-exp2f(-5.0f - (float)h)) * 1.4426950408889634f;
    int hcol = h * HDIM;
    int s0 = qb * 128;
    size_t tok0 = (size_t)b * SEQ;

    int sch  = tid >> 8;
    int srow = (tid >> 2) & 63;
    int sp8  = (tid & 3) << 3;
    const short* kbase  = qkg + (tok0 + srow) * QKG + 1024 + hcol + sch * 32 + sp8;
    const short* vtbase = vT + (size_t)(hcol + srow) * NTOK + tok0 + sch * 32 + sp8;
    int lb = tid << 3;

    const short* qrow = qkg + (tok0 + s0 + w * 16 + l15) * QKG + hcol;
    bf16x8 qa0 = *(const bf16x8*)(qrow + quad * 8);
    bf16x8 qa1 = *(const bf16x8*)(qrow + 32 + quad * 8);

    float colfac[4];
#pragma unroll
    for (int tile = 0; tile < 4; ++tile)
        colfac[tile] = exp2f(-(float)(tile * 16 + l15) * log2g) * 0.125f;

    f32x4 oacc[4];
#pragma unroll
    for (int i = 0; i < 4; ++i) oacc[i] = (f32x4){0.f, 0.f, 0.f, 0.f};

    int sbase = s0 + w * 16 + quad * 4;
    int tmax = 2 * qb + 1;

    GLD16(kbase, &ks[0][lb]);
    GLD16(vtbase, &vt[0][lb]);

    for (int tb = 0; tb <= tmax; ++tb) {
        int cur = tb & 1;
        __syncthreads();
        if (tb < tmax) {
            GLD16(kbase + (size_t)(tb + 1) * 64 * QKG, &ks[cur ^ 1][lb]);
            GLD16(vtbase + (tb + 1) * 64, &vt[cur ^ 1][lb]);
        }

        f32x4 sacc[4];
#pragma unroll
        for (int i = 0; i < 4; ++i) sacc[i] = (f32x4){0.f, 0.f, 0.f, 0.f};
#pragma unroll
        for (int tile = 0; tile < 4; ++tile) {
            bf16x8 kb0 = *(const bf16x8*)(&ks[cur][(tile * 16 + l15) * 32 + quad * 8]);
            bf16x8 kb1 = *(const bf16x8*)(&ks[cur][2048 + (tile * 16 + l15) * 32 + quad * 8]);
            sacc[tile] = __builtin_amdgcn_mfma_f32_16x16x32_bf16(qa0, kb0, sacc[tile], 0, 0, 0);
            sacc[tile] = __builtin_amdgcn_mfma_f32_16x16x32_bf16(qa1, kb1, sacc[tile], 0, 0, 0);
        }

        int fbi = sbase - tb * 64;
        float rf[4];
#pragma unroll
        for (int reg = 0; reg < 4; ++reg)
            rf[reg] = exp2f((float)(fbi + reg) * log2g);

        if (tb * 64 + 63 > s0 + w * 16) {
#pragma unroll
            for (int tile = 0; tile < 4; ++tile) {
                int tt = tile * 16 + l15;
#pragma unroll
                for (int reg = 0; reg < 4; ++reg) {
                    float p = (fbi + reg >= tt) ? sacc[tile][reg] * rf[reg] * colfac[tile] : 0.0f;
                    ps[w][(quad * 4 + reg) * PSTR + tile * 16 + l15] = f2bf(p);
                }
            }
        } else {
#pragma unroll
            for (int tile = 0; tile < 4; ++tile)
#pragma unroll
                for (int reg = 0; reg < 4; ++reg)
                    ps[w][(quad * 4 + reg) * PSTR + tile * 16 + l15] =
                        f2bf(sacc[tile][reg] * (rf[reg] * colfac[tile]));
        }

#pragma unroll
        for (int ksi = 0; ksi < 2; ++ksi) {
            bf16x8 pa = *(const bf16x8*)(&ps[w][l15 * PSTR + ksi * 32 + quad * 8]);
#pragma unroll
            for (int dt = 0; dt < 4; ++dt) {
                bf16x8 vb = *(const bf16x8*)(&vt[cur][ksi * 2048 + (dt * 16 + l15) * 32 + quad * 8]);
                oacc[dt] = __builtin_amdgcn_mfma_f32_16x16x32_bf16(pa, vb, oacc[dt], 0, 0, 0);
            }
        }
    }

    float s1[4], s2[4];
#pragma unroll
    for (int reg = 0; reg < 4; ++reg) {
        s1[reg] = oacc[0][reg] + oacc[1][reg] + oacc[2][reg] + oacc[3][reg];
        s2[reg] = oacc[0][reg] * oacc[0][reg] + oacc[1][reg] * oacc[1][reg]
                + oacc[2][reg] * oacc[2][reg] + oacc[3][reg] * oacc[3][reg];
    }
#pragma unroll
    for (int off = 1; off < 16; off <<= 1) {
#pragma unroll
        for (int reg = 0; reg < 4; ++reg) {
            s1[reg] += __shfl_xor(s1[reg], off);
            s2[reg] += __shfl_xor(s2[reg], off);
        }
    }
    size_t rowtok = tok0 + s0 + w * 16 + quad * 4;
    short* obase = rg + rowtok * D_MODEL + hcol;
    const short* gbase = qkg + rowtok * QKG + 2048 + hcol;
#pragma unroll
    for (int reg = 0; reg < 4; ++reg) {
        float mu  = s1[reg] * (1.0f / 64.0f);
        float var = s2[reg] * (1.0f / 64.0f) - mu * mu;
        float inv = rsqrtf(var + 1e-6f);
#pragma unroll
        for (int dt = 0; dt < 4; ++dt) {
            float gv = bf2f(gbase[(size_t)reg * QKG + dt * 16 + l15]);
            float val = (oacc[dt][reg] - mu) * inv * (gv / (1.0f + expf(-gv)));
            obase[(size_t)reg * D_MODEL + dt * 16 + l15] = f2bf(val);
        }
    }
}

// ---------------------------------------------------------------------------
extern "C" void kernel_launch(void* const* d_in, const int* in_sizes, int n_in,
                              void* d_out, int out_size, void* d_ws, size_t ws_size,
                              hipStream_t stream)
{
    const float* x     = (const float*)d_in[0];
    const float* ln1w  = (const float*)d_in[1];
    const float* ln1b  = (const float*)d_in[2];
    const float* wq    = (const float*)d_in[3];
    const float* wk    = (const float*)d_in[4];
    const float* wv    = (const float*)d_in[5];
    const float* wg    = (const float*)d_in[6];
    const float* wo    = (const float*)d_in[7];
    const float* ln2w  = (const float*)d_in[8];
    const float* ln2b  = (const float*)d_in[9];
    const float* w_in  = (const float*)d_in[10];
    const float* b_in  = (const float*)d_in[11];
    const float* w_out = (const float*)d_in[12];
    const float* b_out = (const float*)d_in[13];
    float* out = (float*)d_out;
    char* base = (char*)d_ws;

    const size_t MB = 1u << 20;
    short* xn     = (short*)(base);            // [0,8)   [4096][1024] bf16 LN out
    short* qkgT   = (short*)(base +  8 * MB);  // [8,14)  wq|wk|wg transposed [3072][1024]
    short* wvT    = (short*)(base + 14 * MB);  // [14,16) [1024][1024]
    short* woT    = (short*)(base + 16 * MB);  // [16,18) [1024][1024]
    short* w_inT  = (short*)(base + 18 * MB);  // [18,29) [5632][1024]
    short* w_outT = (short*)(base + 29 * MB);  // [29,34.5) [1024][2816]
    short* qkg    = (short*)(base + 35 * MB);  // [35,59) [4096][3072] packed q|k|g
    short* hm     = (short*)(base + 35 * MB);  // [35,57) [4096][2816] reuses dead qkg
    short* vT     = (short*)(base + 59 * MB);  // [59,67) [1024][4096] V transposed
    short* rg     = (short*)(base + 67 * MB);  // [67,75) [4096][1024] gated retention out

    // all 8 weight transposes in one launch
    TJobs jobs;
    jobs.j[0] = { wq,    qkgT,                          1024,    0, 1024, 1024, 1024, 1024 };
    jobs.j[1] = { wk,    qkgT + 1024 * 1024,            1024,    0, 1024, 1024, 1024, 1024 };
    jobs.j[2] = { wg,    qkgT + 2 * 1024 * 1024,        1024,    0, 1024, 1024, 1024, 1024 };
    jobs.j[3] = { wv,    wvT,                           1024,    0, 1024, 1024, 1024, 1024 };
    jobs.j[4] = { wo,    woT,                           1024,    0, 1024, 1024, 1024, 1024 };
    jobs.j[5] = { w_in,  w_inT,                         2 * HID, 0,   HID, 1024, 1024, HID_PAD };
    jobs.j[6] = { w_in,  w_inT + (size_t)HID_PAD * 1024, 2 * HID, HID, HID, 1024, 1024, HID_PAD };
    jobs.j[7] = { w_out, w_outT,                        1024,    0, 1024, HID, HID_PAD, 1024 };
    transpose_all<<<dim3(44, 44, 8), 256, 0, stream>>>(jobs);

    // LN1 -> bf16
    ln_kernel<<<NTOK, 256, 0, stream>>>(x, ln1w, ln1b, xn, 1e-5f);
    // merged q|k|g + v^T projections (1024 blocks, one launch)
    proj_kernel<<<1024, 256, 0, stream>>>(xn, qkgT, qkg, wvT, vT);
    // retention + groupnorm + silu gate
    retention_mfma<<<dim3(SEQ / 128, NHEAD, BATCH), 512, 0, stream>>>(qkg, vT, rg);
    // wo projection + residual x -> out (fp32); 512 blocks co-resident
    gemm_n64<1><<<dim3(32, 16), 256, 0, stream>>>(rg, D_MODEL, woT, nullptr, x, D_MODEL, out, D_MODEL, D_MODEL);
    // LN2 -> bf16
    ln_kernel<<<NTOK, 256, 0, stream>>>(out, ln2w, ln2b, xn, 1e-5f);
    // fused SwiGLU-in GEMM
    mlp_fused<<<dim3(NTOK / 128, HID_PAD / 64), 256, 0, stream>>>(xn, w_inT, b_in, hm);
    // w_out GEMM + bias + residual; 512 blocks co-resident
    gemm_n64<2><<<dim3(32, 16), 256, 0, stream>>>(hm, HID_PAD, w_outT, b_out, out, D_MODEL, out, D_MODEL, HID_PAD);
}